// Round 1
// baseline (489.107 us; speedup 1.0000x reference)
//
#include <hip/hip_runtime.h>

typedef unsigned short u16;
typedef __attribute__((ext_vector_type(8))) __bf16 bf16x8;
typedef __attribute__((ext_vector_type(4))) float f32x4;
typedef __attribute__((ext_vector_type(4))) unsigned short u16x4;
typedef __attribute__((ext_vector_type(8))) unsigned short u16x8;

#define LOG2E 1.44269504088896340736f

__device__ __forceinline__ u16 f2bf(float f) {
  union { float f; unsigned u; } c; c.f = f;
  unsigned r = c.u + 0x7FFFu + ((c.u >> 16) & 1u);
  return (u16)(r >> 16);
}
__device__ __forceinline__ float bf2f(u16 h) {
  union { unsigned u; float f; } c; c.u = ((unsigned)h) << 16;
  return c.f;
}

__device__ __forceinline__ void gload_lds16(const u16* g, u16* l) {
  __builtin_amdgcn_global_load_lds((const __attribute__((address_space(1))) unsigned int*)g,
                                   (__attribute__((address_space(3))) unsigned int*)l, 16, 0, 0);
}

// ---------------- f32 -> bf16 conversion ----------------
__global__ __launch_bounds__(256) void cvt_f32_bf16(const float* __restrict__ in, u16* __restrict__ out, int n4) {
  int i = blockIdx.x * 256 + threadIdx.x;
  if (i >= n4) return;
  f32x4 v = ((const f32x4*)in)[i];
  u16x4 o;
  o[0] = f2bf(v[0]); o[1] = f2bf(v[1]); o[2] = f2bf(v[2]); o[3] = f2bf(v[3]);
  ((u16x4*)out)[i] = o;
}

// ---------------- mask expansion (bool/int32 autodetect) ----------------
__global__ void build_masks(const void* __restrict__ pm, float* __restrict__ maskbias,
                            float* __restrict__ qmask, int n) {
  __shared__ int sflag;
  if (threadIdx.x == 0) sflag = 0;
  __syncthreads();
  const unsigned* pw = (const unsigned*)pm;
  int nwords = n / 4;  // first n bytes: safe to read in both layouts
  int local = 0;
  for (int i = threadIdx.x; i < nwords; i += blockDim.x)
    if (pw[i] > 1u) local = 1;
  if (local) atomicOr(&sflag, 1);
  __syncthreads();
  bool isbool = (sflag != 0);  // packed bool bytes -> some word >1
  for (int i = threadIdx.x; i < n; i += blockDim.x) {
    int m = isbool ? (int)((const unsigned char*)pm)[i] : ((const int*)pm)[i];
    maskbias[i] = m ? 0.0f : -1e30f;
    qmask[i]    = m ? 1.0f : 0.0f;
  }
}

// ---------------- GEMM: C[M,N] = act(A[M,K] @ W[N,K]^T + bias) -> bf16 ----------------
// EPI: 0 none, 1 +bias, 2 +bias+exact GELU
template<int EPI>
__global__ __launch_bounds__(256) void gemm_bt(const u16* __restrict__ A, const u16* __restrict__ Bw,
                                               const float* __restrict__ bias, u16* __restrict__ C,
                                               int N, int K) {
  __shared__ u16 As[128 * 32];
  __shared__ u16 Bs[128 * 32];
  int bn = blockIdx.x, bm = blockIdx.y;
  int tid = threadIdx.x;
  int wave = tid >> 6, lane = tid & 63;
  int l15 = lane & 15, l4 = lane >> 4;
  int wr = (wave >> 1) * 64, wc = (wave & 1) * 64;
  int mrow0 = bm * 128, ncol0 = bn * 128;
  int srow = lane >> 2;          // row within 16-row staging chunk
  int scol = (lane & 3) * 8;     // col (elements)

  f32x4 acc[4][4];
#pragma unroll
  for (int i = 0; i < 4; i++)
#pragma unroll
    for (int j = 0; j < 4; j++) acc[i][j] = (f32x4)0.0f;

  for (int k0 = 0; k0 < K; k0 += 32) {
#pragma unroll
    for (int c = 0; c < 2; c++) {
      int q = wave * 2 + c;
      gload_lds16(A  + (size_t)(mrow0 + q * 16 + srow) * K + k0 + scol, &As[q * 512]);
      gload_lds16(Bw + (size_t)(ncol0 + q * 16 + srow) * K + k0 + scol, &Bs[q * 512]);
    }
    __syncthreads();
    bf16x8 af[4], bfr[4];
#pragma unroll
    for (int mi = 0; mi < 4; mi++) af[mi]  = *(const bf16x8*)(&As[(wr + mi * 16 + l15) * 32 + l4 * 8]);
#pragma unroll
    for (int ni = 0; ni < 4; ni++) bfr[ni] = *(const bf16x8*)(&Bs[(wc + ni * 16 + l15) * 32 + l4 * 8]);
#pragma unroll
    for (int mi = 0; mi < 4; mi++)
#pragma unroll
      for (int ni = 0; ni < 4; ni++)
        acc[mi][ni] = __builtin_amdgcn_mfma_f32_16x16x32_bf16(af[mi], bfr[ni], acc[mi][ni], 0, 0, 0);
    __syncthreads();
  }

#pragma unroll
  for (int ni = 0; ni < 4; ni++) {
    int gcol = ncol0 + wc + ni * 16 + l15;
    float bv = (EPI > 0) ? bias[gcol] : 0.0f;
#pragma unroll
    for (int mi = 0; mi < 4; mi++) {
#pragma unroll
      for (int r = 0; r < 4; r++) {
        int grow = mrow0 + wr + mi * 16 + l4 * 4 + r;
        float v = acc[mi][ni][r] + bv;
        if (EPI == 2) v = 0.5f * v * (1.0f + erff(v * 0.70710678118654752f));
        C[(size_t)grow * N + gcol] = f2bf(v);
      }
    }
  }
}

// ---------------- flash attention, per-head contiguous [2048,64] ----------------
__global__ __launch_bounds__(256) void attn_kernel(const u16* __restrict__ Q, const u16* __restrict__ Kg,
                                                   const u16* __restrict__ Vg,
                                                   const float* __restrict__ maskbias,
                                                   const float* __restrict__ qmaskf,
                                                   u16* __restrict__ O) {
  const int T = 2048, KT = 64;
  int bh = blockIdx.y;           // b*16 + head
  int b = bh >> 4;
  const u16* Qh = Q  + (size_t)bh * T * 64;
  const u16* Kh = Kg + (size_t)bh * T * 64;
  const u16* Vh = Vg + (size_t)bh * T * 64;
  u16* Oh = O + (size_t)bh * T * 64;
  const float* mb = maskbias + b * T;
  const float* qm = qmaskf + b * T;
  int qt = blockIdx.x;           // 16 tiles of 128 q-rows
  int tid = threadIdx.x, wave = tid >> 6, lane = tid & 63;
  int l15 = lane & 15, l4 = lane >> 4;

  __shared__ u16 Ks[64 * 72];
  __shared__ u16 VTs[64 * 72];   // VT[d][k]
  __shared__ u16 Ps[4 * 32 * 72];

  int qrow0 = qt * 128 + wave * 32;
  bf16x8 aQ[2][2];
#pragma unroll
  for (int mi = 0; mi < 2; mi++)
#pragma unroll
    for (int kc = 0; kc < 2; kc++)
      aQ[mi][kc] = *(const bf16x8*)(Qh + (size_t)(qrow0 + mi * 16 + l15) * 64 + kc * 32 + l4 * 8);

  f32x4 accO[2][4];
  float mstate[2][4], sstate[2][4];
#pragma unroll
  for (int mi = 0; mi < 2; mi++)
#pragma unroll
    for (int dj = 0; dj < 4; dj++) accO[mi][dj] = (f32x4)0.0f;
#pragma unroll
  for (int mi = 0; mi < 2; mi++)
#pragma unroll
    for (int r = 0; r < 4; r++) { mstate[mi][r] = -1e30f; sstate[mi][r] = 0.0f; }

  for (int kt = 0; kt < T / KT; kt++) {
    int kbase = kt * KT;
    // stage K (row-major, padded rows) and V^T (scattered)
#pragma unroll
    for (int it = 0; it < 2; it++) {
      int idx = it * 256 + tid;        // 0..511 vec8 units
      int kr = idx >> 3;
      int c8 = (idx & 7) * 8;
      bf16x8 kv = *(const bf16x8*)(Kh + (size_t)(kbase + kr) * 64 + c8);
      *(bf16x8*)(&Ks[kr * 72 + c8]) = kv;
      u16x8 vv = *(const u16x8*)(Vh + (size_t)(kbase + kr) * 64 + c8);
#pragma unroll
      for (int e = 0; e < 8; e++) VTs[(c8 + e) * 72 + kr] = vv[e];
    }
    __syncthreads();

    // S = Q K^T
    f32x4 sf[2][4];
#pragma unroll
    for (int mi = 0; mi < 2; mi++)
#pragma unroll
      for (int nj = 0; nj < 4; nj++) sf[mi][nj] = (f32x4)0.0f;
#pragma unroll
    for (int kc = 0; kc < 2; kc++) {
      bf16x8 bK[4];
#pragma unroll
      for (int nj = 0; nj < 4; nj++) bK[nj] = *(const bf16x8*)(&Ks[(nj * 16 + l15) * 72 + kc * 32 + l4 * 8]);
#pragma unroll
      for (int mi = 0; mi < 2; mi++)
#pragma unroll
        for (int nj = 0; nj < 4; nj++)
          sf[mi][nj] = __builtin_amdgcn_mfma_f32_16x16x32_bf16(aQ[mi][kc], bK[nj], sf[mi][nj], 0, 0, 0);
    }

    float colmb[4];
#pragma unroll
    for (int nj = 0; nj < 4; nj++) colmb[nj] = mb[kbase + nj * 16 + l15];

#pragma unroll
    for (int mi = 0; mi < 2; mi++) {
#pragma unroll
      for (int r = 0; r < 4; r++) {
        float mx = -1e30f;
#pragma unroll
        for (int nj = 0; nj < 4; nj++) {
          float val = sf[mi][nj][r] * 0.125f + colmb[nj];
          sf[mi][nj][r] = val;
          mx = fmaxf(mx, val);
        }
#pragma unroll
        for (int m = 1; m < 16; m <<= 1) mx = fmaxf(mx, __shfl_xor(mx, m));
        float mold = mstate[mi][r];
        float mnew = fmaxf(mold, mx);
        float fsc = exp2f((mold - mnew) * LOG2E);
        float rowsum = 0.0f;
#pragma unroll
        for (int nj = 0; nj < 4; nj++) {
          float p = exp2f((sf[mi][nj][r] - mnew) * LOG2E);
          sf[mi][nj][r] = p;
          rowsum += p;
        }
#pragma unroll
        for (int m = 1; m < 16; m <<= 1) rowsum += __shfl_xor(rowsum, m);
        sstate[mi][r] = sstate[mi][r] * fsc + rowsum;
        mstate[mi][r] = mnew;
#pragma unroll
        for (int dj = 0; dj < 4; dj++) accO[mi][dj][r] *= fsc;
        int prow = wave * 32 + mi * 16 + l4 * 4 + r;
#pragma unroll
        for (int nj = 0; nj < 4; nj++) Ps[prow * 72 + nj * 16 + l15] = f2bf(sf[mi][nj][r]);
      }
    }

    // O += P V  (per-wave P buffer; compiler orders ds_write->ds_read within wave)
#pragma unroll
    for (int kc = 0; kc < 2; kc++) {
      bf16x8 aP[2];
#pragma unroll
      for (int mi = 0; mi < 2; mi++)
        aP[mi] = *(const bf16x8*)(&Ps[(wave * 32 + mi * 16 + l15) * 72 + kc * 32 + l4 * 8]);
#pragma unroll
      for (int dj = 0; dj < 4; dj++) {
        bf16x8 bV = *(const bf16x8*)(&VTs[(dj * 16 + l15) * 72 + kc * 32 + l4 * 8]);
#pragma unroll
        for (int mi = 0; mi < 2; mi++)
          accO[mi][dj] = __builtin_amdgcn_mfma_f32_16x16x32_bf16(aP[mi], bV, accO[mi][dj], 0, 0, 0);
      }
    }
    __syncthreads();
  }

#pragma unroll
  for (int mi = 0; mi < 2; mi++) {
#pragma unroll
    for (int r = 0; r < 4; r++) {
      int grow = qrow0 + mi * 16 + l4 * 4 + r;
      float sc = (1.0f / sstate[mi][r]) * qm[grow];
#pragma unroll
      for (int dj = 0; dj < 4; dj++)
        Oh[(size_t)grow * 64 + dj * 16 + l15] = f2bf(accO[mi][dj][r] * sc);
    }
  }
}

// ---------------- residual add + layernorm ----------------
template<int A_F32, int OUT_F32>
__global__ __launch_bounds__(256) void add_ln(const void* __restrict__ Ap, const u16* __restrict__ Bp,
                                              const float* __restrict__ g, const float* __restrict__ be,
                                              void* __restrict__ outp) {
  int row = blockIdx.x, tid = threadIdx.x;
  int lane = tid & 63, wave = tid >> 6;
  float x[4];
  if (A_F32) {
    f32x4 a = ((const f32x4*)((const float*)Ap + (size_t)row * 1024))[tid];
    u16x4 bu = ((const u16x4*)(Bp + (size_t)row * 1024))[tid];
#pragma unroll
    for (int j = 0; j < 4; j++) x[j] = a[j] + bf2f(bu[j]);
  } else {
    u16x4 au = ((const u16x4*)((const u16*)Ap + (size_t)row * 1024))[tid];
    u16x4 bu = ((const u16x4*)(Bp + (size_t)row * 1024))[tid];
#pragma unroll
    for (int j = 0; j < 4; j++) x[j] = bf2f(au[j]) + bf2f(bu[j]);
  }
  float s = x[0] + x[1] + x[2] + x[3];
  float q = x[0] * x[0] + x[1] * x[1] + x[2] * x[2] + x[3] * x[3];
#pragma unroll
  for (int m = 1; m < 64; m <<= 1) { s += __shfl_xor(s, m); q += __shfl_xor(q, m); }
  __shared__ float rs[4], rq[4];
  if (lane == 0) { rs[wave] = s; rq[wave] = q; }
  __syncthreads();
  float S = rs[0] + rs[1] + rs[2] + rs[3];
  float Qq = rq[0] + rq[1] + rq[2] + rq[3];
  float mean = S * (1.0f / 1024.0f);
  float var = Qq * (1.0f / 1024.0f) - mean * mean;
  float rstd = rsqrtf(var + 1e-5f);
  if (OUT_F32) {
    f32x4 y;
#pragma unroll
    for (int j = 0; j < 4; j++) { int col = tid * 4 + j; y[j] = (x[j] - mean) * rstd * g[col] + be[col]; }
    ((f32x4*)((float*)outp + (size_t)row * 1024))[tid] = y;
  } else {
    u16x4 y;
#pragma unroll
    for (int j = 0; j < 4; j++) { int col = tid * 4 + j; y[j] = f2bf((x[j] - mean) * rstd * g[col] + be[col]); }
    ((u16x4*)((u16*)outp + (size_t)row * 1024))[tid] = y;
  }
}

// ---------------- launch ----------------
extern "C" void kernel_launch(void* const* d_in, const int* in_sizes, int n_in,
                              void* d_out, int out_size, void* d_ws, size_t ws_size,
                              hipStream_t stream) {
  const float* q   = (const float*)d_in[0];
  const float* k   = (const float*)d_in[1];
  const float* v   = (const float*)d_in[2];
  const void*  pad = d_in[3];
  const float* Wq  = (const float*)d_in[4];
  const float* Wk  = (const float*)d_in[5];
  const float* Wv  = (const float*)d_in[6];
  const float* Wo  = (const float*)d_in[7];
  const float* W1  = (const float*)d_in[8];
  const float* b1  = (const float*)d_in[9];
  const float* W2  = (const float*)d_in[10];
  const float* b2  = (const float*)d_in[11];
  const float* g1  = (const float*)d_in[12];
  const float* be1 = (const float*)d_in[13];
  const float* g2  = (const float*)d_in[14];
  const float* be2 = (const float*)d_in[15];
  float* out = (float*)d_out;
  char* ws = (char*)d_ws;
  const size_t MB = 1u << 20;

  u16* wq_b = (u16*)(ws + 0 * MB);
  u16* wk_b = (u16*)(ws + 2 * MB);
  u16* wv_b = (u16*)(ws + 4 * MB);
  u16* wo_b = (u16*)(ws + 6 * MB);
  u16* w1_b = (u16*)(ws + 8 * MB);
  u16* w2_b = (u16*)(ws + 16 * MB);
  u16* qb   = (u16*)(ws + 24 * MB);
  u16* kb   = (u16*)(ws + 32 * MB);
  u16* vb   = (u16*)(ws + 40 * MB);
  u16* Qb   = (u16*)(ws + 48 * MB);
  u16* Kb   = (u16*)(ws + 56 * MB);
  u16* Vb   = (u16*)(ws + 64 * MB);
  u16* hatt = (u16*)(ws + 72 * MB);
  u16* atto = (u16*)(ws + 80 * MB);
  u16* h1b  = (u16*)(ws + 88 * MB);
  u16* ff1  = (u16*)(ws + 24 * MB);   // reuse: qb/kb/vb/Qb dead
  u16* ff2  = (u16*)(ws + 56 * MB);   // reuse: Kb dead
  float* maskbias = (float*)(ws + 96 * MB);
  float* qmaskf   = (float*)(ws + 96 * MB + 32768);

  build_masks<<<1, 256, 0, stream>>>(pad, maskbias, qmaskf, in_sizes[3]);

  auto cvt = [&](const float* src, u16* dst, int n) {
    int n4 = n / 4;
    cvt_f32_bf16<<<(n4 + 255) / 256, 256, 0, stream>>>(src, dst, n4);
  };
  cvt(q, qb, 4194304); cvt(k, kb, 4194304); cvt(v, vb, 4194304);
  cvt(Wq, wq_b, 1048576); cvt(Wk, wk_b, 1048576); cvt(Wv, wv_b, 1048576); cvt(Wo, wo_b, 1048576);
  cvt(W1, w1_b, 4194304); cvt(W2, w2_b, 4194304);

  // QKV projections: M=4096, N=1024, K=1024
  gemm_bt<0><<<dim3(8, 32), 256, 0, stream>>>(qb, wq_b, nullptr, Qb, 1024, 1024);
  gemm_bt<0><<<dim3(8, 32), 256, 0, stream>>>(kb, wk_b, nullptr, Kb, 1024, 1024);
  gemm_bt<0><<<dim3(8, 32), 256, 0, stream>>>(vb, wv_b, nullptr, Vb, 1024, 1024);

  // attention: 32 heads x 16 q-tiles
  attn_kernel<<<dim3(16, 32), 256, 0, stream>>>(Qb, Kb, Vb, maskbias, qmaskf, hatt);

  // output projection
  gemm_bt<0><<<dim3(8, 32), 256, 0, stream>>>(hatt, wo_b, nullptr, atto, 1024, 1024);

  // LN1: q(f32) + atto -> h1 (bf16)
  add_ln<1, 0><<<4096, 256, 0, stream>>>(q, atto, g1, be1, h1b);

  // FFN
  gemm_bt<2><<<dim3(32, 32), 256, 0, stream>>>(h1b, w1_b, b1, ff1, 4096, 1024);
  gemm_bt<1><<<dim3(8, 32), 256, 0, stream>>>(ff1, w2_b, b2, ff2, 1024, 4096);

  // LN2: h1 + ff2 -> out (f32)
  add_ln<0, 1><<<4096, 256, 0, stream>>>(h1b, ff2, g2, be2, out);
}

// Round 2
// 453.473 us; speedup vs baseline: 1.0786x; 1.0786x over previous
//
#include <hip/hip_runtime.h>

typedef unsigned short u16;
typedef unsigned int u32;
typedef __attribute__((ext_vector_type(8))) __bf16 bf16x8;
typedef __attribute__((ext_vector_type(4))) float f32x4;
typedef __attribute__((ext_vector_type(16))) float f32x16;
typedef __attribute__((ext_vector_type(4))) unsigned short u16x4;
typedef __attribute__((ext_vector_type(8))) unsigned short u16x8;

#define LOG2E 1.44269504088896340736f

__device__ __forceinline__ u16 f2bf(float f) {
  union { float f; unsigned u; } c; c.f = f;
  unsigned r = c.u + 0x7FFFu + ((c.u >> 16) & 1u);
  return (u16)(r >> 16);
}
__device__ __forceinline__ float bf2f(u16 h) {
  union { unsigned u; float f; } c; c.u = ((unsigned)h) << 16;
  return c.f;
}

__device__ __forceinline__ void gload_lds16(const u16* g, u16* l) {
  __builtin_amdgcn_global_load_lds((const __attribute__((address_space(1))) unsigned int*)g,
                                   (__attribute__((address_space(3))) unsigned int*)l, 16, 0, 0);
}

// ---------------- f32 -> bf16 conversion ----------------
__global__ __launch_bounds__(256) void cvt_f32_bf16(const float* __restrict__ in, u16* __restrict__ out, int n4) {
  int i = blockIdx.x * 256 + threadIdx.x;
  if (i >= n4) return;
  f32x4 v = ((const f32x4*)in)[i];
  u16x4 o;
  o[0] = f2bf(v[0]); o[1] = f2bf(v[1]); o[2] = f2bf(v[2]); o[3] = f2bf(v[3]);
  ((u16x4*)out)[i] = o;
}

// ---------------- mask expansion (bool/int32 autodetect) ----------------
__global__ void build_masks(const void* __restrict__ pm, float* __restrict__ maskbias,
                            float* __restrict__ qmask, int n) {
  __shared__ int sflag;
  if (threadIdx.x == 0) sflag = 0;
  __syncthreads();
  const unsigned* pw = (const unsigned*)pm;
  int nwords = n / 4;
  int local = 0;
  for (int i = threadIdx.x; i < nwords; i += blockDim.x)
    if (pw[i] > 1u) local = 1;
  if (local) atomicOr(&sflag, 1);
  __syncthreads();
  bool isbool = (sflag != 0);
  for (int i = threadIdx.x; i < n; i += blockDim.x) {
    int m = isbool ? (int)((const unsigned char*)pm)[i] : ((const int*)pm)[i];
    maskbias[i] = m ? 0.0f : -2e30f;
    qmask[i]    = m ? 1.0f : 0.0f;
  }
}

// ---------------- GEMM: C[M,N] = act(A[M,K] @ W[N,K]^T + bias) -> bf16 ----------------
template<int EPI>
__global__ __launch_bounds__(256) void gemm_bt(const u16* __restrict__ A, const u16* __restrict__ Bw,
                                               const float* __restrict__ bias, u16* __restrict__ C,
                                               int N, int K) {
  __shared__ u16 As[128 * 32];
  __shared__ u16 Bs[128 * 32];
  int bn = blockIdx.x, bm = blockIdx.y;
  int tid = threadIdx.x;
  int wave = tid >> 6, lane = tid & 63;
  int l15 = lane & 15, l4 = lane >> 4;
  int wr = (wave >> 1) * 64, wc = (wave & 1) * 64;
  int mrow0 = bm * 128, ncol0 = bn * 128;
  int srow = lane >> 2;
  int scol = (lane & 3) * 8;

  f32x4 acc[4][4];
#pragma unroll
  for (int i = 0; i < 4; i++)
#pragma unroll
    for (int j = 0; j < 4; j++) acc[i][j] = (f32x4)0.0f;

  for (int k0 = 0; k0 < K; k0 += 32) {
#pragma unroll
    for (int c = 0; c < 2; c++) {
      int q = wave * 2 + c;
      gload_lds16(A  + (size_t)(mrow0 + q * 16 + srow) * K + k0 + scol, &As[q * 512]);
      gload_lds16(Bw + (size_t)(ncol0 + q * 16 + srow) * K + k0 + scol, &Bs[q * 512]);
    }
    __syncthreads();
    bf16x8 af[4], bfr[4];
#pragma unroll
    for (int mi = 0; mi < 4; mi++) af[mi]  = *(const bf16x8*)(&As[(wr + mi * 16 + l15) * 32 + l4 * 8]);
#pragma unroll
    for (int ni = 0; ni < 4; ni++) bfr[ni] = *(const bf16x8*)(&Bs[(wc + ni * 16 + l15) * 32 + l4 * 8]);
#pragma unroll
    for (int mi = 0; mi < 4; mi++)
#pragma unroll
      for (int ni = 0; ni < 4; ni++)
        acc[mi][ni] = __builtin_amdgcn_mfma_f32_16x16x32_bf16(af[mi], bfr[ni], acc[mi][ni], 0, 0, 0);
    __syncthreads();
  }

#pragma unroll
  for (int ni = 0; ni < 4; ni++) {
    int gcol = ncol0 + wc + ni * 16 + l15;
    float bv = (EPI > 0) ? bias[gcol] : 0.0f;
#pragma unroll
    for (int mi = 0; mi < 4; mi++) {
#pragma unroll
      for (int r = 0; r < 4; r++) {
        int grow = mrow0 + wr + mi * 16 + l4 * 4 + r;
        float v = acc[mi][ni][r] + bv;
        if (EPI == 2) v = 0.5f * v * (1.0f + erff(v * 0.70710678118654752f));
        C[(size_t)grow * N + gcol] = f2bf(v);
      }
    }
  }
}

// ---------------- V transpose: [32][2048][64] -> [32][64][2048] ----------------
__global__ __launch_bounds__(256) void transpose64(const u16* __restrict__ in, u16* __restrict__ out) {
  int bh = blockIdx.y, tb = blockIdx.x;
  __shared__ u16 tile[64 * 72];
  int tid = threadIdx.x;
#pragma unroll
  for (int it = 0; it < 2; it++) {
    int idx = it * 256 + tid;
    int r = idx >> 3, c8 = (idx & 7) * 8;
    u16x8 v = *(const u16x8*)(in + ((size_t)bh * 2048 + tb * 64 + r) * 64 + c8);
    int byte = ((r * 72 + c8) * 2) ^ (((r >> 3) & 7) << 4);
    *(u16x8*)((char*)tile + byte) = v;
  }
  __syncthreads();
#pragma unroll
  for (int it = 0; it < 2; it++) {
    int idx = it * 256 + tid;
    int d = idx >> 3, t8 = (idx & 7) * 8;
    u16x8 o;
#pragma unroll
    for (int e = 0; e < 8; e++) {
      int t = t8 + e;
      int byte = ((t * 72 + d) * 2) ^ (((t >> 3) & 7) << 4);
      o[e] = *(const u16*)((const char*)tile + byte);
    }
    *(u16x8*)(out + ((size_t)bh * 64 + d) * 2048 + tb * 64 + t8) = o;
  }
}

// ---------------- flash attention v2: swapped-QK, lane-local softmax, no LDS ----------------
__global__ __launch_bounds__(256) void attn2(const u16* __restrict__ Q, const u16* __restrict__ Kg,
                                             const u16* __restrict__ VT,
                                             const float* __restrict__ maskbias,
                                             const float* __restrict__ qmaskf,
                                             u16* __restrict__ O) {
  const int T = 2048;
  int bh = blockIdx.x;           // head on x -> 16 q-blocks of a head share an XCD
  int qt = blockIdx.y;
  int b = bh >> 4;
  const u16* Qh = Q  + (size_t)bh * T * 64;
  const u16* Kh = Kg + (size_t)bh * T * 64;
  const u16* Vh = VT + (size_t)bh * T * 64;   // [64][2048]
  u16* Oh = O + (size_t)bh * T * 64;
  const float* mb = maskbias + b * T;
  const float* qm = qmaskf + b * T;
  int tid = threadIdx.x, w = tid >> 6, l = tid & 63;
  int q32 = l & 31, h = l >> 5;
  int qbase = qt * 128 + w * 32;
  const float C = 0.125f * LOG2E;

  // Q fragments (B-operand of swapped QK): lane holds Q[qbase+q32][dc*16 + h*8 + e]
  bf16x8 qf[4];
#pragma unroll
  for (int dc = 0; dc < 4; dc++)
    qf[dc] = *(const bf16x8*)(Qh + (size_t)(qbase + q32) * 64 + dc * 16 + h * 8);

  f32x16 acc[2];
  acc[0] = (f32x16)0.0f; acc[1] = (f32x16)0.0f;
  float m_ = -3e30f, s_ = 0.0f;

  for (int kt = 0; kt < 32; kt++) {
    int kbase = kt * 64;
    // K fragments (A-operand): lane holds K[kbase + kvc*32 + q32][dc*16 + h*8 + e]
    bf16x8 kf[2][4];
#pragma unroll
    for (int kvc = 0; kvc < 2; kvc++)
#pragma unroll
      for (int dc = 0; dc < 4; dc++)
        kf[kvc][dc] = *(const bf16x8*)(Kh + (size_t)(kbase + kvc * 32 + q32) * 64 + dc * 16 + h * 8);

    // S^T[kv][q]: col=q32, row kv = (reg&3) + 8*(reg>>2) + 4*h
    f32x16 st[2];
    st[0] = (f32x16)0.0f; st[1] = (f32x16)0.0f;
#pragma unroll
    for (int kvc = 0; kvc < 2; kvc++)
#pragma unroll
      for (int dc = 0; dc < 4; dc++)
        st[kvc] = __builtin_amdgcn_mfma_f32_32x32x16_bf16(kf[kvc][dc], qf[dc], st[kvc], 0, 0, 0);

    // scale + mask, lane-local max over 32 kv values
    float p[32];
    float pmax = -3e30f;
#pragma unroll
    for (int kvc = 0; kvc < 2; kvc++) {
#pragma unroll
      for (int g = 0; g < 4; g++) {
        f32x4 mv = *(const f32x4*)(mb + kbase + kvc * 32 + g * 8 + h * 4);
#pragma unroll
        for (int r = 0; r < 4; r++) {
          float val = st[kvc][g * 4 + r] * C + mv[r];
          p[kvc * 16 + g * 4 + r] = val;
          pmax = fmaxf(pmax, val);
        }
      }
    }
    pmax = fmaxf(pmax, __shfl_xor(pmax, 32));

    // defer-max: rescale only when max grew by > 8 (log2 units)
    if (__any(pmax - m_ > 8.0f)) {
      float mnew = fmaxf(m_, pmax);
      float fsc = __builtin_amdgcn_exp2f(m_ - mnew);
      s_ *= fsc;
      m_ = mnew;
#pragma unroll
      for (int g = 0; g < 4; g++)
#pragma unroll
        for (int r = 0; r < 4; r++) {
          float f = __shfl(fsc, g * 8 + h * 4 + r);
          acc[0][g * 4 + r] *= f;
          acc[1][g * 4 + r] *= f;
        }
    }

    // exp + sum + pack to bf16 pairs
    float rsum = 0.0f;
    u32 wds[16];
#pragma unroll
    for (int i = 0; i < 16; i++) {
      float a = __builtin_amdgcn_exp2f(p[2 * i] - m_);
      float bq = __builtin_amdgcn_exp2f(p[2 * i + 1] - m_);
      rsum += a + bq;
      union { __bf16 h2[2]; u32 u; } cv;
      cv.h2[0] = (__bf16)a; cv.h2[1] = (__bf16)bq;
      wds[i] = cv.u;
    }
    rsum += __shfl_xor(rsum, 32);
    s_ += rsum;

    // redistribute P to PV A-fragments (cross-half exchange + h-select)
    u32 sw[16];
#pragma unroll
    for (int i = 0; i < 16; i++) sw[i] = __shfl_xor(wds[i], 32);

#pragma unroll
    for (int kvc = 0; kvc < 2; kvc++) {
      int bse = kvc * 8;
      union { u32 u[4]; bf16x8 v; } pa0, pa1;
      pa0.u[0] = h ? sw[bse + 2] : wds[bse + 0];
      pa0.u[1] = h ? sw[bse + 3] : wds[bse + 1];
      pa0.u[2] = h ? wds[bse + 2] : sw[bse + 0];
      pa0.u[3] = h ? wds[bse + 3] : sw[bse + 1];
      pa1.u[0] = h ? sw[bse + 6] : wds[bse + 4];
      pa1.u[1] = h ? sw[bse + 7] : wds[bse + 5];
      pa1.u[2] = h ? wds[bse + 6] : sw[bse + 4];
      pa1.u[3] = h ? wds[bse + 7] : sw[bse + 5];
#pragma unroll
      for (int cl = 0; cl < 2; cl++) {
        bf16x8 pa = cl ? pa1.v : pa0.v;
        int cg = kvc * 2 + cl;
#pragma unroll
        for (int dblk = 0; dblk < 2; dblk++) {
          bf16x8 vf = *(const bf16x8*)(Vh + (size_t)(dblk * 32 + q32) * 2048 + kbase + cg * 16 + h * 8);
          acc[dblk] = __builtin_amdgcn_mfma_f32_32x32x16_bf16(pa, vf, acc[dblk], 0, 0, 0);
        }
      }
    }
  }

  // epilogue: normalize by s, apply query mask, store
  float rs = 1.0f / s_;
  f32x4 qv[4];
#pragma unroll
  for (int g = 0; g < 4; g++)
    qv[g] = *(const f32x4*)(qm + qbase + g * 8 + h * 4);
#pragma unroll
  for (int g = 0; g < 4; g++) {
#pragma unroll
    for (int r = 0; r < 4; r++) {
      int row = g * 8 + h * 4 + r;
      float f = __shfl(rs, row) * qv[g][r];
#pragma unroll
      for (int dblk = 0; dblk < 2; dblk++)
        Oh[(size_t)(qbase + row) * 64 + dblk * 32 + q32] = f2bf(acc[dblk][g * 4 + r] * f);
    }
  }
}

// ---------------- residual add + layernorm ----------------
template<int A_F32, int OUT_F32>
__global__ __launch_bounds__(256) void add_ln(const void* __restrict__ Ap, const u16* __restrict__ Bp,
                                              const float* __restrict__ g, const float* __restrict__ be,
                                              void* __restrict__ outp) {
  int row = blockIdx.x, tid = threadIdx.x;
  int lane = tid & 63, wave = tid >> 6;
  float x[4];
  if (A_F32) {
    f32x4 a = ((const f32x4*)((const float*)Ap + (size_t)row * 1024))[tid];
    u16x4 bu = ((const u16x4*)(Bp + (size_t)row * 1024))[tid];
#pragma unroll
    for (int j = 0; j < 4; j++) x[j] = a[j] + bf2f(bu[j]);
  } else {
    u16x4 au = ((const u16x4*)((const u16*)Ap + (size_t)row * 1024))[tid];
    u16x4 bu = ((const u16x4*)(Bp + (size_t)row * 1024))[tid];
#pragma unroll
    for (int j = 0; j < 4; j++) x[j] = bf2f(au[j]) + bf2f(bu[j]);
  }
  float s = x[0] + x[1] + x[2] + x[3];
  float q = x[0] * x[0] + x[1] * x[1] + x[2] * x[2] + x[3] * x[3];
#pragma unroll
  for (int m = 1; m < 64; m <<= 1) { s += __shfl_xor(s, m); q += __shfl_xor(q, m); }
  __shared__ float rs[4], rq[4];
  if (lane == 0) { rs[wave] = s; rq[wave] = q; }
  __syncthreads();
  float S = rs[0] + rs[1] + rs[2] + rs[3];
  float Qq = rq[0] + rq[1] + rq[2] + rq[3];
  float mean = S * (1.0f / 1024.0f);
  float var = Qq * (1.0f / 1024.0f) - mean * mean;
  float rstd = rsqrtf(var + 1e-5f);
  if (OUT_F32) {
    f32x4 y;
#pragma unroll
    for (int j = 0; j < 4; j++) { int col = tid * 4 + j; y[j] = (x[j] - mean) * rstd * g[col] + be[col]; }
    ((f32x4*)((float*)outp + (size_t)row * 1024))[tid] = y;
  } else {
    u16x4 y;
#pragma unroll
    for (int j = 0; j < 4; j++) { int col = tid * 4 + j; y[j] = f2bf((x[j] - mean) * rstd * g[col] + be[col]); }
    ((u16x4*)((u16*)outp + (size_t)row * 1024))[tid] = y;
  }
}

// ---------------- launch ----------------
extern "C" void kernel_launch(void* const* d_in, const int* in_sizes, int n_in,
                              void* d_out, int out_size, void* d_ws, size_t ws_size,
                              hipStream_t stream) {
  const float* q   = (const float*)d_in[0];
  const float* k   = (const float*)d_in[1];
  const float* v   = (const float*)d_in[2];
  const void*  pad = d_in[3];
  const float* Wq  = (const float*)d_in[4];
  const float* Wk  = (const float*)d_in[5];
  const float* Wv  = (const float*)d_in[6];
  const float* Wo  = (const float*)d_in[7];
  const float* W1  = (const float*)d_in[8];
  const float* b1  = (const float*)d_in[9];
  const float* W2  = (const float*)d_in[10];
  const float* b2  = (const float*)d_in[11];
  const float* g1  = (const float*)d_in[12];
  const float* be1 = (const float*)d_in[13];
  const float* g2  = (const float*)d_in[14];
  const float* be2 = (const float*)d_in[15];
  float* out = (float*)d_out;
  char* ws = (char*)d_ws;
  const size_t MB = 1u << 20;

  u16* wq_b = (u16*)(ws + 0 * MB);
  u16* wk_b = (u16*)(ws + 2 * MB);
  u16* wv_b = (u16*)(ws + 4 * MB);
  u16* wo_b = (u16*)(ws + 6 * MB);
  u16* w1_b = (u16*)(ws + 8 * MB);
  u16* w2_b = (u16*)(ws + 16 * MB);
  u16* qb   = (u16*)(ws + 24 * MB);
  u16* kb   = (u16*)(ws + 32 * MB);
  u16* vb   = (u16*)(ws + 40 * MB);
  u16* Qb   = (u16*)(ws + 48 * MB);
  u16* Kb   = (u16*)(ws + 56 * MB);
  u16* Vb   = (u16*)(ws + 64 * MB);
  u16* VTb  = (u16*)(ws + 72 * MB);
  u16* hatt = (u16*)(ws + 80 * MB);
  u16* atto = (u16*)(ws + 88 * MB);
  u16* h1b  = (u16*)(ws + 24 * MB);   // reuse: qb dead after QKV gemms
  u16* ff1  = (u16*)(ws + 32 * MB);   // reuse: kb/vb/Qb/Kb dead after attn (32MB)
  u16* ff2  = (u16*)(ws + 64 * MB);   // reuse: Vb dead
  float* maskbias = (float*)(ws + 96 * MB);
  float* qmaskf   = (float*)(ws + 96 * MB + 16384);

  build_masks<<<1, 256, 0, stream>>>(pad, maskbias, qmaskf, in_sizes[3]);

  auto cvt = [&](const float* src, u16* dst, int n) {
    int n4 = n / 4;
    cvt_f32_bf16<<<(n4 + 255) / 256, 256, 0, stream>>>(src, dst, n4);
  };
  cvt(q, qb, 4194304); cvt(k, kb, 4194304); cvt(v, vb, 4194304);
  cvt(Wq, wq_b, 1048576); cvt(Wk, wk_b, 1048576); cvt(Wv, wv_b, 1048576); cvt(Wo, wo_b, 1048576);
  cvt(W1, w1_b, 4194304); cvt(W2, w2_b, 4194304);

  gemm_bt<0><<<dim3(8, 32), 256, 0, stream>>>(qb, wq_b, nullptr, Qb, 1024, 1024);
  gemm_bt<0><<<dim3(8, 32), 256, 0, stream>>>(kb, wk_b, nullptr, Kb, 1024, 1024);
  gemm_bt<0><<<dim3(8, 32), 256, 0, stream>>>(vb, wv_b, nullptr, Vb, 1024, 1024);

  transpose64<<<dim3(32, 32), 256, 0, stream>>>(Vb, VTb);

  attn2<<<dim3(32, 16), 256, 0, stream>>>(Qb, Kb, VTb, maskbias, qmaskf, hatt);

  gemm_bt<0><<<dim3(8, 32), 256, 0, stream>>>(hatt, wo_b, nullptr, atto, 1024, 1024);

  add_ln<1, 0><<<4096, 256, 0, stream>>>(q, atto, g1, be1, h1b);

  gemm_bt<2><<<dim3(32, 32), 256, 0, stream>>>(h1b, w1_b, b1, ff1, 4096, 1024);
  gemm_bt<1><<<dim3(8, 32), 256, 0, stream>>>(ff1, w2_b, b2, ff2, 1024, 4096);

  add_ln<0, 1><<<4096, 256, 0, stream>>>(h1b, ff2, g2, be2, out);
}

// Round 3
// 415.955 us; speedup vs baseline: 1.1759x; 1.0902x over previous
//
#include <hip/hip_runtime.h>

typedef unsigned short u16;
typedef unsigned int u32;
typedef __attribute__((ext_vector_type(8))) __bf16 bf16x8;
typedef __attribute__((ext_vector_type(4))) float f32x4;
typedef __attribute__((ext_vector_type(16))) float f32x16;
typedef __attribute__((ext_vector_type(4))) unsigned short u16x4;
typedef __attribute__((ext_vector_type(8))) unsigned short u16x8;

#define LOG2E 1.44269504088896340736f

__device__ __forceinline__ u16 f2bf(float f) {
  union { float f; unsigned u; } c; c.f = f;
  unsigned r = c.u + 0x7FFFu + ((c.u >> 16) & 1u);
  return (u16)(r >> 16);
}
__device__ __forceinline__ float bf2f(u16 h) {
  union { unsigned u; float f; } c; c.u = ((unsigned)h) << 16;
  return c.f;
}

__device__ __forceinline__ void gload_lds16(const u16* g, u16* l) {
  __builtin_amdgcn_global_load_lds((const __attribute__((address_space(1))) unsigned int*)g,
                                   (__attribute__((address_space(3))) unsigned int*)l, 16, 0, 0);
}

// ---------------- fused f32 -> bf16 conversion (all 9 tensors, one launch) ----------------
__global__ __launch_bounds__(256) void cvt_all(
    const float* __restrict__ s0, const float* __restrict__ s1, const float* __restrict__ s2,
    const float* __restrict__ s3, const float* __restrict__ s4, const float* __restrict__ s5,
    const float* __restrict__ s6, const float* __restrict__ s7, const float* __restrict__ s8,
    u16* __restrict__ d0, u16* __restrict__ d1, u16* __restrict__ d2,
    u16* __restrict__ d3, u16* __restrict__ d4, u16* __restrict__ d5,
    u16* __restrict__ d6, u16* __restrict__ d7, u16* __restrict__ d8) {
  int i = blockIdx.x * 256 + threadIdx.x;
  if (i >= 6291456) return;
  const float* src; u16* dst; int off;
  if (i < 3145728) {
    if (i < 1048576)      { src = s0; dst = d0; off = 0; }
    else if (i < 2097152) { src = s1; dst = d1; off = 1048576; }
    else                  { src = s2; dst = d2; off = 2097152; }
  } else if (i < 4194304) {
    if (i < 3407872)      { src = s3; dst = d3; off = 3145728; }
    else if (i < 3670016) { src = s4; dst = d4; off = 3407872; }
    else if (i < 3932160) { src = s5; dst = d5; off = 3670016; }
    else                  { src = s6; dst = d6; off = 3932160; }
  } else {
    if (i < 5242880)      { src = s7; dst = d7; off = 4194304; }
    else                  { src = s8; dst = d8; off = 5242880; }
  }
  int j = i - off;
  f32x4 v = ((const f32x4*)src)[j];
  u16x4 o;
  o[0] = f2bf(v[0]); o[1] = f2bf(v[1]); o[2] = f2bf(v[2]); o[3] = f2bf(v[3]);
  ((u16x4*)dst)[j] = o;
}

// ---------------- mask expansion (bool/int32 autodetect) ----------------
__global__ void build_masks(const void* __restrict__ pm, float* __restrict__ maskbias,
                            float* __restrict__ qmask, int n) {
  __shared__ int sflag;
  if (threadIdx.x == 0) sflag = 0;
  __syncthreads();
  const unsigned* pw = (const unsigned*)pm;
  int nwords = n / 4;
  int local = 0;
  for (int i = threadIdx.x; i < nwords; i += blockDim.x)
    if (pw[i] > 1u) local = 1;
  if (local) atomicOr(&sflag, 1);
  __syncthreads();
  bool isbool = (sflag != 0);
  for (int i = threadIdx.x; i < n; i += blockDim.x) {
    int m = isbool ? (int)((const unsigned char*)pm)[i] : ((const int*)pm)[i];
    maskbias[i] = m ? 0.0f : -2e30f;
    qmask[i]    = m ? 1.0f : 0.0f;
  }
}

// ---------------- GEMM core: C[M,N] = act(A[M,K] @ W[N,K]^T + bias) -> bf16 ----------------
template<int EPI>
__device__ __forceinline__ void gemm_core(const u16* __restrict__ A, const u16* __restrict__ Bw,
                                          const float* __restrict__ bias, u16* __restrict__ C,
                                          int N, int K, int bn, int bm, int tid) {
  __shared__ u16 As[128 * 32];
  __shared__ u16 Bs[128 * 32];
  int wave = tid >> 6, lane = tid & 63;
  int l15 = lane & 15, l4 = lane >> 4;
  int wr = (wave >> 1) * 64, wc = (wave & 1) * 64;
  int mrow0 = bm * 128, ncol0 = bn * 128;
  int srow = lane >> 2;
  int scol = (lane & 3) * 8;

  f32x4 acc[4][4];
#pragma unroll
  for (int i = 0; i < 4; i++)
#pragma unroll
    for (int j = 0; j < 4; j++) acc[i][j] = (f32x4)0.0f;

  for (int k0 = 0; k0 < K; k0 += 32) {
#pragma unroll
    for (int c = 0; c < 2; c++) {
      int q = wave * 2 + c;
      gload_lds16(A  + (size_t)(mrow0 + q * 16 + srow) * K + k0 + scol, &As[q * 512]);
      gload_lds16(Bw + (size_t)(ncol0 + q * 16 + srow) * K + k0 + scol, &Bs[q * 512]);
    }
    __syncthreads();
    bf16x8 af[4], bfr[4];
#pragma unroll
    for (int mi = 0; mi < 4; mi++) af[mi]  = *(const bf16x8*)(&As[(wr + mi * 16 + l15) * 32 + l4 * 8]);
#pragma unroll
    for (int ni = 0; ni < 4; ni++) bfr[ni] = *(const bf16x8*)(&Bs[(wc + ni * 16 + l15) * 32 + l4 * 8]);
#pragma unroll
    for (int mi = 0; mi < 4; mi++)
#pragma unroll
      for (int ni = 0; ni < 4; ni++)
        acc[mi][ni] = __builtin_amdgcn_mfma_f32_16x16x32_bf16(af[mi], bfr[ni], acc[mi][ni], 0, 0, 0);
    __syncthreads();
  }

#pragma unroll
  for (int ni = 0; ni < 4; ni++) {
    int gcol = ncol0 + wc + ni * 16 + l15;
    float bv = (EPI > 0) ? bias[gcol] : 0.0f;
#pragma unroll
    for (int mi = 0; mi < 4; mi++) {
#pragma unroll
      for (int r = 0; r < 4; r++) {
        int grow = mrow0 + wr + mi * 16 + l4 * 4 + r;
        float v = acc[mi][ni][r] + bv;
        if (EPI == 2) v = 0.5f * v * (1.0f + erff(v * 0.70710678118654752f));
        C[(size_t)grow * N + gcol] = f2bf(v);
      }
    }
  }
}

template<int EPI>
__global__ __launch_bounds__(256) void gemm_bt(const u16* __restrict__ A, const u16* __restrict__ Bw,
                                               const float* __restrict__ bias, u16* __restrict__ C,
                                               int N, int K) {
  gemm_core<EPI>(A, Bw, bias, C, N, K, blockIdx.x, blockIdx.y, threadIdx.x);
}

__global__ __launch_bounds__(256) void gemm_qkv(const u16* __restrict__ qb, const u16* __restrict__ kb,
                                                const u16* __restrict__ vb,
                                                const u16* __restrict__ wq, const u16* __restrict__ wk,
                                                const u16* __restrict__ wv,
                                                u16* __restrict__ Qo, u16* __restrict__ Ko, u16* __restrict__ Vo) {
  const u16* A; const u16* W; u16* C;
  if (blockIdx.z == 0)      { A = qb; W = wq; C = Qo; }
  else if (blockIdx.z == 1) { A = kb; W = wk; C = Ko; }
  else                      { A = vb; W = wv; C = Vo; }
  gemm_core<0>(A, W, nullptr, C, 1024, 1024, blockIdx.x, blockIdx.y, threadIdx.x);
}

// ---------------- V transpose: [32][2048][64] -> [32][64][2048] ----------------
__global__ __launch_bounds__(256) void transpose64(const u16* __restrict__ in, u16* __restrict__ out) {
  int bh = blockIdx.y, tb = blockIdx.x;
  __shared__ u16 tile[64 * 72];
  int tid = threadIdx.x;
#pragma unroll
  for (int it = 0; it < 2; it++) {
    int idx = it * 256 + tid;
    int r = idx >> 3, c8 = (idx & 7) * 8;
    u16x8 v = *(const u16x8*)(in + ((size_t)bh * 2048 + tb * 64 + r) * 64 + c8);
    int byte = ((r * 72 + c8) * 2) ^ (((r >> 3) & 7) << 4);
    *(u16x8*)((char*)tile + byte) = v;
  }
  __syncthreads();
#pragma unroll
  for (int it = 0; it < 2; it++) {
    int idx = it * 256 + tid;
    int d = idx >> 3, t8 = (idx & 7) * 8;
    u16x8 o;
#pragma unroll
    for (int e = 0; e < 8; e++) {
      int t = t8 + e;
      int byte = ((t * 72 + d) * 2) ^ (((t >> 3) & 7) << 4);
      o[e] = *(const u16*)((const char*)tile + byte);
    }
    *(u16x8*)(out + ((size_t)bh * 64 + d) * 2048 + tb * 64 + t8) = o;
  }
}

// ---------------- flash attention v3: split-KV x4, swapped-QK, K prefetch ----------------
__global__ __launch_bounds__(256) void attn3(const u16* __restrict__ Q, const u16* __restrict__ Kg,
                                             const u16* __restrict__ VT,
                                             const float* __restrict__ maskbias,
                                             u16* __restrict__ O0, u16* __restrict__ O1,
                                             u16* __restrict__ O2, u16* __restrict__ O3,
                                             float* __restrict__ Ms, float* __restrict__ Ss) {
  const int T = 2048;
  int bh = blockIdx.x;
  int qt = blockIdx.y;
  int sp = blockIdx.z;
  int b = bh >> 4;
  const u16* Qh = Q  + (size_t)bh * T * 64;
  const u16* Kh = Kg + (size_t)bh * T * 64;
  const u16* Vh = VT + (size_t)bh * T * 64;   // [64][2048]
  u16* Oh = (sp == 0 ? O0 : sp == 1 ? O1 : sp == 2 ? O2 : O3) + (size_t)bh * T * 64;
  const float* mb = maskbias + b * T;
  int tid = threadIdx.x, w = tid >> 6, l = tid & 63;
  int q32 = l & 31, h = l >> 5;
  int qbase = qt * 128 + w * 32;
  const float C = 0.125f * LOG2E;

  bf16x8 qf[4];
#pragma unroll
  for (int dc = 0; dc < 4; dc++)
    qf[dc] = *(const bf16x8*)(Qh + (size_t)(qbase + q32) * 64 + dc * 16 + h * 8);

  f32x16 acc[2];
  acc[0] = (f32x16)0.0f; acc[1] = (f32x16)0.0f;
  float m_ = -3e30f, s_ = 0.0f;

  auto loadK = [&](bf16x8 (&buf)[2][4], int ktx) {
#pragma unroll
    for (int kvc = 0; kvc < 2; kvc++)
#pragma unroll
      for (int dc = 0; dc < 4; dc++)
        buf[kvc][dc] = *(const bf16x8*)(Kh + (size_t)(ktx * 64 + kvc * 32 + q32) * 64 + dc * 16 + h * 8);
  };

  auto body = [&](bf16x8 (&cur)[2][4], bf16x8 (&nxt)[2][4], int kt, int ktpre) {
    int kbase = kt * 64;
    f32x16 st[2];
    st[0] = (f32x16)0.0f; st[1] = (f32x16)0.0f;
#pragma unroll
    for (int kvc = 0; kvc < 2; kvc++)
#pragma unroll
      for (int dc = 0; dc < 4; dc++)
        st[kvc] = __builtin_amdgcn_mfma_f32_32x32x16_bf16(cur[kvc][dc], qf[dc], st[kvc], 0, 0, 0);

    loadK(nxt, ktpre);   // prefetch next K tile under softmax

    float p[32];
    float pmax = -3e30f;
#pragma unroll
    for (int kvc = 0; kvc < 2; kvc++) {
#pragma unroll
      for (int g = 0; g < 4; g++) {
        f32x4 mv = *(const f32x4*)(mb + kbase + kvc * 32 + g * 8 + h * 4);
#pragma unroll
        for (int r = 0; r < 4; r++) {
          float val = st[kvc][g * 4 + r] * C + mv[r];
          p[kvc * 16 + g * 4 + r] = val;
          pmax = fmaxf(pmax, val);
        }
      }
    }
    pmax = fmaxf(pmax, __shfl_xor(pmax, 32));

    if (__any(pmax - m_ > 8.0f)) {
      float mnew = fmaxf(m_, pmax);
      float fsc = __builtin_amdgcn_exp2f(m_ - mnew);
      s_ *= fsc;
      m_ = mnew;
#pragma unroll
      for (int g = 0; g < 4; g++)
#pragma unroll
        for (int r = 0; r < 4; r++) {
          float f = __shfl(fsc, g * 8 + h * 4 + r);
          acc[0][g * 4 + r] *= f;
          acc[1][g * 4 + r] *= f;
        }
    }

    float rsum = 0.0f;
    u32 wds[16];
#pragma unroll
    for (int i = 0; i < 16; i++) {
      float a = __builtin_amdgcn_exp2f(p[2 * i] - m_);
      float bq = __builtin_amdgcn_exp2f(p[2 * i + 1] - m_);
      rsum += a + bq;
      union { __bf16 h2[2]; u32 u; } cv;
      cv.h2[0] = (__bf16)a; cv.h2[1] = (__bf16)bq;
      wds[i] = cv.u;
    }
    rsum += __shfl_xor(rsum, 32);
    s_ += rsum;

    u32 sw[16];
#pragma unroll
    for (int i = 0; i < 16; i++) sw[i] = __shfl_xor(wds[i], 32);

#pragma unroll
    for (int kvc = 0; kvc < 2; kvc++) {
      int bse = kvc * 8;
      union { u32 u[4]; bf16x8 v; } pa0, pa1;
      pa0.u[0] = h ? sw[bse + 2] : wds[bse + 0];
      pa0.u[1] = h ? sw[bse + 3] : wds[bse + 1];
      pa0.u[2] = h ? wds[bse + 2] : sw[bse + 0];
      pa0.u[3] = h ? wds[bse + 3] : sw[bse + 1];
      pa1.u[0] = h ? sw[bse + 6] : wds[bse + 4];
      pa1.u[1] = h ? sw[bse + 7] : wds[bse + 5];
      pa1.u[2] = h ? wds[bse + 6] : sw[bse + 4];
      pa1.u[3] = h ? wds[bse + 7] : sw[bse + 5];
#pragma unroll
      for (int cl = 0; cl < 2; cl++) {
        bf16x8 pa = cl ? pa1.v : pa0.v;
        int cg = kvc * 2 + cl;
#pragma unroll
        for (int dblk = 0; dblk < 2; dblk++) {
          bf16x8 vf = *(const bf16x8*)(Vh + (size_t)(dblk * 32 + q32) * 2048 + kbase + cg * 16 + h * 8);
          acc[dblk] = __builtin_amdgcn_mfma_f32_32x32x16_bf16(pa, vf, acc[dblk], 0, 0, 0);
        }
      }
    }
  };

  int kt0 = sp * 8;
  bf16x8 kfA[2][4], kfB[2][4];
  loadK(kfA, kt0);
  for (int kk = 0; kk < 4; kk++) {
    int kt = kt0 + kk * 2;
    body(kfA, kfB, kt, kt + 1);
    body(kfB, kfA, kt + 1, (kt + 2) & 31);
  }

  // epilogue: store unnormalized partial O + (m, s) per query row
#pragma unroll
  for (int g = 0; g < 4; g++) {
#pragma unroll
    for (int r = 0; r < 4; r++) {
      int row = g * 8 + h * 4 + r;
#pragma unroll
      for (int dblk = 0; dblk < 2; dblk++)
        Oh[(size_t)(qbase + row) * 64 + dblk * 32 + q32] = f2bf(acc[dblk][g * 4 + r]);
    }
  }
  if (h == 0) {
    int ro = sp * 65536 + bh * 2048 + qbase + q32;
    Ms[ro] = m_;
    Ss[ro] = s_;
  }
}

// ---------------- split-KV combine ----------------
__global__ __launch_bounds__(256) void attn_combine(const u16* __restrict__ O0, const u16* __restrict__ O1,
                                                    const u16* __restrict__ O2, const u16* __restrict__ O3,
                                                    const float* __restrict__ Ms, const float* __restrict__ Ss,
                                                    const float* __restrict__ qmaskf, u16* __restrict__ out) {
  int idx = blockIdx.x * 256 + threadIdx.x;   // 8-elem chunk
  int row = idx >> 3;                         // bh*2048 + r
  int d8 = (idx & 7) * 8;
  int bh = row >> 11, r = row & 2047, b = bh >> 4;
  float m0 = Ms[row], m1 = Ms[65536 + row], m2 = Ms[131072 + row], m3 = Ms[196608 + row];
  float mstar = fmaxf(fmaxf(m0, m1), fmaxf(m2, m3));
  float w0 = __builtin_amdgcn_exp2f(m0 - mstar);
  float w1 = __builtin_amdgcn_exp2f(m1 - mstar);
  float w2 = __builtin_amdgcn_exp2f(m2 - mstar);
  float w3 = __builtin_amdgcn_exp2f(m3 - mstar);
  float den = w0 * Ss[row] + w1 * Ss[65536 + row] + w2 * Ss[131072 + row] + w3 * Ss[196608 + row];
  float scale = qmaskf[b * 2048 + r] / den;
  size_t base = (size_t)row * 64 + d8;
  u16x8 a0 = *(const u16x8*)(O0 + base);
  u16x8 a1 = *(const u16x8*)(O1 + base);
  u16x8 a2 = *(const u16x8*)(O2 + base);
  u16x8 a3 = *(const u16x8*)(O3 + base);
  u16x8 o;
#pragma unroll
  for (int e = 0; e < 8; e++)
    o[e] = f2bf((w0 * bf2f(a0[e]) + w1 * bf2f(a1[e]) + w2 * bf2f(a2[e]) + w3 * bf2f(a3[e])) * scale);
  *(u16x8*)(out + base) = o;
}

// ---------------- residual add + layernorm ----------------
template<int A_F32, int OUT_F32>
__global__ __launch_bounds__(256) void add_ln(const void* __restrict__ Ap, const u16* __restrict__ Bp,
                                              const float* __restrict__ g, const float* __restrict__ be,
                                              void* __restrict__ outp) {
  int row = blockIdx.x, tid = threadIdx.x;
  int lane = tid & 63, wave = tid >> 6;
  float x[4];
  if (A_F32) {
    f32x4 a = ((const f32x4*)((const float*)Ap + (size_t)row * 1024))[tid];
    u16x4 bu = ((const u16x4*)(Bp + (size_t)row * 1024))[tid];
#pragma unroll
    for (int j = 0; j < 4; j++) x[j] = a[j] + bf2f(bu[j]);
  } else {
    u16x4 au = ((const u16x4*)((const u16*)Ap + (size_t)row * 1024))[tid];
    u16x4 bu = ((const u16x4*)(Bp + (size_t)row * 1024))[tid];
#pragma unroll
    for (int j = 0; j < 4; j++) x[j] = bf2f(au[j]) + bf2f(bu[j]);
  }
  float s = x[0] + x[1] + x[2] + x[3];
  float q = x[0] * x[0] + x[1] * x[1] + x[2] * x[2] + x[3] * x[3];
#pragma unroll
  for (int m = 1; m < 64; m <<= 1) { s += __shfl_xor(s, m); q += __shfl_xor(q, m); }
  __shared__ float rs[4], rq[4];
  if (lane == 0) { rs[wave] = s; rq[wave] = q; }
  __syncthreads();
  float S = rs[0] + rs[1] + rs[2] + rs[3];
  float Qq = rq[0] + rq[1] + rq[2] + rq[3];
  float mean = S * (1.0f / 1024.0f);
  float var = Qq * (1.0f / 1024.0f) - mean * mean;
  float rstd = rsqrtf(var + 1e-5f);
  if (OUT_F32) {
    f32x4 y;
#pragma unroll
    for (int j = 0; j < 4; j++) { int col = tid * 4 + j; y[j] = (x[j] - mean) * rstd * g[col] + be[col]; }
    ((f32x4*)((float*)outp + (size_t)row * 1024))[tid] = y;
  } else {
    u16x4 y;
#pragma unroll
    for (int j = 0; j < 4; j++) { int col = tid * 4 + j; y[j] = f2bf((x[j] - mean) * rstd * g[col] + be[col]); }
    ((u16x4*)((u16*)outp + (size_t)row * 1024))[tid] = y;
  }
}

// ---------------- launch ----------------
extern "C" void kernel_launch(void* const* d_in, const int* in_sizes, int n_in,
                              void* d_out, int out_size, void* d_ws, size_t ws_size,
                              hipStream_t stream) {
  const float* q   = (const float*)d_in[0];
  const float* k   = (const float*)d_in[1];
  const float* v   = (const float*)d_in[2];
  const void*  pad = d_in[3];
  const float* Wq  = (const float*)d_in[4];
  const float* Wk  = (const float*)d_in[5];
  const float* Wv  = (const float*)d_in[6];
  const float* Wo  = (const float*)d_in[7];
  const float* W1  = (const float*)d_in[8];
  const float* b1  = (const float*)d_in[9];
  const float* W2  = (const float*)d_in[10];
  const float* b2  = (const float*)d_in[11];
  const float* g1  = (const float*)d_in[12];
  const float* be1 = (const float*)d_in[13];
  const float* g2  = (const float*)d_in[14];
  const float* be2 = (const float*)d_in[15];
  float* out = (float*)d_out;
  char* ws = (char*)d_ws;
  const size_t MB = 1u << 20;

  u16* wq_b = (u16*)(ws + 0 * MB);
  u16* wk_b = (u16*)(ws + 2 * MB);
  u16* wv_b = (u16*)(ws + 4 * MB);
  u16* wo_b = (u16*)(ws + 6 * MB);
  u16* w1_b = (u16*)(ws + 8 * MB);
  u16* w2_b = (u16*)(ws + 16 * MB);
  u16* qb   = (u16*)(ws + 24 * MB);
  u16* kb   = (u16*)(ws + 32 * MB);
  u16* vb   = (u16*)(ws + 40 * MB);
  u16* Qb   = (u16*)(ws + 48 * MB);
  u16* Kb   = (u16*)(ws + 56 * MB);
  u16* Vb   = (u16*)(ws + 64 * MB);
  u16* VTb  = (u16*)(ws + 72 * MB);
  u16* hatt = (u16*)(ws + 80 * MB);
  u16* atto = (u16*)(ws + 88 * MB);
  // attn split partials (live only between attn3 and combine; regions dead then)
  u16* Op0  = (u16*)(ws + 24 * MB);   // qb region
  u16* Op1  = (u16*)(ws + 32 * MB);   // kb region
  u16* Op2  = (u16*)(ws + 40 * MB);   // vb region
  u16* Op3  = (u16*)(ws + 64 * MB);   // Vb region (dead after transpose)
  float* Ms = (float*)(ws + 88 * MB); // atto region (atto written after combine)
  float* Ss = (float*)(ws + 89 * MB);
  u16* h1b  = (u16*)(ws + 24 * MB);   // after attn
  u16* ff1  = (u16*)(ws + 32 * MB);
  u16* ff2  = (u16*)(ws + 64 * MB);
  float* maskbias = (float*)(ws + 96 * MB);
  float* qmaskf   = (float*)(ws + 96 * MB + 16384);

  build_masks<<<1, 256, 0, stream>>>(pad, maskbias, qmaskf, in_sizes[3]);

  cvt_all<<<24576, 256, 0, stream>>>(q, k, v, Wq, Wk, Wv, Wo, W1, W2,
                                     qb, kb, vb, wq_b, wk_b, wv_b, wo_b, w1_b, w2_b);

  gemm_qkv<<<dim3(8, 32, 3), 256, 0, stream>>>(qb, kb, vb, wq_b, wk_b, wv_b, Qb, Kb, Vb);

  transpose64<<<dim3(32, 32), 256, 0, stream>>>(Vb, VTb);

  attn3<<<dim3(32, 16, 4), 256, 0, stream>>>(Qb, Kb, VTb, maskbias, Op0, Op1, Op2, Op3, Ms, Ss);

  attn_combine<<<2048, 256, 0, stream>>>(Op0, Op1, Op2, Op3, Ms, Ss, qmaskf, hatt);

  gemm_bt<0><<<dim3(8, 32), 256, 0, stream>>>(hatt, wo_b, nullptr, atto, 1024, 1024);

  add_ln<1, 0><<<4096, 256, 0, stream>>>(q, atto, g1, be1, h1b);

  gemm_bt<2><<<dim3(32, 32), 256, 0, stream>>>(h1b, w1_b, b1, ff1, 4096, 1024);
  gemm_bt<1><<<dim3(8, 32), 256, 0, stream>>>(ff1, w2_b, b2, ff2, 1024, 4096);

  add_ln<0, 1><<<4096, 256, 0, stream>>>(h1b, ff2, g2, be2, out);
}

// Round 4
// 333.721 us; speedup vs baseline: 1.4656x; 1.2464x over previous
//
#include <hip/hip_runtime.h>

typedef unsigned short u16;
typedef unsigned int u32;
typedef __attribute__((ext_vector_type(8))) __bf16 bf16x8;
typedef __attribute__((ext_vector_type(4))) float f32x4;
typedef __attribute__((ext_vector_type(16))) float f32x16;
typedef __attribute__((ext_vector_type(4))) unsigned short u16x4;
typedef __attribute__((ext_vector_type(8))) unsigned short u16x8;

#define LOG2E 1.44269504088896340736f

__device__ __forceinline__ u16 f2bf(float f) {
  union { float f; unsigned u; } c; c.f = f;
  unsigned r = c.u + 0x7FFFu + ((c.u >> 16) & 1u);
  return (u16)(r >> 16);
}
__device__ __forceinline__ float bf2f(u16 h) {
  union { unsigned u; float f; } c; c.u = ((unsigned)h) << 16;
  return c.f;
}

__device__ __forceinline__ void gload_lds16(const u16* g, u16* l) {
  __builtin_amdgcn_global_load_lds((const __attribute__((address_space(1))) unsigned int*)g,
                                   (__attribute__((address_space(3))) unsigned int*)l, 16, 0, 0);
}

// ---------------- fused f32 -> bf16 conversion (all 9 tensors, one launch) ----------------
__global__ __launch_bounds__(256) void cvt_all(
    const float* __restrict__ s0, const float* __restrict__ s1, const float* __restrict__ s2,
    const float* __restrict__ s3, const float* __restrict__ s4, const float* __restrict__ s5,
    const float* __restrict__ s6, const float* __restrict__ s7, const float* __restrict__ s8,
    u16* __restrict__ d0, u16* __restrict__ d1, u16* __restrict__ d2,
    u16* __restrict__ d3, u16* __restrict__ d4, u16* __restrict__ d5,
    u16* __restrict__ d6, u16* __restrict__ d7, u16* __restrict__ d8) {
  int i = blockIdx.x * 256 + threadIdx.x;
  if (i >= 6291456) return;
  const float* src; u16* dst; int off;
  if (i < 3145728) {
    if (i < 1048576)      { src = s0; dst = d0; off = 0; }
    else if (i < 2097152) { src = s1; dst = d1; off = 1048576; }
    else                  { src = s2; dst = d2; off = 2097152; }
  } else if (i < 4194304) {
    if (i < 3407872)      { src = s3; dst = d3; off = 3145728; }
    else if (i < 3670016) { src = s4; dst = d4; off = 3407872; }
    else if (i < 3932160) { src = s5; dst = d5; off = 3670016; }
    else                  { src = s6; dst = d6; off = 3932160; }
  } else {
    if (i < 5242880)      { src = s7; dst = d7; off = 4194304; }
    else                  { src = s8; dst = d8; off = 5242880; }
  }
  int j = i - off;
  f32x4 v = ((const f32x4*)src)[j];
  u16x4 o;
  o[0] = f2bf(v[0]); o[1] = f2bf(v[1]); o[2] = f2bf(v[2]); o[3] = f2bf(v[3]);
  ((u16x4*)dst)[j] = o;
}

// ---------------- mask expansion (bool/int32 autodetect) ----------------
__global__ void build_masks(const void* __restrict__ pm, float* __restrict__ maskbias,
                            float* __restrict__ qmask, int n) {
  __shared__ int sflag;
  if (threadIdx.x == 0) sflag = 0;
  __syncthreads();
  const unsigned* pw = (const unsigned*)pm;
  int nwords = n / 4;
  int local = 0;
  for (int i = threadIdx.x; i < nwords; i += blockDim.x)
    if (pw[i] > 1u) local = 1;
  if (local) atomicOr(&sflag, 1);
  __syncthreads();
  bool isbool = (sflag != 0);
  for (int i = threadIdx.x; i < n; i += blockDim.x) {
    int m = isbool ? (int)((const unsigned char*)pm)[i] : ((const int*)pm)[i];
    maskbias[i] = m ? 0.0f : -2e30f;
    qmask[i]    = m ? 1.0f : 0.0f;
  }
}

// ---------------- GEMM core: C[M,N] = act(A[M,K] @ W[N,K]^T + bias) -> bf16 ----------------
template<int EPI>
__device__ __forceinline__ void gemm_core(const u16* __restrict__ A, const u16* __restrict__ Bw,
                                          const float* __restrict__ bias, u16* __restrict__ C,
                                          int N, int K, int bn, int bm, int tid) {
  __shared__ u16 As[128 * 32];
  __shared__ u16 Bs[128 * 32];
  int wave = tid >> 6, lane = tid & 63;
  int l15 = lane & 15, l4 = lane >> 4;
  int wr = (wave >> 1) * 64, wc = (wave & 1) * 64;
  int mrow0 = bm * 128, ncol0 = bn * 128;
  int srow = lane >> 2;
  int scol = (lane & 3) * 8;

  f32x4 acc[4][4];
#pragma unroll
  for (int i = 0; i < 4; i++)
#pragma unroll
    for (int j = 0; j < 4; j++) acc[i][j] = (f32x4)0.0f;

  for (int k0 = 0; k0 < K; k0 += 32) {
#pragma unroll
    for (int c = 0; c < 2; c++) {
      int q = wave * 2 + c;
      gload_lds16(A  + (size_t)(mrow0 + q * 16 + srow) * K + k0 + scol, &As[q * 512]);
      gload_lds16(Bw + (size_t)(ncol0 + q * 16 + srow) * K + k0 + scol, &Bs[q * 512]);
    }
    __syncthreads();
    bf16x8 af[4], bfr[4];
#pragma unroll
    for (int mi = 0; mi < 4; mi++) af[mi]  = *(const bf16x8*)(&As[(wr + mi * 16 + l15) * 32 + l4 * 8]);
#pragma unroll
    for (int ni = 0; ni < 4; ni++) bfr[ni] = *(const bf16x8*)(&Bs[(wc + ni * 16 + l15) * 32 + l4 * 8]);
#pragma unroll
    for (int mi = 0; mi < 4; mi++)
#pragma unroll
      for (int ni = 0; ni < 4; ni++)
        acc[mi][ni] = __builtin_amdgcn_mfma_f32_16x16x32_bf16(af[mi], bfr[ni], acc[mi][ni], 0, 0, 0);
    __syncthreads();
  }

#pragma unroll
  for (int ni = 0; ni < 4; ni++) {
    int gcol = ncol0 + wc + ni * 16 + l15;
    float bv = (EPI > 0) ? bias[gcol] : 0.0f;
#pragma unroll
    for (int mi = 0; mi < 4; mi++) {
#pragma unroll
      for (int r = 0; r < 4; r++) {
        int grow = mrow0 + wr + mi * 16 + l4 * 4 + r;
        float v = acc[mi][ni][r] + bv;
        if (EPI == 2) v = 0.5f * v * (1.0f + erff(v * 0.70710678118654752f));
        C[(size_t)grow * N + gcol] = f2bf(v);
      }
    }
  }
}

template<int EPI>
__global__ __launch_bounds__(256) void gemm_bt(const u16* __restrict__ A, const u16* __restrict__ Bw,
                                               const float* __restrict__ bias, u16* __restrict__ C,
                                               int N, int K) {
  gemm_core<EPI>(A, Bw, bias, C, N, K, blockIdx.x, blockIdx.y, threadIdx.x);
}

__global__ __launch_bounds__(256) void gemm_qkv(const u16* __restrict__ qb, const u16* __restrict__ kb,
                                                const u16* __restrict__ vb,
                                                const u16* __restrict__ wq, const u16* __restrict__ wk,
                                                const u16* __restrict__ wv,
                                                u16* __restrict__ Qo, u16* __restrict__ Ko, u16* __restrict__ Vo) {
  const u16* A; const u16* W; u16* C;
  if (blockIdx.z == 0)      { A = qb; W = wq; C = Qo; }
  else if (blockIdx.z == 1) { A = kb; W = wk; C = Ko; }
  else                      { A = vb; W = wv; C = Vo; }
  gemm_core<0>(A, W, nullptr, C, 1024, 1024, blockIdx.x, blockIdx.y, threadIdx.x);
}

// ---------------- V transpose: [32][2048][64] -> [32][64][2048] ----------------
__global__ __launch_bounds__(256) void transpose64(const u16* __restrict__ in, u16* __restrict__ out) {
  int bh = blockIdx.y, tb = blockIdx.x;
  __shared__ u16 tile[64 * 72];
  int tid = threadIdx.x;
#pragma unroll
  for (int it = 0; it < 2; it++) {
    int idx = it * 256 + tid;
    int r = idx >> 3, c8 = (idx & 7) * 8;
    u16x8 v = *(const u16x8*)(in + ((size_t)bh * 2048 + tb * 64 + r) * 64 + c8);
    int byte = ((r * 72 + c8) * 2) ^ (((r >> 3) & 7) << 4);
    *(u16x8*)((char*)tile + byte) = v;
  }
  __syncthreads();
#pragma unroll
  for (int it = 0; it < 2; it++) {
    int idx = it * 256 + tid;
    int d = idx >> 3, t8 = (idx & 7) * 8;
    u16x8 o;
#pragma unroll
    for (int e = 0; e < 8; e++) {
      int t = t8 + e;
      int byte = ((t * 72 + d) * 2) ^ (((t >> 3) & 7) << 4);
      o[e] = *(const u16*)((const char*)tile + byte);
    }
    *(u16x8*)(out + ((size_t)bh * 64 + d) * 2048 + tb * 64 + t8) = o;
  }
}

// ---------------- flash attention v4: LDS-staged K/V, swapped-QK, split-KV x2 ----------------
__global__ __launch_bounds__(256, 4) void attn4(const u16* __restrict__ Q, const u16* __restrict__ Kg,
                                                const u16* __restrict__ VT,
                                                const float* __restrict__ maskbias,
                                                u16* __restrict__ O0, u16* __restrict__ O1,
                                                float* __restrict__ Ms, float* __restrict__ Ss) {
  const int T = 2048;
  int bh = blockIdx.x;
  int qt = blockIdx.y;
  int sp = blockIdx.z;
  int b = bh >> 4;
  const u16* Qh = Q  + (size_t)bh * T * 64;
  const u16* Kh = Kg + (size_t)bh * T * 64;
  const u16* Vh = VT + (size_t)bh * T * 64;   // [64][2048]
  u16* Oh = (sp ? O1 : O0) + (size_t)bh * T * 64;
  const float* mb = maskbias + b * T + sp * 1024;
  int tid = threadIdx.x, w = tid >> 6, l = tid & 63;
  int q32 = l & 31, h = l >> 5;
  int qbase = qt * 128 + w * 32;
  const float C = 0.125f * LOG2E;

  __shared__ u16 Ks[2][4096];   // [buf][64 kv rows x 64 d], 128B rows, XOR-swizzled content
  __shared__ u16 Vs[2][4096];   // [buf][64 d rows x 64 kv]

  // Q fragments (B-operand): lane holds Q[qbase+q32][dc*16 + h*8 + e]
  bf16x8 qf[4];
#pragma unroll
  for (int dc = 0; dc < 4; dc++)
    qf[dc] = *(const bf16x8*)(Qh + (size_t)(qbase + q32) * 64 + dc * 16 + h * 8);

  // per-lane pre-swizzled staging source pointers (rule-21: linear LDS dest, swizzled global src)
  int rl = l >> 3, ob = (l & 7) * 16;
  int osw = ob ^ (rl << 4);
  int r0 = w * 16 + rl, r1 = w * 16 + 8 + rl;
  const u16* pK0 = Kh + (size_t)(sp * 1024 + r0) * 64 + (osw >> 1);
  const u16* pK1 = Kh + (size_t)(sp * 1024 + r1) * 64 + (osw >> 1);
  const u16* pV0 = Vh + (size_t)r0 * 2048 + sp * 1024 + (osw >> 1);
  const u16* pV1 = Vh + (size_t)r1 * 2048 + sp * 1024 + (osw >> 1);
  u16* dK0 = &Ks[0][0] + (w * 16) * 64;
  u16* dK1 = &Ks[0][0] + (w * 16 + 8) * 64;
  u16* dV0 = &Vs[0][0] + (w * 16) * 64;
  u16* dV1 = &Vs[0][0] + (w * 16 + 8) * 64;

  auto stage = [&](int buf) {
    gload_lds16(pK0, dK0 + buf * 4096);
    gload_lds16(pK1, dK1 + buf * 4096);
    gload_lds16(pV0, dV0 + buf * 4096);
    gload_lds16(pV1, dV1 + buf * 4096);
    pK0 += 4096; pK1 += 4096; pV0 += 64; pV1 += 64;
  };

  f32x16 acc[2];
  acc[0] = (f32x16)0.0f; acc[1] = (f32x16)0.0f;
  float m_ = -3e30f, s_ = 0.0f;

  int swz = (q32 & 7) << 4;   // read-side XOR (byte)

  stage(0);
  for (int t = 0; t < 16; t++) {
    int cur = t & 1;
    __syncthreads();                 // compiler drains vmcnt before s_barrier -> buf[cur] ready
    if (t < 15) stage(cur ^ 1);      // async prefetch under compute
    const char* ksb = (const char*)(&Ks[0][0] + cur * 4096);
    const char* vsb = (const char*)(&Vs[0][0] + cur * 4096);

    // K fragments (A-operand) from LDS
    bf16x8 kf[2][4];
#pragma unroll
    for (int kvc = 0; kvc < 2; kvc++)
#pragma unroll
      for (int dc = 0; dc < 4; dc++)
        kf[kvc][dc] = *(const bf16x8*)(ksb + (kvc * 32 + q32) * 128 + ((dc * 32 + h * 16) ^ swz));

    f32x16 st[2];
    st[0] = (f32x16)0.0f; st[1] = (f32x16)0.0f;
#pragma unroll
    for (int kvc = 0; kvc < 2; kvc++)
#pragma unroll
      for (int dc = 0; dc < 4; dc++)
        st[kvc] = __builtin_amdgcn_mfma_f32_32x32x16_bf16(kf[kvc][dc], qf[dc], st[kvc], 0, 0, 0);

    // scale + mask, lane-local max over 32 kv values
    float p[32];
    float pmax = -3e30f;
#pragma unroll
    for (int kvc = 0; kvc < 2; kvc++) {
#pragma unroll
      for (int g = 0; g < 4; g++) {
        f32x4 mv = *(const f32x4*)(mb + t * 64 + kvc * 32 + g * 8 + h * 4);
#pragma unroll
        for (int r = 0; r < 4; r++) {
          float val = st[kvc][g * 4 + r] * C + mv[r];
          p[kvc * 16 + g * 4 + r] = val;
          pmax = fmaxf(pmax, val);
        }
      }
    }
    pmax = fmaxf(pmax, __shfl_xor(pmax, 32));

    if (__any(pmax - m_ > 8.0f)) {
      float mnew = fmaxf(m_, pmax);
      float fsc = __builtin_amdgcn_exp2f(m_ - mnew);
      s_ *= fsc;
      m_ = mnew;
#pragma unroll
      for (int g = 0; g < 4; g++)
#pragma unroll
        for (int r = 0; r < 4; r++) {
          float f = __shfl(fsc, g * 8 + h * 4 + r);
          acc[0][g * 4 + r] *= f;
          acc[1][g * 4 + r] *= f;
        }
    }

    float rsum = 0.0f;
    u32 wds[16];
#pragma unroll
    for (int i = 0; i < 16; i++) {
      float a = __builtin_amdgcn_exp2f(p[2 * i] - m_);
      float bq = __builtin_amdgcn_exp2f(p[2 * i + 1] - m_);
      rsum += a + bq;
      union { __bf16 h2[2]; u32 u; } cv;
      cv.h2[0] = (__bf16)a; cv.h2[1] = (__bf16)bq;
      wds[i] = cv.u;
    }
    rsum += __shfl_xor(rsum, 32);
    s_ += rsum;

#pragma unroll
    for (int kvc = 0; kvc < 2; kvc++) {
      int bse = kvc * 8;
      u32 sw0 = __shfl_xor(wds[bse + 0], 32), sw1 = __shfl_xor(wds[bse + 1], 32);
      u32 sw2 = __shfl_xor(wds[bse + 2], 32), sw3 = __shfl_xor(wds[bse + 3], 32);
      u32 sw4 = __shfl_xor(wds[bse + 4], 32), sw5 = __shfl_xor(wds[bse + 5], 32);
      u32 sw6 = __shfl_xor(wds[bse + 6], 32), sw7 = __shfl_xor(wds[bse + 7], 32);
      union { u32 u[4]; bf16x8 v; } pa0, pa1;
      pa0.u[0] = h ? sw2 : wds[bse + 0];
      pa0.u[1] = h ? sw3 : wds[bse + 1];
      pa0.u[2] = h ? wds[bse + 2] : sw0;
      pa0.u[3] = h ? wds[bse + 3] : sw1;
      pa1.u[0] = h ? sw6 : wds[bse + 4];
      pa1.u[1] = h ? sw7 : wds[bse + 5];
      pa1.u[2] = h ? wds[bse + 6] : sw4;
      pa1.u[3] = h ? wds[bse + 7] : sw5;
#pragma unroll
      for (int cl = 0; cl < 2; cl++) {
        bf16x8 pa = cl ? pa1.v : pa0.v;
        int cg = kvc * 2 + cl;
#pragma unroll
        for (int dblk = 0; dblk < 2; dblk++) {
          bf16x8 vf = *(const bf16x8*)(vsb + (dblk * 32 + q32) * 128 + ((cg * 32 + h * 16) ^ swz));
          acc[dblk] = __builtin_amdgcn_mfma_f32_32x32x16_bf16(pa, vf, acc[dblk], 0, 0, 0);
        }
      }
    }
  }

  // epilogue: store unnormalized partial O + (m, s) per query row
#pragma unroll
  for (int g = 0; g < 4; g++) {
#pragma unroll
    for (int r = 0; r < 4; r++) {
      int row = g * 8 + h * 4 + r;
#pragma unroll
      for (int dblk = 0; dblk < 2; dblk++)
        Oh[(size_t)(qbase + row) * 64 + dblk * 32 + q32] = f2bf(acc[dblk][g * 4 + r]);
    }
  }
  if (h == 0) {
    int ro = sp * 65536 + bh * 2048 + qbase + q32;
    Ms[ro] = m_;
    Ss[ro] = s_;
  }
}

// ---------------- split-KV combine (2 splits) ----------------
__global__ __launch_bounds__(256) void attn_combine(const u16* __restrict__ O0, const u16* __restrict__ O1,
                                                    const float* __restrict__ Ms, const float* __restrict__ Ss,
                                                    const float* __restrict__ qmaskf, u16* __restrict__ out) {
  int idx = blockIdx.x * 256 + threadIdx.x;   // 8-elem chunk
  int row = idx >> 3;                         // bh*2048 + r
  int d8 = (idx & 7) * 8;
  int bh = row >> 11, r = row & 2047, b = bh >> 4;
  float m0 = Ms[row], m1 = Ms[65536 + row];
  float mstar = fmaxf(m0, m1);
  float w0 = __builtin_amdgcn_exp2f(m0 - mstar);
  float w1 = __builtin_amdgcn_exp2f(m1 - mstar);
  float den = w0 * Ss[row] + w1 * Ss[65536 + row];
  float scale = qmaskf[b * 2048 + r] / den;
  size_t base = (size_t)row * 64 + d8;
  u16x8 a0 = *(const u16x8*)(O0 + base);
  u16x8 a1 = *(const u16x8*)(O1 + base);
  u16x8 o;
#pragma unroll
  for (int e = 0; e < 8; e++)
    o[e] = f2bf((w0 * bf2f(a0[e]) + w1 * bf2f(a1[e])) * scale);
  *(u16x8*)(out + base) = o;
}

// ---------------- residual add + layernorm ----------------
template<int A_F32, int OUT_F32>
__global__ __launch_bounds__(256) void add_ln(const void* __restrict__ Ap, const u16* __restrict__ Bp,
                                              const float* __restrict__ g, const float* __restrict__ be,
                                              void* __restrict__ outp) {
  int row = blockIdx.x, tid = threadIdx.x;
  int lane = tid & 63, wave = tid >> 6;
  float x[4];
  if (A_F32) {
    f32x4 a = ((const f32x4*)((const float*)Ap + (size_t)row * 1024))[tid];
    u16x4 bu = ((const u16x4*)(Bp + (size_t)row * 1024))[tid];
#pragma unroll
    for (int j = 0; j < 4; j++) x[j] = a[j] + bf2f(bu[j]);
  } else {
    u16x4 au = ((const u16x4*)((const u16*)Ap + (size_t)row * 1024))[tid];
    u16x4 bu = ((const u16x4*)(Bp + (size_t)row * 1024))[tid];
#pragma unroll
    for (int j = 0; j < 4; j++) x[j] = bf2f(au[j]) + bf2f(bu[j]);
  }
  float s = x[0] + x[1] + x[2] + x[3];
  float q = x[0] * x[0] + x[1] * x[1] + x[2] * x[2] + x[3] * x[3];
#pragma unroll
  for (int m = 1; m < 64; m <<= 1) { s += __shfl_xor(s, m); q += __shfl_xor(q, m); }
  __shared__ float rs[4], rq[4];
  if (lane == 0) { rs[wave] = s; rq[wave] = q; }
  __syncthreads();
  float S = rs[0] + rs[1] + rs[2] + rs[3];
  float Qq = rq[0] + rq[1] + rq[2] + rq[3];
  float mean = S * (1.0f / 1024.0f);
  float var = Qq * (1.0f / 1024.0f) - mean * mean;
  float rstd = rsqrtf(var + 1e-5f);
  if (OUT_F32) {
    f32x4 y;
#pragma unroll
    for (int j = 0; j < 4; j++) { int col = tid * 4 + j; y[j] = (x[j] - mean) * rstd * g[col] + be[col]; }
    ((f32x4*)((float*)outp + (size_t)row * 1024))[tid] = y;
  } else {
    u16x4 y;
#pragma unroll
    for (int j = 0; j < 4; j++) { int col = tid * 4 + j; y[j] = f2bf((x[j] - mean) * rstd * g[col] + be[col]); }
    ((u16x4*)((u16*)outp + (size_t)row * 1024))[tid] = y;
  }
}

// ---------------- launch ----------------
extern "C" void kernel_launch(void* const* d_in, const int* in_sizes, int n_in,
                              void* d_out, int out_size, void* d_ws, size_t ws_size,
                              hipStream_t stream) {
  const float* q   = (const float*)d_in[0];
  const float* k   = (const float*)d_in[1];
  const float* v   = (const float*)d_in[2];
  const void*  pad = d_in[3];
  const float* Wq  = (const float*)d_in[4];
  const float* Wk  = (const float*)d_in[5];
  const float* Wv  = (const float*)d_in[6];
  const float* Wo  = (const float*)d_in[7];
  const float* W1  = (const float*)d_in[8];
  const float* b1  = (const float*)d_in[9];
  const float* W2  = (const float*)d_in[10];
  const float* b2  = (const float*)d_in[11];
  const float* g1  = (const float*)d_in[12];
  const float* be1 = (const float*)d_in[13];
  const float* g2  = (const float*)d_in[14];
  const float* be2 = (const float*)d_in[15];
  float* out = (float*)d_out;
  char* ws = (char*)d_ws;
  const size_t MB = 1u << 20;

  u16* wq_b = (u16*)(ws + 0 * MB);
  u16* wk_b = (u16*)(ws + 2 * MB);
  u16* wv_b = (u16*)(ws + 4 * MB);
  u16* wo_b = (u16*)(ws + 6 * MB);
  u16* w1_b = (u16*)(ws + 8 * MB);
  u16* w2_b = (u16*)(ws + 16 * MB);
  u16* qb   = (u16*)(ws + 24 * MB);
  u16* kb   = (u16*)(ws + 32 * MB);
  u16* vb   = (u16*)(ws + 40 * MB);
  u16* Qb   = (u16*)(ws + 48 * MB);
  u16* Kb   = (u16*)(ws + 56 * MB);
  u16* Vb   = (u16*)(ws + 64 * MB);
  u16* VTb  = (u16*)(ws + 72 * MB);
  u16* hatt = (u16*)(ws + 80 * MB);
  u16* atto = (u16*)(ws + 88 * MB);
  // attn split partials (live only between attn4 and combine)
  u16* Op0  = (u16*)(ws + 24 * MB);   // qb region (dead after QKV gemms)
  u16* Op1  = (u16*)(ws + 32 * MB);   // kb region
  float* Ms = (float*)(ws + 88 * MB); // atto region (atto written after combine)
  float* Ss = (float*)(ws + 89 * MB);
  u16* h1b  = (u16*)(ws + 24 * MB);   // after attn combine consumed Op0
  u16* ff1  = (u16*)(ws + 32 * MB);
  u16* ff2  = (u16*)(ws + 64 * MB);
  float* maskbias = (float*)(ws + 96 * MB);
  float* qmaskf   = (float*)(ws + 96 * MB + 16384);

  build_masks<<<1, 256, 0, stream>>>(pad, maskbias, qmaskf, in_sizes[3]);

  cvt_all<<<24576, 256, 0, stream>>>(q, k, v, Wq, Wk, Wv, Wo, W1, W2,
                                     qb, kb, vb, wq_b, wk_b, wv_b, wo_b, w1_b, w2_b);

  gemm_qkv<<<dim3(8, 32, 3), 256, 0, stream>>>(qb, kb, vb, wq_b, wk_b, wv_b, Qb, Kb, Vb);

  transpose64<<<dim3(32, 32), 256, 0, stream>>>(Vb, VTb);

  attn4<<<dim3(32, 16, 2), 256, 0, stream>>>(Qb, Kb, VTb, maskbias, Op0, Op1, Ms, Ss);

  attn_combine<<<2048, 256, 0, stream>>>(Op0, Op1, Ms, Ss, qmaskf, hatt);

  gemm_bt<0><<<dim3(8, 32), 256, 0, stream>>>(hatt, wo_b, nullptr, atto, 1024, 1024);

  add_ln<1, 0><<<4096, 256, 0, stream>>>(q, atto, g1, be1, h1b);

  gemm_bt<2><<<dim3(32, 32), 256, 0, stream>>>(h1b, w1_b, b1, ff1, 4096, 1024);
  gemm_bt<1><<<dim3(8, 32), 256, 0, stream>>>(ff1, w2_b, b2, ff2, 1024, 4096);

  add_ln<0, 1><<<4096, 256, 0, stream>>>(h1b, ff2, g2, be2, out);
}

// Round 5
// 313.052 us; speedup vs baseline: 1.5624x; 1.0660x over previous
//
#include <hip/hip_runtime.h>

typedef unsigned short u16;
typedef unsigned int u32;
typedef __attribute__((ext_vector_type(8))) __bf16 bf16x8;
typedef __attribute__((ext_vector_type(4))) float f32x4;
typedef __attribute__((ext_vector_type(16))) float f32x16;
typedef __attribute__((ext_vector_type(4))) unsigned short u16x4;
typedef __attribute__((ext_vector_type(8))) unsigned short u16x8;

#define LOG2E 1.44269504088896340736f

__device__ __forceinline__ u16 f2bf(float f) {
  union { float f; unsigned u; } c; c.f = f;
  unsigned r = c.u + 0x7FFFu + ((c.u >> 16) & 1u);
  return (u16)(r >> 16);
}
__device__ __forceinline__ float bf2f(u16 h) {
  union { unsigned u; float f; } c; c.u = ((unsigned)h) << 16;
  return c.f;
}

__device__ __forceinline__ void gload_lds16(const u16* g, u16* l) {
  __builtin_amdgcn_global_load_lds((const __attribute__((address_space(1))) unsigned int*)g,
                                   (__attribute__((address_space(3))) unsigned int*)l, 16, 0, 0);
}

// ---------------- fused f32 -> bf16 conversion (all 9 tensors, one launch) ----------------
__global__ __launch_bounds__(256) void cvt_all(
    const float* __restrict__ s0, const float* __restrict__ s1, const float* __restrict__ s2,
    const float* __restrict__ s3, const float* __restrict__ s4, const float* __restrict__ s5,
    const float* __restrict__ s6, const float* __restrict__ s7, const float* __restrict__ s8,
    u16* __restrict__ d0, u16* __restrict__ d1, u16* __restrict__ d2,
    u16* __restrict__ d3, u16* __restrict__ d4, u16* __restrict__ d5,
    u16* __restrict__ d6, u16* __restrict__ d7, u16* __restrict__ d8) {
  int i = blockIdx.x * 256 + threadIdx.x;
  if (i >= 6291456) return;
  const float* src; u16* dst; int off;
  if (i < 3145728) {
    if (i < 1048576)      { src = s0; dst = d0; off = 0; }
    else if (i < 2097152) { src = s1; dst = d1; off = 1048576; }
    else                  { src = s2; dst = d2; off = 2097152; }
  } else if (i < 4194304) {
    if (i < 3407872)      { src = s3; dst = d3; off = 3145728; }
    else if (i < 3670016) { src = s4; dst = d4; off = 3407872; }
    else if (i < 3932160) { src = s5; dst = d5; off = 3670016; }
    else                  { src = s6; dst = d6; off = 3932160; }
  } else {
    if (i < 5242880)      { src = s7; dst = d7; off = 4194304; }
    else                  { src = s8; dst = d8; off = 5242880; }
  }
  int j = i - off;
  f32x4 v = ((const f32x4*)src)[j];
  u16x4 o;
  o[0] = f2bf(v[0]); o[1] = f2bf(v[1]); o[2] = f2bf(v[2]); o[3] = f2bf(v[3]);
  ((u16x4*)dst)[j] = o;
}

// ---------------- mask expansion (bool/int32 autodetect) ----------------
__global__ void build_masks(const void* __restrict__ pm, float* __restrict__ maskbias,
                            float* __restrict__ qmask, int n) {
  __shared__ int sflag;
  if (threadIdx.x == 0) sflag = 0;
  __syncthreads();
  const unsigned* pw = (const unsigned*)pm;
  int nwords = n / 4;
  int local = 0;
  for (int i = threadIdx.x; i < nwords; i += blockDim.x)
    if (pw[i] > 1u) local = 1;
  if (local) atomicOr(&sflag, 1);
  __syncthreads();
  bool isbool = (sflag != 0);
  for (int i = threadIdx.x; i < n; i += blockDim.x) {
    int m = isbool ? (int)((const unsigned char*)pm)[i] : ((const int*)pm)[i];
    maskbias[i] = m ? 0.0f : -2e30f;
    qmask[i]    = m ? 1.0f : 0.0f;
  }
}

// ---------------- GEMM core: C[M,N] = act(A[M,Klen]@W[N,Klen]^T + bias) -> bf16 ----------------
// Kstride = row stride of A and W (elements); Klen = K extent to accumulate.
template<int EPI>
__device__ __forceinline__ void gemm_core(const u16* __restrict__ A, const u16* __restrict__ Bw,
                                          const float* __restrict__ bias, u16* __restrict__ C,
                                          int N, int Kstride, int Klen, int bn, int bm, int tid) {
  __shared__ u16 As[128 * 32];
  __shared__ u16 Bs[128 * 32];
  int wave = tid >> 6, lane = tid & 63;
  int l15 = lane & 15, l4 = lane >> 4;
  int wr = (wave >> 1) * 64, wc = (wave & 1) * 64;
  int mrow0 = bm * 128, ncol0 = bn * 128;
  int srow = lane >> 2;
  int scol = (lane & 3) * 8;

  f32x4 acc[4][4];
#pragma unroll
  for (int i = 0; i < 4; i++)
#pragma unroll
    for (int j = 0; j < 4; j++) acc[i][j] = (f32x4)0.0f;

  for (int k0 = 0; k0 < Klen; k0 += 32) {
#pragma unroll
    for (int c = 0; c < 2; c++) {
      int q = wave * 2 + c;
      gload_lds16(A  + (size_t)(mrow0 + q * 16 + srow) * Kstride + k0 + scol, &As[q * 512]);
      gload_lds16(Bw + (size_t)(ncol0 + q * 16 + srow) * Kstride + k0 + scol, &Bs[q * 512]);
    }
    __syncthreads();
    bf16x8 af[4], bfr[4];
#pragma unroll
    for (int mi = 0; mi < 4; mi++) af[mi]  = *(const bf16x8*)(&As[(wr + mi * 16 + l15) * 32 + l4 * 8]);
#pragma unroll
    for (int ni = 0; ni < 4; ni++) bfr[ni] = *(const bf16x8*)(&Bs[(wc + ni * 16 + l15) * 32 + l4 * 8]);
#pragma unroll
    for (int mi = 0; mi < 4; mi++)
#pragma unroll
      for (int ni = 0; ni < 4; ni++)
        acc[mi][ni] = __builtin_amdgcn_mfma_f32_16x16x32_bf16(af[mi], bfr[ni], acc[mi][ni], 0, 0, 0);
    __syncthreads();
  }

#pragma unroll
  for (int ni = 0; ni < 4; ni++) {
    int gcol = ncol0 + wc + ni * 16 + l15;
    float bv = (EPI > 0) ? bias[gcol] : 0.0f;
#pragma unroll
    for (int mi = 0; mi < 4; mi++) {
#pragma unroll
      for (int r = 0; r < 4; r++) {
        int grow = mrow0 + wr + mi * 16 + l4 * 4 + r;
        float v = acc[mi][ni][r] + bv;
        if (EPI == 2) v = 0.5f * v * (1.0f + erff(v * 0.70710678118654752f));
        C[(size_t)grow * N + gcol] = f2bf(v);
      }
    }
  }
}

template<int EPI>
__global__ __launch_bounds__(256) void gemm_bt(const u16* __restrict__ A, const u16* __restrict__ Bw,
                                               const float* __restrict__ bias, u16* __restrict__ C,
                                               int N, int K) {
  gemm_core<EPI>(A, Bw, bias, C, N, K, K, blockIdx.x, blockIdx.y, threadIdx.x);
}

// split-K GEMM: blockIdx.z selects K-chunk of length Kc; writes bf16 partial at P + z*M*N
__global__ __launch_bounds__(256) void gemm_splitk(const u16* __restrict__ A, const u16* __restrict__ Bw,
                                                   u16* __restrict__ P, int N, int Kstride, int Kc) {
  int z = blockIdx.z;
  size_t M = (size_t)gridDim.y * 128;
  gemm_core<0>(A + (size_t)z * Kc, Bw + (size_t)z * Kc, nullptr,
               P + (size_t)z * M * N, N, Kstride, Kc, blockIdx.x, blockIdx.y, threadIdx.x);
}

__global__ __launch_bounds__(256) void gemm_qkv(const u16* __restrict__ qb, const u16* __restrict__ kb,
                                                const u16* __restrict__ vb,
                                                const u16* __restrict__ wq, const u16* __restrict__ wk,
                                                const u16* __restrict__ wv,
                                                u16* __restrict__ Qo, u16* __restrict__ Ko, u16* __restrict__ Vo) {
  const u16* A; const u16* W; u16* C;
  if (blockIdx.z == 0)      { A = qb; W = wq; C = Qo; }
  else if (blockIdx.z == 1) { A = kb; W = wk; C = Ko; }
  else                      { A = vb; W = wv; C = Vo; }
  gemm_core<0>(A, W, nullptr, C, 1024, 1024, 1024, blockIdx.x, blockIdx.y, threadIdx.x);
}

// ---------------- V transpose: [32][2048][64] -> [32][64][2048] ----------------
__global__ __launch_bounds__(256) void transpose64(const u16* __restrict__ in, u16* __restrict__ out) {
  int bh = blockIdx.y, tb = blockIdx.x;
  __shared__ u16 tile[64 * 72];
  int tid = threadIdx.x;
#pragma unroll
  for (int it = 0; it < 2; it++) {
    int idx = it * 256 + tid;
    int r = idx >> 3, c8 = (idx & 7) * 8;
    u16x8 v = *(const u16x8*)(in + ((size_t)bh * 2048 + tb * 64 + r) * 64 + c8);
    int byte = ((r * 72 + c8) * 2) ^ (((r >> 3) & 7) << 4);
    *(u16x8*)((char*)tile + byte) = v;
  }
  __syncthreads();
#pragma unroll
  for (int it = 0; it < 2; it++) {
    int idx = it * 256 + tid;
    int d = idx >> 3, t8 = (idx & 7) * 8;
    u16x8 o;
#pragma unroll
    for (int e = 0; e < 8; e++) {
      int t = t8 + e;
      int byte = ((t * 72 + d) * 2) ^ (((t >> 3) & 7) << 4);
      o[e] = *(const u16*)((const char*)tile + byte);
    }
    *(u16x8*)(out + ((size_t)bh * 64 + d) * 2048 + tb * 64 + t8) = o;
  }
}

// ---------------- flash attention v4: LDS-staged K/V, swapped-QK, split-KV x2 ----------------
__global__ __launch_bounds__(256, 4) void attn4(const u16* __restrict__ Q, const u16* __restrict__ Kg,
                                                const u16* __restrict__ VT,
                                                const float* __restrict__ maskbias,
                                                u16* __restrict__ O0, u16* __restrict__ O1,
                                                float* __restrict__ Ms, float* __restrict__ Ss) {
  const int T = 2048;
  int bh = blockIdx.x;
  int qt = blockIdx.y;
  int sp = blockIdx.z;
  int b = bh >> 4;
  const u16* Qh = Q  + (size_t)bh * T * 64;
  const u16* Kh = Kg + (size_t)bh * T * 64;
  const u16* Vh = VT + (size_t)bh * T * 64;   // [64][2048]
  u16* Oh = (sp ? O1 : O0) + (size_t)bh * T * 64;
  const float* mb = maskbias + b * T + sp * 1024;
  int tid = threadIdx.x, w = tid >> 6, l = tid & 63;
  int q32 = l & 31, h = l >> 5;
  int qbase = qt * 128 + w * 32;
  const float C = 0.125f * LOG2E;

  __shared__ u16 Ks[2][4096];
  __shared__ u16 Vs[2][4096];

  bf16x8 qf[4];
#pragma unroll
  for (int dc = 0; dc < 4; dc++)
    qf[dc] = *(const bf16x8*)(Qh + (size_t)(qbase + q32) * 64 + dc * 16 + h * 8);

  int rl = l >> 3, ob = (l & 7) * 16;
  int osw = ob ^ (rl << 4);
  int r0 = w * 16 + rl, r1 = w * 16 + 8 + rl;
  const u16* pK0 = Kh + (size_t)(sp * 1024 + r0) * 64 + (osw >> 1);
  const u16* pK1 = Kh + (size_t)(sp * 1024 + r1) * 64 + (osw >> 1);
  const u16* pV0 = Vh + (size_t)r0 * 2048 + sp * 1024 + (osw >> 1);
  const u16* pV1 = Vh + (size_t)r1 * 2048 + sp * 1024 + (osw >> 1);
  u16* dK0 = &Ks[0][0] + (w * 16) * 64;
  u16* dK1 = &Ks[0][0] + (w * 16 + 8) * 64;
  u16* dV0 = &Vs[0][0] + (w * 16) * 64;
  u16* dV1 = &Vs[0][0] + (w * 16 + 8) * 64;

  auto stage = [&](int buf) {
    gload_lds16(pK0, dK0 + buf * 4096);
    gload_lds16(pK1, dK1 + buf * 4096);
    gload_lds16(pV0, dV0 + buf * 4096);
    gload_lds16(pV1, dV1 + buf * 4096);
    pK0 += 4096; pK1 += 4096; pV0 += 64; pV1 += 64;
  };

  f32x16 acc[2];
  acc[0] = (f32x16)0.0f; acc[1] = (f32x16)0.0f;
  float m_ = -3e30f, s_ = 0.0f;

  int swz = (q32 & 7) << 4;

  stage(0);
  for (int t = 0; t < 16; t++) {
    int cur = t & 1;
    __syncthreads();
    if (t < 15) stage(cur ^ 1);
    const char* ksb = (const char*)(&Ks[0][0] + cur * 4096);
    const char* vsb = (const char*)(&Vs[0][0] + cur * 4096);

    bf16x8 kf[2][4];
#pragma unroll
    for (int kvc = 0; kvc < 2; kvc++)
#pragma unroll
      for (int dc = 0; dc < 4; dc++)
        kf[kvc][dc] = *(const bf16x8*)(ksb + (kvc * 32 + q32) * 128 + ((dc * 32 + h * 16) ^ swz));

    f32x16 st[2];
    st[0] = (f32x16)0.0f; st[1] = (f32x16)0.0f;
#pragma unroll
    for (int kvc = 0; kvc < 2; kvc++)
#pragma unroll
      for (int dc = 0; dc < 4; dc++)
        st[kvc] = __builtin_amdgcn_mfma_f32_32x32x16_bf16(kf[kvc][dc], qf[dc], st[kvc], 0, 0, 0);

    float p[32];
    float pmax = -3e30f;
#pragma unroll
    for (int kvc = 0; kvc < 2; kvc++) {
#pragma unroll
      for (int g = 0; g < 4; g++) {
        f32x4 mv = *(const f32x4*)(mb + t * 64 + kvc * 32 + g * 8 + h * 4);
#pragma unroll
        for (int r = 0; r < 4; r++) {
          float val = st[kvc][g * 4 + r] * C + mv[r];
          p[kvc * 16 + g * 4 + r] = val;
          pmax = fmaxf(pmax, val);
        }
      }
    }
    pmax = fmaxf(pmax, __shfl_xor(pmax, 32));

    if (__any(pmax - m_ > 8.0f)) {
      float mnew = fmaxf(m_, pmax);
      float fsc = __builtin_amdgcn_exp2f(m_ - mnew);
      s_ *= fsc;
      m_ = mnew;
#pragma unroll
      for (int g = 0; g < 4; g++)
#pragma unroll
        for (int r = 0; r < 4; r++) {
          float f = __shfl(fsc, g * 8 + h * 4 + r);
          acc[0][g * 4 + r] *= f;
          acc[1][g * 4 + r] *= f;
        }
    }

    float rsum = 0.0f;
    u32 wds[16];
#pragma unroll
    for (int i = 0; i < 16; i++) {
      float a = __builtin_amdgcn_exp2f(p[2 * i] - m_);
      float bq = __builtin_amdgcn_exp2f(p[2 * i + 1] - m_);
      rsum += a + bq;
      union { __bf16 h2[2]; u32 u; } cv;
      cv.h2[0] = (__bf16)a; cv.h2[1] = (__bf16)bq;
      wds[i] = cv.u;
    }
    rsum += __shfl_xor(rsum, 32);
    s_ += rsum;

#pragma unroll
    for (int kvc = 0; kvc < 2; kvc++) {
      int bse = kvc * 8;
      u32 sw0 = __shfl_xor(wds[bse + 0], 32), sw1 = __shfl_xor(wds[bse + 1], 32);
      u32 sw2 = __shfl_xor(wds[bse + 2], 32), sw3 = __shfl_xor(wds[bse + 3], 32);
      u32 sw4 = __shfl_xor(wds[bse + 4], 32), sw5 = __shfl_xor(wds[bse + 5], 32);
      u32 sw6 = __shfl_xor(wds[bse + 6], 32), sw7 = __shfl_xor(wds[bse + 7], 32);
      union { u32 u[4]; bf16x8 v; } pa0, pa1;
      pa0.u[0] = h ? sw2 : wds[bse + 0];
      pa0.u[1] = h ? sw3 : wds[bse + 1];
      pa0.u[2] = h ? wds[bse + 2] : sw0;
      pa0.u[3] = h ? wds[bse + 3] : sw1;
      pa1.u[0] = h ? sw6 : wds[bse + 4];
      pa1.u[1] = h ? sw7 : wds[bse + 5];
      pa1.u[2] = h ? wds[bse + 6] : sw4;
      pa1.u[3] = h ? wds[bse + 7] : sw5;
#pragma unroll
      for (int cl = 0; cl < 2; cl++) {
        bf16x8 pa = cl ? pa1.v : pa0.v;
        int cg = kvc * 2 + cl;
#pragma unroll
        for (int dblk = 0; dblk < 2; dblk++) {
          bf16x8 vf = *(const bf16x8*)(vsb + (dblk * 32 + q32) * 128 + ((cg * 32 + h * 16) ^ swz));
          acc[dblk] = __builtin_amdgcn_mfma_f32_32x32x16_bf16(pa, vf, acc[dblk], 0, 0, 0);
        }
      }
    }
  }

#pragma unroll
  for (int g = 0; g < 4; g++) {
#pragma unroll
    for (int r = 0; r < 4; r++) {
      int row = g * 8 + h * 4 + r;
#pragma unroll
      for (int dblk = 0; dblk < 2; dblk++)
        Oh[(size_t)(qbase + row) * 64 + dblk * 32 + q32] = f2bf(acc[dblk][g * 4 + r]);
    }
  }
  if (h == 0) {
    int ro = sp * 65536 + bh * 2048 + qbase + q32;
    Ms[ro] = m_;
    Ss[ro] = s_;
  }
}

// ---------------- split-KV combine (2 splits) ----------------
__global__ __launch_bounds__(256) void attn_combine(const u16* __restrict__ O0, const u16* __restrict__ O1,
                                                    const float* __restrict__ Ms, const float* __restrict__ Ss,
                                                    const float* __restrict__ qmaskf, u16* __restrict__ out) {
  int idx = blockIdx.x * 256 + threadIdx.x;
  int row = idx >> 3;
  int d8 = (idx & 7) * 8;
  int bh = row >> 11, r = row & 2047, b = bh >> 4;
  float m0 = Ms[row], m1 = Ms[65536 + row];
  float mstar = fmaxf(m0, m1);
  float w0 = __builtin_amdgcn_exp2f(m0 - mstar);
  float w1 = __builtin_amdgcn_exp2f(m1 - mstar);
  float den = w0 * Ss[row] + w1 * Ss[65536 + row];
  float scale = qmaskf[b * 2048 + r] / den;
  size_t base = (size_t)row * 64 + d8;
  u16x8 a0 = *(const u16x8*)(O0 + base);
  u16x8 a1 = *(const u16x8*)(O1 + base);
  u16x8 o;
#pragma unroll
  for (int e = 0; e < 8; e++)
    o[e] = f2bf((w0 * bf2f(a0[e]) + w1 * bf2f(a1[e])) * scale);
  *(u16x8*)(out + base) = o;
}

// ---------------- residual + split-K partial sum + (bias) + layernorm ----------------
// x = base(Ap) + sum_{z<NP} P[z] + (ADD_BIAS? bias : 0); out = LN(x)*g + be
template<int NP, int A_F32, int ADD_BIAS, int OUT_F32>
__global__ __launch_bounds__(256) void add_ln_multi(const void* __restrict__ Ap,
                                                    const u16* __restrict__ P0, const u16* __restrict__ P1,
                                                    const u16* __restrict__ P2, const u16* __restrict__ P3,
                                                    const float* __restrict__ bias,
                                                    const float* __restrict__ g, const float* __restrict__ be,
                                                    void* __restrict__ outp) {
  int row = blockIdx.x, tid = threadIdx.x;
  int lane = tid & 63, wave = tid >> 6;
  size_t rb = (size_t)row * 1024;
  float x[4];
  if (A_F32) {
    f32x4 a = ((const f32x4*)((const float*)Ap + rb))[tid];
#pragma unroll
    for (int j = 0; j < 4; j++) x[j] = a[j];
  } else {
    u16x4 au = ((const u16x4*)((const u16*)Ap + rb))[tid];
#pragma unroll
    for (int j = 0; j < 4; j++) x[j] = bf2f(au[j]);
  }
  {
    u16x4 p = ((const u16x4*)(P0 + rb))[tid];
#pragma unroll
    for (int j = 0; j < 4; j++) x[j] += bf2f(p[j]);
  }
  if (NP > 1) {
    u16x4 p = ((const u16x4*)(P1 + rb))[tid];
#pragma unroll
    for (int j = 0; j < 4; j++) x[j] += bf2f(p[j]);
  }
  if (NP > 2) {
    u16x4 p = ((const u16x4*)(P2 + rb))[tid];
#pragma unroll
    for (int j = 0; j < 4; j++) x[j] += bf2f(p[j]);
  }
  if (NP > 3) {
    u16x4 p = ((const u16x4*)(P3 + rb))[tid];
#pragma unroll
    for (int j = 0; j < 4; j++) x[j] += bf2f(p[j]);
  }
  if (ADD_BIAS) {
    f32x4 bv = ((const f32x4*)bias)[tid];
#pragma unroll
    for (int j = 0; j < 4; j++) x[j] += bv[j];
  }
  float s = x[0] + x[1] + x[2] + x[3];
  float q = x[0] * x[0] + x[1] * x[1] + x[2] * x[2] + x[3] * x[3];
#pragma unroll
  for (int m = 1; m < 64; m <<= 1) { s += __shfl_xor(s, m); q += __shfl_xor(q, m); }
  __shared__ float rs[4], rq[4];
  if (lane == 0) { rs[wave] = s; rq[wave] = q; }
  __syncthreads();
  float S = rs[0] + rs[1] + rs[2] + rs[3];
  float Qq = rq[0] + rq[1] + rq[2] + rq[3];
  float mean = S * (1.0f / 1024.0f);
  float var = Qq * (1.0f / 1024.0f) - mean * mean;
  float rstd = rsqrtf(var + 1e-5f);
  if (OUT_F32) {
    f32x4 y;
#pragma unroll
    for (int j = 0; j < 4; j++) { int col = tid * 4 + j; y[j] = (x[j] - mean) * rstd * g[col] + be[col]; }
    ((f32x4*)((float*)outp + rb))[tid] = y;
  } else {
    u16x4 y;
#pragma unroll
    for (int j = 0; j < 4; j++) { int col = tid * 4 + j; y[j] = f2bf((x[j] - mean) * rstd * g[col] + be[col]); }
    ((u16x4*)((u16*)outp + rb))[tid] = y;
  }
}

// ---------------- launch ----------------
extern "C" void kernel_launch(void* const* d_in, const int* in_sizes, int n_in,
                              void* d_out, int out_size, void* d_ws, size_t ws_size,
                              hipStream_t stream) {
  const float* q   = (const float*)d_in[0];
  const float* k   = (const float*)d_in[1];
  const float* v   = (const float*)d_in[2];
  const void*  pad = d_in[3];
  const float* Wq  = (const float*)d_in[4];
  const float* Wk  = (const float*)d_in[5];
  const float* Wv  = (const float*)d_in[6];
  const float* Wo  = (const float*)d_in[7];
  const float* W1  = (const float*)d_in[8];
  const float* b1  = (const float*)d_in[9];
  const float* W2  = (const float*)d_in[10];
  const float* b2  = (const float*)d_in[11];
  const float* g1  = (const float*)d_in[12];
  const float* be1 = (const float*)d_in[13];
  const float* g2  = (const float*)d_in[14];
  const float* be2 = (const float*)d_in[15];
  float* out = (float*)d_out;
  char* ws = (char*)d_ws;
  const size_t MB = 1u << 20;

  u16* wq_b = (u16*)(ws + 0 * MB);
  u16* wk_b = (u16*)(ws + 2 * MB);
  u16* wv_b = (u16*)(ws + 4 * MB);
  u16* wo_b = (u16*)(ws + 6 * MB);
  u16* w1_b = (u16*)(ws + 8 * MB);
  u16* w2_b = (u16*)(ws + 16 * MB);
  u16* qb   = (u16*)(ws + 24 * MB);
  u16* kb   = (u16*)(ws + 32 * MB);
  u16* vb   = (u16*)(ws + 40 * MB);
  u16* Qb   = (u16*)(ws + 48 * MB);
  u16* Kb   = (u16*)(ws + 56 * MB);
  u16* Vb   = (u16*)(ws + 64 * MB);
  u16* VTb  = (u16*)(ws + 72 * MB);
  u16* hatt = (u16*)(ws + 80 * MB);
  // liveness overlays
  u16* Op0  = (u16*)(ws + 24 * MB);   // qb dead after QKV
  u16* Op1  = (u16*)(ws + 32 * MB);   // kb dead
  float* Ms = (float*)(ws + 88 * MB);
  float* Ss = (float*)(ws + 89 * MB);
  u16* WP   = (u16*)(ws + 40 * MB);   // Wo split-K partials x2 (vb,Qb dead): 40-56
  u16* h1b  = (u16*)(ws + 24 * MB);   // Op0 dead after combine
  u16* ff1  = (u16*)(ws + 32 * MB);   // Op1/WP/Kb dead after LN1: 32-64 (32 MB)
  u16* Fp   = (u16*)(ws + 64 * MB);   // FFN2 split-K partials x4 (Vb,VTb,hatt,Ms/Ss dead): 64-96
  float* maskbias = (float*)(ws + 96 * MB);
  float* qmaskf   = (float*)(ws + 96 * MB + 16384);

  build_masks<<<1, 256, 0, stream>>>(pad, maskbias, qmaskf, in_sizes[3]);

  cvt_all<<<24576, 256, 0, stream>>>(q, k, v, Wq, Wk, Wv, Wo, W1, W2,
                                     qb, kb, vb, wq_b, wk_b, wv_b, wo_b, w1_b, w2_b);

  gemm_qkv<<<dim3(8, 32, 3), 256, 0, stream>>>(qb, kb, vb, wq_b, wk_b, wv_b, Qb, Kb, Vb);

  transpose64<<<dim3(32, 32), 256, 0, stream>>>(Vb, VTb);

  attn4<<<dim3(32, 16, 2), 256, 0, stream>>>(Qb, Kb, VTb, maskbias, Op0, Op1, Ms, Ss);

  attn_combine<<<2048, 256, 0, stream>>>(Op0, Op1, Ms, Ss, qmaskf, hatt);

  // Wo: split-K x2 (Kc=512), partials -> WP[2][4096][1024]
  gemm_splitk<<<dim3(8, 32, 2), 256, 0, stream>>>(hatt, wo_b, WP, 1024, 1024, 512);

  // LN1: q + WP0 + WP1 -> h1b (bf16)
  add_ln_multi<2, 1, 0, 0><<<4096, 256, 0, stream>>>(q, WP, WP + 4194304, nullptr, nullptr,
                                                     nullptr, g1, be1, h1b);

  // FFN1: h1 @ W1^T + b1, GELU -> ff1
  gemm_bt<2><<<dim3(32, 32), 256, 0, stream>>>(h1b, w1_b, b1, ff1, 4096, 1024);

  // FFN2: split-K x4 (Kc=1024), partials -> Fp[4][4096][1024]
  gemm_splitk<<<dim3(8, 32, 4), 256, 0, stream>>>(ff1, w2_b, Fp, 1024, 4096, 1024);

  // LN2: h1 + sum(Fp) + b2 -> out (f32)
  add_ln_multi<4, 0, 1, 1><<<4096, 256, 0, stream>>>(h1b, Fp, Fp + 4194304, Fp + 2 * 4194304,
                                                     Fp + 3 * 4194304, b2, g2, be2, out);
}

// Round 6
// 307.183 us; speedup vs baseline: 1.5922x; 1.0191x over previous
//
#include <hip/hip_runtime.h>

typedef unsigned short u16;
typedef unsigned int u32;
typedef __attribute__((ext_vector_type(8))) __bf16 bf16x8;
typedef __attribute__((ext_vector_type(4))) float f32x4;
typedef __attribute__((ext_vector_type(16))) float f32x16;
typedef __attribute__((ext_vector_type(4))) unsigned short u16x4;
typedef __attribute__((ext_vector_type(8))) unsigned short u16x8;

#define LOG2E 1.44269504088896340736f

__device__ __forceinline__ u16 f2bf(float f) {
  union { float f; unsigned u; } c; c.f = f;
  unsigned r = c.u + 0x7FFFu + ((c.u >> 16) & 1u);
  return (u16)(r >> 16);
}
__device__ __forceinline__ float bf2f(u16 h) {
  union { unsigned u; float f; } c; c.u = ((unsigned)h) << 16;
  return c.f;
}

__device__ __forceinline__ void gload_lds16(const u16* g, u16* l) {
  __builtin_amdgcn_global_load_lds((const __attribute__((address_space(1))) unsigned int*)g,
                                   (__attribute__((address_space(3))) unsigned int*)l, 16, 0, 0);
}

// fast exact GELU: erf via Abramowitz-Stegun 7.1.26 (|eps| <= 1.5e-7), exp via v_exp_f32
__device__ __forceinline__ float gelu_fast(float x) {
  float z = fabsf(x) * 0.70710678118654752f;
  float t = 1.0f / (1.0f + 0.3275911f * z);
  float poly = t * (0.254829592f + t * (-0.284496736f + t * (1.421413741f +
               t * (-1.453152027f + t * 1.061405429f))));
  float e = __builtin_amdgcn_exp2f(-z * z * LOG2E);
  float erfz = 1.0f - poly * e;
  float s = (x >= 0.0f) ? erfz : -erfz;
  return 0.5f * x * (1.0f + s);
}

// ---------------- fused f32 -> bf16 conversion (all 9 tensors, one launch) ----------------
__global__ __launch_bounds__(256) void cvt_all(
    const float* __restrict__ s0, const float* __restrict__ s1, const float* __restrict__ s2,
    const float* __restrict__ s3, const float* __restrict__ s4, const float* __restrict__ s5,
    const float* __restrict__ s6, const float* __restrict__ s7, const float* __restrict__ s8,
    u16* __restrict__ d0, u16* __restrict__ d1, u16* __restrict__ d2,
    u16* __restrict__ d3, u16* __restrict__ d4, u16* __restrict__ d5,
    u16* __restrict__ d6, u16* __restrict__ d7, u16* __restrict__ d8) {
  int i = blockIdx.x * 256 + threadIdx.x;
  if (i >= 6291456) return;
  const float* src; u16* dst; int off;
  if (i < 3145728) {
    if (i < 1048576)      { src = s0; dst = d0; off = 0; }
    else if (i < 2097152) { src = s1; dst = d1; off = 1048576; }
    else                  { src = s2; dst = d2; off = 2097152; }
  } else if (i < 4194304) {
    if (i < 3407872)      { src = s3; dst = d3; off = 3145728; }
    else if (i < 3670016) { src = s4; dst = d4; off = 3407872; }
    else if (i < 3932160) { src = s5; dst = d5; off = 3670016; }
    else                  { src = s6; dst = d6; off = 3932160; }
  } else {
    if (i < 5242880)      { src = s7; dst = d7; off = 4194304; }
    else                  { src = s8; dst = d8; off = 5242880; }
  }
  int j = i - off;
  f32x4 v = ((const f32x4*)src)[j];
  u16x4 o;
  o[0] = f2bf(v[0]); o[1] = f2bf(v[1]); o[2] = f2bf(v[2]); o[3] = f2bf(v[3]);
  ((u16x4*)dst)[j] = o;
}

// ---------------- mask expansion (bool/int32 autodetect) ----------------
__global__ void build_masks(const void* __restrict__ pm, float* __restrict__ maskbias,
                            float* __restrict__ qmask, int n) {
  __shared__ int sflag;
  if (threadIdx.x == 0) sflag = 0;
  __syncthreads();
  const unsigned* pw = (const unsigned*)pm;
  int nwords = n / 4;
  int local = 0;
  for (int i = threadIdx.x; i < nwords; i += blockDim.x)
    if (pw[i] > 1u) local = 1;
  if (local) atomicOr(&sflag, 1);
  __syncthreads();
  bool isbool = (sflag != 0);
  for (int i = threadIdx.x; i < n; i += blockDim.x) {
    int m = isbool ? (int)((const unsigned char*)pm)[i] : ((const int*)pm)[i];
    maskbias[i] = m ? 0.0f : -2e30f;
    qmask[i]    = m ? 1.0f : 0.0f;
  }
}

// ---------------- GEMM core v2: double-buffered prefetch + coalesced LDS-bounce epilogue ----
// C[M,N] = act(A[M,Klen] @ W[N,Klen]^T + bias) -> bf16
template<int EPI>
__device__ __forceinline__ void gemm_core(const u16* __restrict__ A, const u16* __restrict__ Bw,
                                          const float* __restrict__ bias, u16* __restrict__ C,
                                          int N, int Kstride, int Klen, int bn, int bm, int tid) {
  __shared__ u16 smem[2][8192];   // [buf][ A-tile 0..4095 | B-tile 4096..8191 ]
  int wave = tid >> 6, lane = tid & 63;
  int l15 = lane & 15, l4 = lane >> 4;
  int wr = (wave >> 1) * 64, wc = (wave & 1) * 64;
  int mrow0 = bm * 128, ncol0 = bn * 128;
  int srow = lane >> 2;
  int scol = (lane & 3) * 8;

  const u16* asrc0 = A  + (size_t)(mrow0 + (wave * 2 + 0) * 16 + srow) * Kstride + scol;
  const u16* asrc1 = A  + (size_t)(mrow0 + (wave * 2 + 1) * 16 + srow) * Kstride + scol;
  const u16* bsrc0 = Bw + (size_t)(ncol0 + (wave * 2 + 0) * 16 + srow) * Kstride + scol;
  const u16* bsrc1 = Bw + (size_t)(ncol0 + (wave * 2 + 1) * 16 + srow) * Kstride + scol;
  u16* ad0 = &smem[0][(wave * 2 + 0) * 512];
  u16* ad1 = &smem[0][(wave * 2 + 1) * 512];
  u16* bd0 = &smem[0][4096 + (wave * 2 + 0) * 512];
  u16* bd1 = &smem[0][4096 + (wave * 2 + 1) * 512];

  auto stage = [&](int buf, int k0) {
    gload_lds16(asrc0 + k0, ad0 + buf * 8192);
    gload_lds16(asrc1 + k0, ad1 + buf * 8192);
    gload_lds16(bsrc0 + k0, bd0 + buf * 8192);
    gload_lds16(bsrc1 + k0, bd1 + buf * 8192);
  };

  f32x4 acc[4][4];
#pragma unroll
  for (int i = 0; i < 4; i++)
#pragma unroll
    for (int j = 0; j < 4; j++) acc[i][j] = (f32x4)0.0f;

  int nsteps = Klen >> 5;
  stage(0, 0);
  for (int s = 0; s < nsteps; s++) {
    int cur = s & 1;
    __syncthreads();                     // vmcnt drain: buf[cur] ready; buf[cur^1] free
    if (s + 1 < nsteps) stage(cur ^ 1, (s + 1) << 5);   // prefetch under compute
    const u16* as = &smem[cur][0];
    const u16* bs = &smem[cur][4096];
    bf16x8 af[4], bfr[4];
#pragma unroll
    for (int mi = 0; mi < 4; mi++) af[mi]  = *(const bf16x8*)(as + (wr + mi * 16 + l15) * 32 + l4 * 8);
#pragma unroll
    for (int ni = 0; ni < 4; ni++) bfr[ni] = *(const bf16x8*)(bs + (wc + ni * 16 + l15) * 32 + l4 * 8);
#pragma unroll
    for (int mi = 0; mi < 4; mi++)
#pragma unroll
      for (int ni = 0; ni < 4; ni++)
        acc[mi][ni] = __builtin_amdgcn_mfma_f32_16x16x32_bf16(af[mi], bfr[ni], acc[mi][ni], 0, 0, 0);
  }

  // epilogue: bounce 64-row half-tiles through LDS ([64][136] u16, padded rows) -> u16x8 stores
  u16* ct = &smem[0][0];
  for (int p = 0; p < 2; p++) {
    __syncthreads();   // all LDS reads (K-loop or prev pass) done before overwrite
    if ((wave >> 1) == p) {
#pragma unroll
      for (int ni = 0; ni < 4; ni++) {
        int gcol = ncol0 + wc + ni * 16 + l15;
        float bv = (EPI > 0) ? bias[gcol] : 0.0f;
#pragma unroll
        for (int mi = 0; mi < 4; mi++) {
#pragma unroll
          for (int r = 0; r < 4; r++) {
            float v = acc[mi][ni][r] + bv;
            if (EPI == 2) v = gelu_fast(v);
            ct[(mi * 16 + l4 * 4 + r) * 136 + wc + ni * 16 + l15] = f2bf(v);
          }
        }
      }
    }
    __syncthreads();
    int lrow = tid >> 2, cq = tid & 3;
#pragma unroll
    for (int j = 0; j < 4; j++) {
      int col = cq * 8 + j * 32;
      u16x8 vv = *(const u16x8*)(ct + lrow * 136 + col);
      *(u16x8*)(C + (size_t)(mrow0 + p * 64 + lrow) * N + ncol0 + col) = vv;
    }
  }
}

template<int EPI>
__global__ __launch_bounds__(256) void gemm_bt(const u16* __restrict__ A, const u16* __restrict__ Bw,
                                               const float* __restrict__ bias, u16* __restrict__ C,
                                               int N, int K) {
  gemm_core<EPI>(A, Bw, bias, C, N, K, K, blockIdx.x, blockIdx.y, threadIdx.x);
}

// split-K GEMM: blockIdx.z selects K-chunk of length Kc; writes bf16 partial at P + z*M*N
__global__ __launch_bounds__(256) void gemm_splitk(const u16* __restrict__ A, const u16* __restrict__ Bw,
                                                   u16* __restrict__ P, int N, int Kstride, int Kc) {
  int z = blockIdx.z;
  size_t M = (size_t)gridDim.y * 128;
  gemm_core<0>(A + (size_t)z * Kc, Bw + (size_t)z * Kc, nullptr,
               P + (size_t)z * M * N, N, Kstride, Kc, blockIdx.x, blockIdx.y, threadIdx.x);
}

__global__ __launch_bounds__(256) void gemm_qkv(const u16* __restrict__ qb, const u16* __restrict__ kb,
                                                const u16* __restrict__ vb,
                                                const u16* __restrict__ wq, const u16* __restrict__ wk,
                                                const u16* __restrict__ wv,
                                                u16* __restrict__ Qo, u16* __restrict__ Ko, u16* __restrict__ Vo) {
  const u16* A; const u16* W; u16* C;
  if (blockIdx.z == 0)      { A = qb; W = wq; C = Qo; }
  else if (blockIdx.z == 1) { A = kb; W = wk; C = Ko; }
  else                      { A = vb; W = wv; C = Vo; }
  gemm_core<0>(A, W, nullptr, C, 1024, 1024, 1024, blockIdx.x, blockIdx.y, threadIdx.x);
}

// ---------------- V transpose: [32][2048][64] -> [32][64][2048] ----------------
__global__ __launch_bounds__(256) void transpose64(const u16* __restrict__ in, u16* __restrict__ out) {
  int bh = blockIdx.y, tb = blockIdx.x;
  __shared__ u16 tile[64 * 72];
  int tid = threadIdx.x;
#pragma unroll
  for (int it = 0; it < 2; it++) {
    int idx = it * 256 + tid;
    int r = idx >> 3, c8 = (idx & 7) * 8;
    u16x8 v = *(const u16x8*)(in + ((size_t)bh * 2048 + tb * 64 + r) * 64 + c8);
    int byte = ((r * 72 + c8) * 2) ^ (((r >> 3) & 7) << 4);
    *(u16x8*)((char*)tile + byte) = v;
  }
  __syncthreads();
#pragma unroll
  for (int it = 0; it < 2; it++) {
    int idx = it * 256 + tid;
    int d = idx >> 3, t8 = (idx & 7) * 8;
    u16x8 o;
#pragma unroll
    for (int e = 0; e < 8; e++) {
      int t = t8 + e;
      int byte = ((t * 72 + d) * 2) ^ (((t >> 3) & 7) << 4);
      o[e] = *(const u16*)((const char*)tile + byte);
    }
    *(u16x8*)(out + ((size_t)bh * 64 + d) * 2048 + tb * 64 + t8) = o;
  }
}

// ---------------- flash attention v4: LDS-staged K/V, swapped-QK, split-KV x2 ----------------
__global__ __launch_bounds__(256, 4) void attn4(const u16* __restrict__ Q, const u16* __restrict__ Kg,
                                                const u16* __restrict__ VT,
                                                const float* __restrict__ maskbias,
                                                u16* __restrict__ O0, u16* __restrict__ O1,
                                                float* __restrict__ Ms, float* __restrict__ Ss) {
  const int T = 2048;
  int bh = blockIdx.x;
  int qt = blockIdx.y;
  int sp = blockIdx.z;
  int b = bh >> 4;
  const u16* Qh = Q  + (size_t)bh * T * 64;
  const u16* Kh = Kg + (size_t)bh * T * 64;
  const u16* Vh = VT + (size_t)bh * T * 64;   // [64][2048]
  u16* Oh = (sp ? O1 : O0) + (size_t)bh * T * 64;
  const float* mb = maskbias + b * T + sp * 1024;
  int tid = threadIdx.x, w = tid >> 6, l = tid & 63;
  int q32 = l & 31, h = l >> 5;
  int qbase = qt * 128 + w * 32;
  const float C = 0.125f * LOG2E;

  __shared__ u16 Ks[2][4096];
  __shared__ u16 Vs[2][4096];

  bf16x8 qf[4];
#pragma unroll
  for (int dc = 0; dc < 4; dc++)
    qf[dc] = *(const bf16x8*)(Qh + (size_t)(qbase + q32) * 64 + dc * 16 + h * 8);

  int rl = l >> 3, ob = (l & 7) * 16;
  int osw = ob ^ (rl << 4);
  int r0 = w * 16 + rl, r1 = w * 16 + 8 + rl;
  const u16* pK0 = Kh + (size_t)(sp * 1024 + r0) * 64 + (osw >> 1);
  const u16* pK1 = Kh + (size_t)(sp * 1024 + r1) * 64 + (osw >> 1);
  const u16* pV0 = Vh + (size_t)r0 * 2048 + sp * 1024 + (osw >> 1);
  const u16* pV1 = Vh + (size_t)r1 * 2048 + sp * 1024 + (osw >> 1);
  u16* dK0 = &Ks[0][0] + (w * 16) * 64;
  u16* dK1 = &Ks[0][0] + (w * 16 + 8) * 64;
  u16* dV0 = &Vs[0][0] + (w * 16) * 64;
  u16* dV1 = &Vs[0][0] + (w * 16 + 8) * 64;

  auto stage = [&](int buf) {
    gload_lds16(pK0, dK0 + buf * 4096);
    gload_lds16(pK1, dK1 + buf * 4096);
    gload_lds16(pV0, dV0 + buf * 4096);
    gload_lds16(pV1, dV1 + buf * 4096);
    pK0 += 4096; pK1 += 4096; pV0 += 64; pV1 += 64;
  };

  f32x16 acc[2];
  acc[0] = (f32x16)0.0f; acc[1] = (f32x16)0.0f;
  float m_ = -3e30f, s_ = 0.0f;

  int swz = (q32 & 7) << 4;

  stage(0);
  for (int t = 0; t < 16; t++) {
    int cur = t & 1;
    __syncthreads();
    if (t < 15) stage(cur ^ 1);
    const char* ksb = (const char*)(&Ks[0][0] + cur * 4096);
    const char* vsb = (const char*)(&Vs[0][0] + cur * 4096);

    bf16x8 kf[2][4];
#pragma unroll
    for (int kvc = 0; kvc < 2; kvc++)
#pragma unroll
      for (int dc = 0; dc < 4; dc++)
        kf[kvc][dc] = *(const bf16x8*)(ksb + (kvc * 32 + q32) * 128 + ((dc * 32 + h * 16) ^ swz));

    f32x16 st[2];
    st[0] = (f32x16)0.0f; st[1] = (f32x16)0.0f;
#pragma unroll
    for (int kvc = 0; kvc < 2; kvc++)
#pragma unroll
      for (int dc = 0; dc < 4; dc++)
        st[kvc] = __builtin_amdgcn_mfma_f32_32x32x16_bf16(kf[kvc][dc], qf[dc], st[kvc], 0, 0, 0);

    float p[32];
    float pmax = -3e30f;
#pragma unroll
    for (int kvc = 0; kvc < 2; kvc++) {
#pragma unroll
      for (int g = 0; g < 4; g++) {
        f32x4 mv = *(const f32x4*)(mb + t * 64 + kvc * 32 + g * 8 + h * 4);
#pragma unroll
        for (int r = 0; r < 4; r++) {
          float val = st[kvc][g * 4 + r] * C + mv[r];
          p[kvc * 16 + g * 4 + r] = val;
          pmax = fmaxf(pmax, val);
        }
      }
    }
    pmax = fmaxf(pmax, __shfl_xor(pmax, 32));

    if (__any(pmax - m_ > 8.0f)) {
      float mnew = fmaxf(m_, pmax);
      float fsc = __builtin_amdgcn_exp2f(m_ - mnew);
      s_ *= fsc;
      m_ = mnew;
#pragma unroll
      for (int g = 0; g < 4; g++)
#pragma unroll
        for (int r = 0; r < 4; r++) {
          float f = __shfl(fsc, g * 8 + h * 4 + r);
          acc[0][g * 4 + r] *= f;
          acc[1][g * 4 + r] *= f;
        }
    }

    float rsum = 0.0f;
    u32 wds[16];
#pragma unroll
    for (int i = 0; i < 16; i++) {
      float a = __builtin_amdgcn_exp2f(p[2 * i] - m_);
      float bq = __builtin_amdgcn_exp2f(p[2 * i + 1] - m_);
      rsum += a + bq;
      union { __bf16 h2[2]; u32 u; } cv;
      cv.h2[0] = (__bf16)a; cv.h2[1] = (__bf16)bq;
      wds[i] = cv.u;
    }
    rsum += __shfl_xor(rsum, 32);
    s_ += rsum;

#pragma unroll
    for (int kvc = 0; kvc < 2; kvc++) {
      int bse = kvc * 8;
      u32 sw0 = __shfl_xor(wds[bse + 0], 32), sw1 = __shfl_xor(wds[bse + 1], 32);
      u32 sw2 = __shfl_xor(wds[bse + 2], 32), sw3 = __shfl_xor(wds[bse + 3], 32);
      u32 sw4 = __shfl_xor(wds[bse + 4], 32), sw5 = __shfl_xor(wds[bse + 5], 32);
      u32 sw6 = __shfl_xor(wds[bse + 6], 32), sw7 = __shfl_xor(wds[bse + 7], 32);
      union { u32 u[4]; bf16x8 v; } pa0, pa1;
      pa0.u[0] = h ? sw2 : wds[bse + 0];
      pa0.u[1] = h ? sw3 : wds[bse + 1];
      pa0.u[2] = h ? wds[bse + 2] : sw0;
      pa0.u[3] = h ? wds[bse + 3] : sw1;
      pa1.u[0] = h ? sw6 : wds[bse + 4];
      pa1.u[1] = h ? sw7 : wds[bse + 5];
      pa1.u[2] = h ? wds[bse + 6] : sw4;
      pa1.u[3] = h ? wds[bse + 7] : sw5;
#pragma unroll
      for (int cl = 0; cl < 2; cl++) {
        bf16x8 pa = cl ? pa1.v : pa0.v;
        int cg = kvc * 2 + cl;
#pragma unroll
        for (int dblk = 0; dblk < 2; dblk++) {
          bf16x8 vf = *(const bf16x8*)(vsb + (dblk * 32 + q32) * 128 + ((cg * 32 + h * 16) ^ swz));
          acc[dblk] = __builtin_amdgcn_mfma_f32_32x32x16_bf16(pa, vf, acc[dblk], 0, 0, 0);
        }
      }
    }
  }

#pragma unroll
  for (int g = 0; g < 4; g++) {
#pragma unroll
    for (int r = 0; r < 4; r++) {
      int row = g * 8 + h * 4 + r;
#pragma unroll
      for (int dblk = 0; dblk < 2; dblk++)
        Oh[(size_t)(qbase + row) * 64 + dblk * 32 + q32] = f2bf(acc[dblk][g * 4 + r]);
    }
  }
  if (h == 0) {
    int ro = sp * 65536 + bh * 2048 + qbase + q32;
    Ms[ro] = m_;
    Ss[ro] = s_;
  }
}

// ---------------- split-KV combine (2 splits) ----------------
__global__ __launch_bounds__(256) void attn_combine(const u16* __restrict__ O0, const u16* __restrict__ O1,
                                                    const float* __restrict__ Ms, const float* __restrict__ Ss,
                                                    const float* __restrict__ qmaskf, u16* __restrict__ out) {
  int idx = blockIdx.x * 256 + threadIdx.x;
  int row = idx >> 3;
  int d8 = (idx & 7) * 8;
  int bh = row >> 11, r = row & 2047, b = bh >> 4;
  float m0 = Ms[row], m1 = Ms[65536 + row];
  float mstar = fmaxf(m0, m1);
  float w0 = __builtin_amdgcn_exp2f(m0 - mstar);
  float w1 = __builtin_amdgcn_exp2f(m1 - mstar);
  float den = w0 * Ss[row] + w1 * Ss[65536 + row];
  float scale = qmaskf[b * 2048 + r] / den;
  size_t base = (size_t)row * 64 + d8;
  u16x8 a0 = *(const u16x8*)(O0 + base);
  u16x8 a1 = *(const u16x8*)(O1 + base);
  u16x8 o;
#pragma unroll
  for (int e = 0; e < 8; e++)
    o[e] = f2bf((w0 * bf2f(a0[e]) + w1 * bf2f(a1[e])) * scale);
  *(u16x8*)(out + base) = o;
}

// ---------------- residual + split-K partial sum + (bias) + layernorm ----------------
template<int NP, int A_F32, int ADD_BIAS, int OUT_F32>
__global__ __launch_bounds__(256) void add_ln_multi(const void* __restrict__ Ap,
                                                    const u16* __restrict__ P0, const u16* __restrict__ P1,
                                                    const u16* __restrict__ P2, const u16* __restrict__ P3,
                                                    const float* __restrict__ bias,
                                                    const float* __restrict__ g, const float* __restrict__ be,
                                                    void* __restrict__ outp) {
  int row = blockIdx.x, tid = threadIdx.x;
  int lane = tid & 63, wave = tid >> 6;
  size_t rb = (size_t)row * 1024;
  float x[4];
  if (A_F32) {
    f32x4 a = ((const f32x4*)((const float*)Ap + rb))[tid];
#pragma unroll
    for (int j = 0; j < 4; j++) x[j] = a[j];
  } else {
    u16x4 au = ((const u16x4*)((const u16*)Ap + rb))[tid];
#pragma unroll
    for (int j = 0; j < 4; j++) x[j] = bf2f(au[j]);
  }
  {
    u16x4 p = ((const u16x4*)(P0 + rb))[tid];
#pragma unroll
    for (int j = 0; j < 4; j++) x[j] += bf2f(p[j]);
  }
  if (NP > 1) {
    u16x4 p = ((const u16x4*)(P1 + rb))[tid];
#pragma unroll
    for (int j = 0; j < 4; j++) x[j] += bf2f(p[j]);
  }
  if (NP > 2) {
    u16x4 p = ((const u16x4*)(P2 + rb))[tid];
#pragma unroll
    for (int j = 0; j < 4; j++) x[j] += bf2f(p[j]);
  }
  if (NP > 3) {
    u16x4 p = ((const u16x4*)(P3 + rb))[tid];
#pragma unroll
    for (int j = 0; j < 4; j++) x[j] += bf2f(p[j]);
  }
  if (ADD_BIAS) {
    f32x4 bv = ((const f32x4*)bias)[tid];
#pragma unroll
    for (int j = 0; j < 4; j++) x[j] += bv[j];
  }
  float s = x[0] + x[1] + x[2] + x[3];
  float q = x[0] * x[0] + x[1] * x[1] + x[2] * x[2] + x[3] * x[3];
#pragma unroll
  for (int m = 1; m < 64; m <<= 1) { s += __shfl_xor(s, m); q += __shfl_xor(q, m); }
  __shared__ float rs[4], rq[4];
  if (lane == 0) { rs[wave] = s; rq[wave] = q; }
  __syncthreads();
  float S = rs[0] + rs[1] + rs[2] + rs[3];
  float Qq = rq[0] + rq[1] + rq[2] + rq[3];
  float mean = S * (1.0f / 1024.0f);
  float var = Qq * (1.0f / 1024.0f) - mean * mean;
  float rstd = rsqrtf(var + 1e-5f);
  if (OUT_F32) {
    f32x4 y;
#pragma unroll
    for (int j = 0; j < 4; j++) { int col = tid * 4 + j; y[j] = (x[j] - mean) * rstd * g[col] + be[col]; }
    ((f32x4*)((float*)outp + rb))[tid] = y;
  } else {
    u16x4 y;
#pragma unroll
    for (int j = 0; j < 4; j++) { int col = tid * 4 + j; y[j] = f2bf((x[j] - mean) * rstd * g[col] + be[col]); }
    ((u16x4*)((u16*)outp + rb))[tid] = y;
  }
}

// ---------------- launch ----------------
extern "C" void kernel_launch(void* const* d_in, const int* in_sizes, int n_in,
                              void* d_out, int out_size, void* d_ws, size_t ws_size,
                              hipStream_t stream) {
  const float* q   = (const float*)d_in[0];
  const float* k   = (const float*)d_in[1];
  const float* v   = (const float*)d_in[2];
  const void*  pad = d_in[3];
  const float* Wq  = (const float*)d_in[4];
  const float* Wk  = (const float*)d_in[5];
  const float* Wv  = (const float*)d_in[6];
  const float* Wo  = (const float*)d_in[7];
  const float* W1  = (const float*)d_in[8];
  const float* b1  = (const float*)d_in[9];
  const float* W2  = (const float*)d_in[10];
  const float* b2  = (const float*)d_in[11];
  const float* g1  = (const float*)d_in[12];
  const float* be1 = (const float*)d_in[13];
  const float* g2  = (const float*)d_in[14];
  const float* be2 = (const float*)d_in[15];
  float* out = (float*)d_out;
  char* ws = (char*)d_ws;
  const size_t MB = 1u << 20;

  u16* wq_b = (u16*)(ws + 0 * MB);
  u16* wk_b = (u16*)(ws + 2 * MB);
  u16* wv_b = (u16*)(ws + 4 * MB);
  u16* wo_b = (u16*)(ws + 6 * MB);
  u16* w1_b = (u16*)(ws + 8 * MB);
  u16* w2_b = (u16*)(ws + 16 * MB);
  u16* qb   = (u16*)(ws + 24 * MB);
  u16* kb   = (u16*)(ws + 32 * MB);
  u16* vb   = (u16*)(ws + 40 * MB);
  u16* Qb   = (u16*)(ws + 48 * MB);
  u16* Kb   = (u16*)(ws + 56 * MB);
  u16* Vb   = (u16*)(ws + 64 * MB);
  u16* VTb  = (u16*)(ws + 72 * MB);
  u16* hatt = (u16*)(ws + 80 * MB);
  // liveness overlays
  u16* Op0  = (u16*)(ws + 24 * MB);   // qb dead after QKV
  u16* Op1  = (u16*)(ws + 32 * MB);   // kb dead
  float* Ms = (float*)(ws + 88 * MB);
  float* Ss = (float*)(ws + 89 * MB);
  u16* WP   = (u16*)(ws + 40 * MB);   // Wo split-K partials x2 (vb,Qb dead): 40-56
  u16* h1b  = (u16*)(ws + 24 * MB);   // Op0 dead after combine
  u16* ff1  = (u16*)(ws + 32 * MB);   // Op1/WP/Kb dead after LN1: 32-64 (32 MB)
  u16* Fp   = (u16*)(ws + 64 * MB);   // FFN2 split-K partials x4: 64-96
  float* maskbias = (float*)(ws + 96 * MB);
  float* qmaskf   = (float*)(ws + 96 * MB + 16384);

  build_masks<<<1, 256, 0, stream>>>(pad, maskbias, qmaskf, in_sizes[3]);

  cvt_all<<<24576, 256, 0, stream>>>(q, k, v, Wq, Wk, Wv, Wo, W1, W2,
                                     qb, kb, vb, wq_b, wk_b, wv_b, wo_b, w1_b, w2_b);

  gemm_qkv<<<dim3(8, 32, 3), 256, 0, stream>>>(qb, kb, vb, wq_b, wk_b, wv_b, Qb, Kb, Vb);

  transpose64<<<dim3(32, 32), 256, 0, stream>>>(Vb, VTb);

  attn4<<<dim3(32, 16, 2), 256, 0, stream>>>(Qb, Kb, VTb, maskbias, Op0, Op1, Ms, Ss);

  attn_combine<<<2048, 256, 0, stream>>>(Op0, Op1, Ms, Ss, qmaskf, hatt);

  // Wo: split-K x2 (Kc=512), partials -> WP[2][4096][1024]
  gemm_splitk<<<dim3(8, 32, 2), 256, 0, stream>>>(hatt, wo_b, WP, 1024, 1024, 512);

  // LN1: q + WP0 + WP1 -> h1b (bf16)
  add_ln_multi<2, 1, 0, 0><<<4096, 256, 0, stream>>>(q, WP, WP + 4194304, nullptr, nullptr,
                                                     nullptr, g1, be1, h1b);

  // FFN1: h1 @ W1^T + b1, GELU -> ff1
  gemm_bt<2><<<dim3(32, 32), 256, 0, stream>>>(h1b, w1_b, b1, ff1, 4096, 1024);

  // FFN2: split-K x4 (Kc=1024), partials -> Fp[4][4096][1024]
  gemm_splitk<<<dim3(8, 32, 4), 256, 0, stream>>>(ff1, w2_b, Fp, 1024, 4096, 1024);

  // LN2: h1 + sum(Fp) + b2 -> out (f32)
  add_ln_multi<4, 0, 1, 1><<<4096, 256, 0, stream>>>(h1b, Fp, Fp + 4194304, Fp + 2 * 4194304,
                                                     Fp + 3 * 4194304, b2, g2, be2, out);
}

// Round 7
// 302.701 us; speedup vs baseline: 1.6158x; 1.0148x over previous
//
#include <hip/hip_runtime.h>

typedef unsigned short u16;
typedef unsigned int u32;
typedef __attribute__((ext_vector_type(8))) __bf16 bf16x8;
typedef __attribute__((ext_vector_type(4))) float f32x4;
typedef __attribute__((ext_vector_type(16))) float f32x16;
typedef __attribute__((ext_vector_type(4))) unsigned short u16x4;
typedef __attribute__((ext_vector_type(8))) unsigned short u16x8;

#define LOG2E 1.44269504088896340736f

__device__ __forceinline__ u16 f2bf(float f) {
  union { float f; unsigned u; } c; c.f = f;
  unsigned r = c.u + 0x7FFFu + ((c.u >> 16) & 1u);
  return (u16)(r >> 16);
}
__device__ __forceinline__ float bf2f(u16 h) {
  union { unsigned u; float f; } c; c.u = ((unsigned)h) << 16;
  return c.f;
}

__device__ __forceinline__ void gload_lds16(const u16* g, u16* l) {
  __builtin_amdgcn_global_load_lds((const __attribute__((address_space(1))) unsigned int*)g,
                                   (__attribute__((address_space(3))) unsigned int*)l, 16, 0, 0);
}

// fast exact GELU: erf via Abramowitz-Stegun 7.1.26 (|eps| <= 1.5e-7), exp via v_exp_f32
__device__ __forceinline__ float gelu_fast(float x) {
  float z = fabsf(x) * 0.70710678118654752f;
  float t = 1.0f / (1.0f + 0.3275911f * z);
  float poly = t * (0.254829592f + t * (-0.284496736f + t * (1.421413741f +
               t * (-1.453152027f + t * 1.061405429f))));
  float e = __builtin_amdgcn_exp2f(-z * z * LOG2E);
  float erfz = 1.0f - poly * e;
  float s = (x >= 0.0f) ? erfz : -erfz;
  return 0.5f * x * (1.0f + s);
}

// ---------------- fused f32 -> bf16 conversion (all 9 tensors, one launch) ----------------
__global__ __launch_bounds__(256) void cvt_all(
    const float* __restrict__ s0, const float* __restrict__ s1, const float* __restrict__ s2,
    const float* __restrict__ s3, const float* __restrict__ s4, const float* __restrict__ s5,
    const float* __restrict__ s6, const float* __restrict__ s7, const float* __restrict__ s8,
    u16* __restrict__ d0, u16* __restrict__ d1, u16* __restrict__ d2,
    u16* __restrict__ d3, u16* __restrict__ d4, u16* __restrict__ d5,
    u16* __restrict__ d6, u16* __restrict__ d7, u16* __restrict__ d8) {
  int i = blockIdx.x * 256 + threadIdx.x;
  if (i >= 6291456) return;
  const float* src; u16* dst; int off;
  if (i < 3145728) {
    if (i < 1048576)      { src = s0; dst = d0; off = 0; }
    else if (i < 2097152) { src = s1; dst = d1; off = 1048576; }
    else                  { src = s2; dst = d2; off = 2097152; }
  } else if (i < 4194304) {
    if (i < 3407872)      { src = s3; dst = d3; off = 3145728; }
    else if (i < 3670016) { src = s4; dst = d4; off = 3407872; }
    else if (i < 3932160) { src = s5; dst = d5; off = 3670016; }
    else                  { src = s6; dst = d6; off = 3932160; }
  } else {
    if (i < 5242880)      { src = s7; dst = d7; off = 4194304; }
    else                  { src = s8; dst = d8; off = 5242880; }
  }
  int j = i - off;
  f32x4 v = ((const f32x4*)src)[j];
  u16x4 o;
  o[0] = f2bf(v[0]); o[1] = f2bf(v[1]); o[2] = f2bf(v[2]); o[3] = f2bf(v[3]);
  ((u16x4*)dst)[j] = o;
}

// ---------------- mask expansion (bool/int32 autodetect) ----------------
__global__ void build_masks(const void* __restrict__ pm, float* __restrict__ maskbias,
                            float* __restrict__ qmask, int n) {
  __shared__ int sflag;
  if (threadIdx.x == 0) sflag = 0;
  __syncthreads();
  const unsigned* pw = (const unsigned*)pm;
  int nwords = n / 4;
  int local = 0;
  for (int i = threadIdx.x; i < nwords; i += blockDim.x)
    if (pw[i] > 1u) local = 1;
  if (local) atomicOr(&sflag, 1);
  __syncthreads();
  bool isbool = (sflag != 0);
  for (int i = threadIdx.x; i < n; i += blockDim.x) {
    int m = isbool ? (int)((const unsigned char*)pm)[i] : ((const int*)pm)[i];
    maskbias[i] = m ? 0.0f : -2e30f;
    qmask[i]    = m ? 1.0f : 0.0f;
  }
}

// ---------------- GEMM core v3: 3-buffer 2-deep pipeline, counted vmcnt, raw s_barrier ----
// C[M,N] = act(A[M,Klen] @ W[N,Klen]^T + bias) -> bf16
template<int EPI>
__device__ __forceinline__ void gemm_core(const u16* __restrict__ A, const u16* __restrict__ Bw,
                                          const float* __restrict__ bias, u16* __restrict__ C,
                                          int N, int Kstride, int Klen, int bn, int bm, int tid) {
  __shared__ u16 smem[3][8192];   // [buf][ A-tile 0..4095 | B-tile 4096..8191 ]  48 KB
  int wave = tid >> 6, lane = tid & 63;
  int l15 = lane & 15, l4 = lane >> 4;
  int wr = (wave >> 1) * 64, wc = (wave & 1) * 64;
  int mrow0 = bm * 128, ncol0 = bn * 128;
  int srow = lane >> 2;
  int scol = (lane & 3) * 8;

  const u16* asrc0 = A  + (size_t)(mrow0 + (wave * 2 + 0) * 16 + srow) * Kstride + scol;
  const u16* asrc1 = A  + (size_t)(mrow0 + (wave * 2 + 1) * 16 + srow) * Kstride + scol;
  const u16* bsrc0 = Bw + (size_t)(ncol0 + (wave * 2 + 0) * 16 + srow) * Kstride + scol;
  const u16* bsrc1 = Bw + (size_t)(ncol0 + (wave * 2 + 1) * 16 + srow) * Kstride + scol;
  u16* ad0 = &smem[0][(wave * 2 + 0) * 512];
  u16* ad1 = &smem[0][(wave * 2 + 1) * 512];
  u16* bd0 = &smem[0][4096 + (wave * 2 + 0) * 512];
  u16* bd1 = &smem[0][4096 + (wave * 2 + 1) * 512];

  auto stage = [&](int buf, int k0) {
    gload_lds16(asrc0 + k0, ad0 + buf * 8192);
    gload_lds16(asrc1 + k0, ad1 + buf * 8192);
    gload_lds16(bsrc0 + k0, bd0 + buf * 8192);
    gload_lds16(bsrc1 + k0, bd1 + buf * 8192);
  };

  f32x4 acc[4][4];
#pragma unroll
  for (int i = 0; i < 4; i++)
#pragma unroll
    for (int j = 0; j < 4; j++) acc[i][j] = (f32x4)0.0f;

  int nsteps = Klen >> 5;
  stage(0, 0);
  stage(1, 32);
  int cur = 0;
  for (int s = 0; s < nsteps; s++) {
    // tile s's 4 per-wave loads are the oldest outstanding; tile s+1's 4 may stay in flight.
    if (s + 1 < nsteps) {
      asm volatile("s_waitcnt vmcnt(4)" ::: "memory");
    } else {
      asm volatile("s_waitcnt vmcnt(0)" ::: "memory");
    }
    __builtin_amdgcn_s_barrier();          // all waves' tile-s loads landed; buf[(s-1)%3] free
    if (s + 2 < nsteps) {
      int nb = cur + 2; if (nb >= 3) nb -= 3;
      stage(nb, (s + 2) << 5);             // 2-deep prefetch, stays in flight across barriers
    }
    const u16* as = &smem[cur][0];
    const u16* bs = &smem[cur][4096];
    bf16x8 af[4], bfr[4];
#pragma unroll
    for (int mi = 0; mi < 4; mi++) af[mi]  = *(const bf16x8*)(as + (wr + mi * 16 + l15) * 32 + l4 * 8);
#pragma unroll
    for (int ni = 0; ni < 4; ni++) bfr[ni] = *(const bf16x8*)(bs + (wc + ni * 16 + l15) * 32 + l4 * 8);
#pragma unroll
    for (int mi = 0; mi < 4; mi++)
#pragma unroll
      for (int ni = 0; ni < 4; ni++)
        acc[mi][ni] = __builtin_amdgcn_mfma_f32_16x16x32_bf16(af[mi], bfr[ni], acc[mi][ni], 0, 0, 0);
    cur++; if (cur >= 3) cur = 0;
  }

  // epilogue: bounce 64-row half-tiles through LDS ([64][136] u16, padded rows) -> u16x8 stores
  __syncthreads();   // full drain; K-loop LDS reads done everywhere before overwrite
  u16* ct = &smem[0][0];
  for (int p = 0; p < 2; p++) {
    if (p) __syncthreads();
    if ((wave >> 1) == p) {
#pragma unroll
      for (int ni = 0; ni < 4; ni++) {
        int gcol = ncol0 + wc + ni * 16 + l15;
        float bv = (EPI > 0) ? bias[gcol] : 0.0f;
#pragma unroll
        for (int mi = 0; mi < 4; mi++) {
#pragma unroll
          for (int r = 0; r < 4; r++) {
            float v = acc[mi][ni][r] + bv;
            if (EPI == 2) v = gelu_fast(v);
            ct[(mi * 16 + l4 * 4 + r) * 136 + wc + ni * 16 + l15] = f2bf(v);
          }
        }
      }
    }
    __syncthreads();
    int lrow = tid >> 2, cq = tid & 3;
#pragma unroll
    for (int j = 0; j < 4; j++) {
      int col = cq * 8 + j * 32;
      u16x8 vv = *(const u16x8*)(ct + lrow * 136 + col);
      *(u16x8*)(C + (size_t)(mrow0 + p * 64 + lrow) * N + ncol0 + col) = vv;
    }
  }
}

template<int EPI>
__global__ __launch_bounds__(256) void gemm_bt(const u16* __restrict__ A, const u16* __restrict__ Bw,
                                               const float* __restrict__ bias, u16* __restrict__ C,
                                               int N, int K) {
  gemm_core<EPI>(A, Bw, bias, C, N, K, K, blockIdx.x, blockIdx.y, threadIdx.x);
}

// split-K GEMM: blockIdx.z selects K-chunk of length Kc; writes bf16 partial at P + z*M*N
__global__ __launch_bounds__(256) void gemm_splitk(const u16* __restrict__ A, const u16* __restrict__ Bw,
                                                   u16* __restrict__ P, int N, int Kstride, int Kc) {
  int z = blockIdx.z;
  size_t M = (size_t)gridDim.y * 128;
  gemm_core<0>(A + (size_t)z * Kc, Bw + (size_t)z * Kc, nullptr,
               P + (size_t)z * M * N, N, Kstride, Kc, blockIdx.x, blockIdx.y, threadIdx.x);
}

__global__ __launch_bounds__(256) void gemm_qkv(const u16* __restrict__ qb, const u16* __restrict__ kb,
                                                const u16* __restrict__ vb,
                                                const u16* __restrict__ wq, const u16* __restrict__ wk,
                                                const u16* __restrict__ wv,
                                                u16* __restrict__ Qo, u16* __restrict__ Ko, u16* __restrict__ Vo) {
  const u16* A; const u16* W; u16* C;
  if (blockIdx.z == 0)      { A = qb; W = wq; C = Qo; }
  else if (blockIdx.z == 1) { A = kb; W = wk; C = Ko; }
  else                      { A = vb; W = wv; C = Vo; }
  gemm_core<0>(A, W, nullptr, C, 1024, 1024, 1024, blockIdx.x, blockIdx.y, threadIdx.x);
}

// ---------------- V transpose: [32][2048][64] -> [32][64][2048] ----------------
__global__ __launch_bounds__(256) void transpose64(const u16* __restrict__ in, u16* __restrict__ out) {
  int bh = blockIdx.y, tb = blockIdx.x;
  __shared__ u16 tile[64 * 72];
  int tid = threadIdx.x;
#pragma unroll
  for (int it = 0; it < 2; it++) {
    int idx = it * 256 + tid;
    int r = idx >> 3, c8 = (idx & 7) * 8;
    u16x8 v = *(const u16x8*)(in + ((size_t)bh * 2048 + tb * 64 + r) * 64 + c8);
    int byte = ((r * 72 + c8) * 2) ^ (((r >> 3) & 7) << 4);
    *(u16x8*)((char*)tile + byte) = v;
  }
  __syncthreads();
#pragma unroll
  for (int it = 0; it < 2; it++) {
    int idx = it * 256 + tid;
    int d = idx >> 3, t8 = (idx & 7) * 8;
    u16x8 o;
#pragma unroll
    for (int e = 0; e < 8; e++) {
      int t = t8 + e;
      int byte = ((t * 72 + d) * 2) ^ (((t >> 3) & 7) << 4);
      o[e] = *(const u16*)((const char*)tile + byte);
    }
    *(u16x8*)(out + ((size_t)bh * 64 + d) * 2048 + tb * 64 + t8) = o;
  }
}

// ---------------- flash attention v4: LDS-staged K/V, swapped-QK, split-KV x2 ----------------
__global__ __launch_bounds__(256, 4) void attn4(const u16* __restrict__ Q, const u16* __restrict__ Kg,
                                                const u16* __restrict__ VT,
                                                const float* __restrict__ maskbias,
                                                u16* __restrict__ O0, u16* __restrict__ O1,
                                                float* __restrict__ Ms, float* __restrict__ Ss) {
  const int T = 2048;
  int bh = blockIdx.x;
  int qt = blockIdx.y;
  int sp = blockIdx.z;
  int b = bh >> 4;
  const u16* Qh = Q  + (size_t)bh * T * 64;
  const u16* Kh = Kg + (size_t)bh * T * 64;
  const u16* Vh = VT + (size_t)bh * T * 64;   // [64][2048]
  u16* Oh = (sp ? O1 : O0) + (size_t)bh * T * 64;
  const float* mb = maskbias + b * T + sp * 1024;
  int tid = threadIdx.x, w = tid >> 6, l = tid & 63;
  int q32 = l & 31, h = l >> 5;
  int qbase = qt * 128 + w * 32;
  const float C = 0.125f * LOG2E;

  __shared__ u16 Ks[2][4096];
  __shared__ u16 Vs[2][4096];

  bf16x8 qf[4];
#pragma unroll
  for (int dc = 0; dc < 4; dc++)
    qf[dc] = *(const bf16x8*)(Qh + (size_t)(qbase + q32) * 64 + dc * 16 + h * 8);

  int rl = l >> 3, ob = (l & 7) * 16;
  int osw = ob ^ (rl << 4);
  int r0 = w * 16 + rl, r1 = w * 16 + 8 + rl;
  const u16* pK0 = Kh + (size_t)(sp * 1024 + r0) * 64 + (osw >> 1);
  const u16* pK1 = Kh + (size_t)(sp * 1024 + r1) * 64 + (osw >> 1);
  const u16* pV0 = Vh + (size_t)r0 * 2048 + sp * 1024 + (osw >> 1);
  const u16* pV1 = Vh + (size_t)r1 * 2048 + sp * 1024 + (osw >> 1);
  u16* dK0 = &Ks[0][0] + (w * 16) * 64;
  u16* dK1 = &Ks[0][0] + (w * 16 + 8) * 64;
  u16* dV0 = &Vs[0][0] + (w * 16) * 64;
  u16* dV1 = &Vs[0][0] + (w * 16 + 8) * 64;

  auto stage = [&](int buf) {
    gload_lds16(pK0, dK0 + buf * 4096);
    gload_lds16(pK1, dK1 + buf * 4096);
    gload_lds16(pV0, dV0 + buf * 4096);
    gload_lds16(pV1, dV1 + buf * 4096);
    pK0 += 4096; pK1 += 4096; pV0 += 64; pV1 += 64;
  };

  f32x16 acc[2];
  acc[0] = (f32x16)0.0f; acc[1] = (f32x16)0.0f;
  float m_ = -3e30f, s_ = 0.0f;

  int swz = (q32 & 7) << 4;

  stage(0);
  for (int t = 0; t < 16; t++) {
    int cur = t & 1;
    __syncthreads();
    if (t < 15) stage(cur ^ 1);
    const char* ksb = (const char*)(&Ks[0][0] + cur * 4096);
    const char* vsb = (const char*)(&Vs[0][0] + cur * 4096);

    bf16x8 kf[2][4];
#pragma unroll
    for (int kvc = 0; kvc < 2; kvc++)
#pragma unroll
      for (int dc = 0; dc < 4; dc++)
        kf[kvc][dc] = *(const bf16x8*)(ksb + (kvc * 32 + q32) * 128 + ((dc * 32 + h * 16) ^ swz));

    f32x16 st[2];
    st[0] = (f32x16)0.0f; st[1] = (f32x16)0.0f;
#pragma unroll
    for (int kvc = 0; kvc < 2; kvc++)
#pragma unroll
      for (int dc = 0; dc < 4; dc++)
        st[kvc] = __builtin_amdgcn_mfma_f32_32x32x16_bf16(kf[kvc][dc], qf[dc], st[kvc], 0, 0, 0);

    float p[32];
    float pmax = -3e30f;
#pragma unroll
    for (int kvc = 0; kvc < 2; kvc++) {
#pragma unroll
      for (int g = 0; g < 4; g++) {
        f32x4 mv = *(const f32x4*)(mb + t * 64 + kvc * 32 + g * 8 + h * 4);
#pragma unroll
        for (int r = 0; r < 4; r++) {
          float val = st[kvc][g * 4 + r] * C + mv[r];
          p[kvc * 16 + g * 4 + r] = val;
          pmax = fmaxf(pmax, val);
        }
      }
    }
    pmax = fmaxf(pmax, __shfl_xor(pmax, 32));

    if (__any(pmax - m_ > 8.0f)) {
      float mnew = fmaxf(m_, pmax);
      float fsc = __builtin_amdgcn_exp2f(m_ - mnew);
      s_ *= fsc;
      m_ = mnew;
#pragma unroll
      for (int g = 0; g < 4; g++)
#pragma unroll
        for (int r = 0; r < 4; r++) {
          float f = __shfl(fsc, g * 8 + h * 4 + r);
          acc[0][g * 4 + r] *= f;
          acc[1][g * 4 + r] *= f;
        }
    }

    float rsum = 0.0f;
    u32 wds[16];
#pragma unroll
    for (int i = 0; i < 16; i++) {
      float a = __builtin_amdgcn_exp2f(p[2 * i] - m_);
      float bq = __builtin_amdgcn_exp2f(p[2 * i + 1] - m_);
      rsum += a + bq;
      union { __bf16 h2[2]; u32 u; } cv;
      cv.h2[0] = (__bf16)a; cv.h2[1] = (__bf16)bq;
      wds[i] = cv.u;
    }
    rsum += __shfl_xor(rsum, 32);
    s_ += rsum;

#pragma unroll
    for (int kvc = 0; kvc < 2; kvc++) {
      int bse = kvc * 8;
      u32 sw0 = __shfl_xor(wds[bse + 0], 32), sw1 = __shfl_xor(wds[bse + 1], 32);
      u32 sw2 = __shfl_xor(wds[bse + 2], 32), sw3 = __shfl_xor(wds[bse + 3], 32);
      u32 sw4 = __shfl_xor(wds[bse + 4], 32), sw5 = __shfl_xor(wds[bse + 5], 32);
      u32 sw6 = __shfl_xor(wds[bse + 6], 32), sw7 = __shfl_xor(wds[bse + 7], 32);
      union { u32 u[4]; bf16x8 v; } pa0, pa1;
      pa0.u[0] = h ? sw2 : wds[bse + 0];
      pa0.u[1] = h ? sw3 : wds[bse + 1];
      pa0.u[2] = h ? wds[bse + 2] : sw0;
      pa0.u[3] = h ? wds[bse + 3] : sw1;
      pa1.u[0] = h ? sw6 : wds[bse + 4];
      pa1.u[1] = h ? sw7 : wds[bse + 5];
      pa1.u[2] = h ? wds[bse + 6] : sw4;
      pa1.u[3] = h ? wds[bse + 7] : sw5;
#pragma unroll
      for (int cl = 0; cl < 2; cl++) {
        bf16x8 pa = cl ? pa1.v : pa0.v;
        int cg = kvc * 2 + cl;
#pragma unroll
        for (int dblk = 0; dblk < 2; dblk++) {
          bf16x8 vf = *(const bf16x8*)(vsb + (dblk * 32 + q32) * 128 + ((cg * 32 + h * 16) ^ swz));
          acc[dblk] = __builtin_amdgcn_mfma_f32_32x32x16_bf16(pa, vf, acc[dblk], 0, 0, 0);
        }
      }
    }
  }

#pragma unroll
  for (int g = 0; g < 4; g++) {
#pragma unroll
    for (int r = 0; r < 4; r++) {
      int row = g * 8 + h * 4 + r;
#pragma unroll
      for (int dblk = 0; dblk < 2; dblk++)
        Oh[(size_t)(qbase + row) * 64 + dblk * 32 + q32] = f2bf(acc[dblk][g * 4 + r]);
    }
  }
  if (h == 0) {
    int ro = sp * 65536 + bh * 2048 + qbase + q32;
    Ms[ro] = m_;
    Ss[ro] = s_;
  }
}

// ---------------- split-KV combine (2 splits) ----------------
__global__ __launch_bounds__(256) void attn_combine(const u16* __restrict__ O0, const u16* __restrict__ O1,
                                                    const float* __restrict__ Ms, const float* __restrict__ Ss,
                                                    const float* __restrict__ qmaskf, u16* __restrict__ out) {
  int idx = blockIdx.x * 256 + threadIdx.x;
  int row = idx >> 3;
  int d8 = (idx & 7) * 8;
  int bh = row >> 11, r = row & 2047, b = bh >> 4;
  float m0 = Ms[row], m1 = Ms[65536 + row];
  float mstar = fmaxf(m0, m1);
  float w0 = __builtin_amdgcn_exp2f(m0 - mstar);
  float w1 = __builtin_amdgcn_exp2f(m1 - mstar);
  float den = w0 * Ss[row] + w1 * Ss[65536 + row];
  float scale = qmaskf[b * 2048 + r] / den;
  size_t base = (size_t)row * 64 + d8;
  u16x8 a0 = *(const u16x8*)(O0 + base);
  u16x8 a1 = *(const u16x8*)(O1 + base);
  u16x8 o;
#pragma unroll
  for (int e = 0; e < 8; e++)
    o[e] = f2bf((w0 * bf2f(a0[e]) + w1 * bf2f(a1[e])) * scale);
  *(u16x8*)(out + base) = o;
}

// ---------------- residual + split-K partial sum + (bias) + layernorm ----------------
template<int NP, int A_F32, int ADD_BIAS, int OUT_F32>
__global__ __launch_bounds__(256) void add_ln_multi(const void* __restrict__ Ap,
                                                    const u16* __restrict__ P0, const u16* __restrict__ P1,
                                                    const u16* __restrict__ P2, const u16* __restrict__ P3,
                                                    const float* __restrict__ bias,
                                                    const float* __restrict__ g, const float* __restrict__ be,
                                                    void* __restrict__ outp) {
  int row = blockIdx.x, tid = threadIdx.x;
  int lane = tid & 63, wave = tid >> 6;
  size_t rb = (size_t)row * 1024;
  float x[4];
  if (A_F32) {
    f32x4 a = ((const f32x4*)((const float*)Ap + rb))[tid];
#pragma unroll
    for (int j = 0; j < 4; j++) x[j] = a[j];
  } else {
    u16x4 au = ((const u16x4*)((const u16*)Ap + rb))[tid];
#pragma unroll
    for (int j = 0; j < 4; j++) x[j] = bf2f(au[j]);
  }
  {
    u16x4 p = ((const u16x4*)(P0 + rb))[tid];
#pragma unroll
    for (int j = 0; j < 4; j++) x[j] += bf2f(p[j]);
  }
  if (NP > 1) {
    u16x4 p = ((const u16x4*)(P1 + rb))[tid];
#pragma unroll
    for (int j = 0; j < 4; j++) x[j] += bf2f(p[j]);
  }
  if (NP > 2) {
    u16x4 p = ((const u16x4*)(P2 + rb))[tid];
#pragma unroll
    for (int j = 0; j < 4; j++) x[j] += bf2f(p[j]);
  }
  if (NP > 3) {
    u16x4 p = ((const u16x4*)(P3 + rb))[tid];
#pragma unroll
    for (int j = 0; j < 4; j++) x[j] += bf2f(p[j]);
  }
  if (ADD_BIAS) {
    f32x4 bv = ((const f32x4*)bias)[tid];
#pragma unroll
    for (int j = 0; j < 4; j++) x[j] += bv[j];
  }
  float s = x[0] + x[1] + x[2] + x[3];
  float q = x[0] * x[0] + x[1] * x[1] + x[2] * x[2] + x[3] * x[3];
#pragma unroll
  for (int m = 1; m < 64; m <<= 1) { s += __shfl_xor(s, m); q += __shfl_xor(q, m); }
  __shared__ float rs[4], rq[4];
  if (lane == 0) { rs[wave] = s; rq[wave] = q; }
  __syncthreads();
  float S = rs[0] + rs[1] + rs[2] + rs[3];
  float Qq = rq[0] + rq[1] + rq[2] + rq[3];
  float mean = S * (1.0f / 1024.0f);
  float var = Qq * (1.0f / 1024.0f) - mean * mean;
  float rstd = rsqrtf(var + 1e-5f);
  if (OUT_F32) {
    f32x4 y;
#pragma unroll
    for (int j = 0; j < 4; j++) { int col = tid * 4 + j; y[j] = (x[j] - mean) * rstd * g[col] + be[col]; }
    ((f32x4*)((float*)outp + rb))[tid] = y;
  } else {
    u16x4 y;
#pragma unroll
    for (int j = 0; j < 4; j++) { int col = tid * 4 + j; y[j] = f2bf((x[j] - mean) * rstd * g[col] + be[col]); }
    ((u16x4*)((u16*)outp + rb))[tid] = y;
  }
}

// ---------------- launch ----------------
extern "C" void kernel_launch(void* const* d_in, const int* in_sizes, int n_in,
                              void* d_out, int out_size, void* d_ws, size_t ws_size,
                              hipStream_t stream) {
  const float* q   = (const float*)d_in[0];
  const float* k   = (const float*)d_in[1];
  const float* v   = (const float*)d_in[2];
  const void*  pad = d_in[3];
  const float* Wq  = (const float*)d_in[4];
  const float* Wk  = (const float*)d_in[5];
  const float* Wv  = (const float*)d_in[6];
  const float* Wo  = (const float*)d_in[7];
  const float* W1  = (const float*)d_in[8];
  const float* b1  = (const float*)d_in[9];
  const float* W2  = (const float*)d_in[10];
  const float* b2  = (const float*)d_in[11];
  const float* g1  = (const float*)d_in[12];
  const float* be1 = (const float*)d_in[13];
  const float* g2  = (const float*)d_in[14];
  const float* be2 = (const float*)d_in[15];
  float* out = (float*)d_out;
  char* ws = (char*)d_ws;
  const size_t MB = 1u << 20;

  u16* wq_b = (u16*)(ws + 0 * MB);
  u16* wk_b = (u16*)(ws + 2 * MB);
  u16* wv_b = (u16*)(ws + 4 * MB);
  u16* wo_b = (u16*)(ws + 6 * MB);
  u16* w1_b = (u16*)(ws + 8 * MB);
  u16* w2_b = (u16*)(ws + 16 * MB);
  u16* qb   = (u16*)(ws + 24 * MB);
  u16* kb   = (u16*)(ws + 32 * MB);
  u16* vb   = (u16*)(ws + 40 * MB);
  u16* Qb   = (u16*)(ws + 48 * MB);
  u16* Kb   = (u16*)(ws + 56 * MB);
  u16* Vb   = (u16*)(ws + 64 * MB);
  u16* VTb  = (u16*)(ws + 72 * MB);
  u16* hatt = (u16*)(ws + 80 * MB);
  // liveness overlays
  u16* Op0  = (u16*)(ws + 24 * MB);   // qb dead after QKV
  u16* Op1  = (u16*)(ws + 32 * MB);   // kb dead
  float* Ms = (float*)(ws + 88 * MB);
  float* Ss = (float*)(ws + 89 * MB);
  u16* WP   = (u16*)(ws + 40 * MB);   // Wo split-K partials x2 (vb,Qb dead): 40-56
  u16* h1b  = (u16*)(ws + 24 * MB);   // Op0 dead after combine
  u16* ff1  = (u16*)(ws + 32 * MB);   // Op1/WP/Kb dead after LN1: 32-64 (32 MB)
  u16* Fp   = (u16*)(ws + 64 * MB);   // FFN2 split-K partials x4: 64-96
  float* maskbias = (float*)(ws + 96 * MB);
  float* qmaskf   = (float*)(ws + 96 * MB + 16384);

  build_masks<<<1, 256, 0, stream>>>(pad, maskbias, qmaskf, in_sizes[3]);

  cvt_all<<<24576, 256, 0, stream>>>(q, k, v, Wq, Wk, Wv, Wo, W1, W2,
                                     qb, kb, vb, wq_b, wk_b, wv_b, wo_b, w1_b, w2_b);

  gemm_qkv<<<dim3(8, 32, 3), 256, 0, stream>>>(qb, kb, vb, wq_b, wk_b, wv_b, Qb, Kb, Vb);

  transpose64<<<dim3(32, 32), 256, 0, stream>>>(Vb, VTb);

  attn4<<<dim3(32, 16, 2), 256, 0, stream>>>(Qb, Kb, VTb, maskbias, Op0, Op1, Ms, Ss);

  attn_combine<<<2048, 256, 0, stream>>>(Op0, Op1, Ms, Ss, qmaskf, hatt);

  // Wo: split-K x2 (Kc=512), partials -> WP[2][4096][1024]
  gemm_splitk<<<dim3(8, 32, 2), 256, 0, stream>>>(hatt, wo_b, WP, 1024, 1024, 512);

  // LN1: q + WP0 + WP1 -> h1b (bf16)
  add_ln_multi<2, 1, 0, 0><<<4096, 256, 0, stream>>>(q, WP, WP + 4194304, nullptr, nullptr,
                                                     nullptr, g1, be1, h1b);

  // FFN1: h1 @ W1^T + b1, GELU -> ff1
  gemm_bt<2><<<dim3(32, 32), 256, 0, stream>>>(h1b, w1_b, b1, ff1, 4096, 1024);

  // FFN2: split-K x4 (Kc=1024), partials -> Fp[4][4096][1024]
  gemm_splitk<<<dim3(8, 32, 4), 256, 0, stream>>>(ff1, w2_b, Fp, 1024, 4096, 1024);

  // LN2: h1 + sum(Fp) + b2 -> out (f32)
  add_ln_multi<4, 0, 1, 1><<<4096, 256, 0, stream>>>(h1b, Fp, Fp + 4194304, Fp + 2 * 4194304,
                                                     Fp + 3 * 4194304, b2, g2, be2, out);
}

// Round 8
// 279.057 us; speedup vs baseline: 1.7527x; 1.0847x over previous
//
#include <hip/hip_runtime.h>

typedef unsigned short u16;
typedef unsigned int u32;
typedef __attribute__((ext_vector_type(8))) __bf16 bf16x8;
typedef __attribute__((ext_vector_type(4))) float f32x4;
typedef __attribute__((ext_vector_type(16))) float f32x16;
typedef __attribute__((ext_vector_type(4))) unsigned short u16x4;
typedef __attribute__((ext_vector_type(8))) unsigned short u16x8;

#define LOG2E 1.44269504088896340736f

__device__ __forceinline__ u16 f2bf(float f) {
  union { float f; unsigned u; } c; c.f = f;
  unsigned r = c.u + 0x7FFFu + ((c.u >> 16) & 1u);
  return (u16)(r >> 16);
}
__device__ __forceinline__ float bf2f(u16 h) {
  union { unsigned u; float f; } c; c.u = ((unsigned)h) << 16;
  return c.f;
}

__device__ __forceinline__ void gload_lds16(const u16* g, u16* l) {
  __builtin_amdgcn_global_load_lds((const __attribute__((address_space(1))) unsigned int*)g,
                                   (__attribute__((address_space(3))) unsigned int*)l, 16, 0, 0);
}

// fast exact GELU: erf via Abramowitz-Stegun 7.1.26 (|eps| <= 1.5e-7)
__device__ __forceinline__ float gelu_fast(float x) {
  float z = fabsf(x) * 0.70710678118654752f;
  float t = 1.0f / (1.0f + 0.3275911f * z);
  float poly = t * (0.254829592f + t * (-0.284496736f + t * (1.421413741f +
               t * (-1.453152027f + t * 1.061405429f))));
  float e = __builtin_amdgcn_exp2f(-z * z * LOG2E);
  float erfz = 1.0f - poly * e;
  float s = (x >= 0.0f) ? erfz : -erfz;
  return 0.5f * x * (1.0f + s);
}

// ---------------- fused f32 -> bf16 conversion (all 9 tensors, one launch) ----------------
__global__ __launch_bounds__(256) void cvt_all(
    const float* __restrict__ s0, const float* __restrict__ s1, const float* __restrict__ s2,
    const float* __restrict__ s3, const float* __restrict__ s4, const float* __restrict__ s5,
    const float* __restrict__ s6, const float* __restrict__ s7, const float* __restrict__ s8,
    u16* __restrict__ d0, u16* __restrict__ d1, u16* __restrict__ d2,
    u16* __restrict__ d3, u16* __restrict__ d4, u16* __restrict__ d5,
    u16* __restrict__ d6, u16* __restrict__ d7, u16* __restrict__ d8) {
  int i = blockIdx.x * 256 + threadIdx.x;
  if (i >= 6291456) return;
  const float* src; u16* dst; int off;
  if (i < 3145728) {
    if (i < 1048576)      { src = s0; dst = d0; off = 0; }
    else if (i < 2097152) { src = s1; dst = d1; off = 1048576; }
    else                  { src = s2; dst = d2; off = 2097152; }
  } else if (i < 4194304) {
    if (i < 3407872)      { src = s3; dst = d3; off = 3145728; }
    else if (i < 3670016) { src = s4; dst = d4; off = 3407872; }
    else if (i < 3932160) { src = s5; dst = d5; off = 3670016; }
    else                  { src = s6; dst = d6; off = 3932160; }
  } else {
    if (i < 5242880)      { src = s7; dst = d7; off = 4194304; }
    else                  { src = s8; dst = d8; off = 5242880; }
  }
  int j = i - off;
  f32x4 v = ((const f32x4*)src)[j];
  u16x4 o;
  o[0] = f2bf(v[0]); o[1] = f2bf(v[1]); o[2] = f2bf(v[2]); o[3] = f2bf(v[3]);
  ((u16x4*)dst)[j] = o;
}

// ---------------- mask expansion (bool/int32 autodetect) ----------------
__global__ void build_masks(const void* __restrict__ pm, float* __restrict__ maskbias,
                            float* __restrict__ qmask, int n) {
  __shared__ int sflag;
  if (threadIdx.x == 0) sflag = 0;
  __syncthreads();
  const unsigned* pw = (const unsigned*)pm;
  int nwords = n / 4;
  int local = 0;
  for (int i = threadIdx.x; i < nwords; i += blockDim.x)
    if (pw[i] > 1u) local = 1;
  if (local) atomicOr(&sflag, 1);
  __syncthreads();
  bool isbool = (sflag != 0);
  for (int i = threadIdx.x; i < n; i += blockDim.x) {
    int m = isbool ? (int)((const unsigned char*)pm)[i] : ((const int*)pm)[i];
    maskbias[i] = m ? 0.0f : -2e30f;
    qmask[i]    = m ? 1.0f : 0.0f;
  }
}

// ---------------- GEMM core v4: 8 waves x (32x64), 3-buf counted vmcnt, 4 waves/SIMD ----
// C[M,N] = act(A[M,Klen] @ W[N,Klen]^T + bias) -> bf16.  512 threads/block.
template<int EPI>
__device__ __forceinline__ void gemm_core(const u16* __restrict__ A, const u16* __restrict__ Bw,
                                          const float* __restrict__ bias, u16* __restrict__ C,
                                          int N, int Kstride, int Klen, int bn, int bm, int tid) {
  __shared__ u16 smem[3][8192];   // [buf][ A-tile 0..4095 | B-tile 4096..8191 ]  48 KB
  int wave = tid >> 6, lane = tid & 63;
  int l15 = lane & 15, l4 = lane >> 4;
  int wr = (wave >> 1) * 32;      // wave row block (4 waves over 128 rows)
  int wc = (wave & 1) * 64;       // wave col block (2 waves over 128 cols)
  int mrow0 = bm * 128, ncol0 = bn * 128;
  int srow = lane >> 2;           // staging: row within 16-row wave chunk
  int scol = (lane & 3) * 8;

  const u16* asrc = A  + (size_t)(mrow0 + wave * 16 + srow) * Kstride + scol;
  const u16* bsrc = Bw + (size_t)(ncol0 + wave * 16 + srow) * Kstride + scol;
  u16* ad = &smem[0][wave * 512];
  u16* bd = &smem[0][4096 + wave * 512];

  auto stage = [&](int buf, int k0) {
    gload_lds16(asrc + k0, ad + buf * 8192);
    gload_lds16(bsrc + k0, bd + buf * 8192);
  };

  f32x4 acc[2][4];
#pragma unroll
  for (int i = 0; i < 2; i++)
#pragma unroll
    for (int j = 0; j < 4; j++) acc[i][j] = (f32x4)0.0f;

  int nsteps = Klen >> 5;
  stage(0, 0);
  stage(1, 32);
  int cur = 0;
  for (int s = 0; s < nsteps; s++) {
    // tile s's 2 per-thread loads are oldest; tile s+1's 2 may stay in flight.
    if (s + 1 < nsteps) {
      asm volatile("s_waitcnt vmcnt(2)" ::: "memory");
    } else {
      asm volatile("s_waitcnt vmcnt(0)" ::: "memory");
    }
    __builtin_amdgcn_s_barrier();
    if (s + 2 < nsteps) {
      int nb = cur + 2; if (nb >= 3) nb -= 3;
      stage(nb, (s + 2) << 5);
    }
    const u16* as = &smem[cur][0];
    const u16* bs = &smem[cur][4096];
    bf16x8 af[2], bfr[4];
#pragma unroll
    for (int mi = 0; mi < 2; mi++) af[mi]  = *(const bf16x8*)(as + (wr + mi * 16 + l15) * 32 + l4 * 8);
#pragma unroll
    for (int ni = 0; ni < 4; ni++) bfr[ni] = *(const bf16x8*)(bs + (wc + ni * 16 + l15) * 32 + l4 * 8);
#pragma unroll
    for (int mi = 0; mi < 2; mi++)
#pragma unroll
      for (int ni = 0; ni < 4; ni++)
        acc[mi][ni] = __builtin_amdgcn_mfma_f32_16x16x32_bf16(af[mi], bfr[ni], acc[mi][ni], 0, 0, 0);
    cur++; if (cur >= 3) cur = 0;
  }

  // epilogue: single-pass LDS bounce ([128][136] u16 = 34 KB) -> coalesced u16x8 stores
  __syncthreads();
  u16* ct = &smem[0][0];
#pragma unroll
  for (int ni = 0; ni < 4; ni++) {
    int gcol = ncol0 + wc + ni * 16 + l15;
    float bv = (EPI > 0) ? bias[gcol] : 0.0f;
#pragma unroll
    for (int mi = 0; mi < 2; mi++) {
#pragma unroll
      for (int r = 0; r < 4; r++) {
        float v = acc[mi][ni][r] + bv;
        if (EPI == 2) v = gelu_fast(v);
        ct[(wr + mi * 16 + l4 * 4 + r) * 136 + wc + ni * 16 + l15] = f2bf(v);
      }
    }
  }
  __syncthreads();
  int lrow = tid >> 2, cq = tid & 3;
#pragma unroll
  for (int j = 0; j < 4; j++) {
    int col = cq * 8 + j * 32;
    u16x8 vv = *(const u16x8*)(ct + lrow * 136 + col);
    *(u16x8*)(C + (size_t)(mrow0 + lrow) * N + ncol0 + col) = vv;
  }
}

template<int EPI>
__global__ __launch_bounds__(512, 4) void gemm_bt(const u16* __restrict__ A, const u16* __restrict__ Bw,
                                                  const float* __restrict__ bias, u16* __restrict__ C,
                                                  int N, int K) {
  gemm_core<EPI>(A, Bw, bias, C, N, K, K, blockIdx.x, blockIdx.y, threadIdx.x);
}

// split-K GEMM: blockIdx.z selects K-chunk of length Kc; writes bf16 partial at P + z*M*N
__global__ __launch_bounds__(512, 4) void gemm_splitk(const u16* __restrict__ A, const u16* __restrict__ Bw,
                                                      u16* __restrict__ P, int N, int Kstride, int Kc) {
  int z = blockIdx.z;
  size_t M = (size_t)gridDim.y * 128;
  gemm_core<0>(A + (size_t)z * Kc, Bw + (size_t)z * Kc, nullptr,
               P + (size_t)z * M * N, N, Kstride, Kc, blockIdx.x, blockIdx.y, threadIdx.x);
}

__global__ __launch_bounds__(512, 4) void gemm_qkv(const u16* __restrict__ qb, const u16* __restrict__ kb,
                                                   const u16* __restrict__ vb,
                                                   const u16* __restrict__ wq, const u16* __restrict__ wk,
                                                   const u16* __restrict__ wv,
                                                   u16* __restrict__ Qo, u16* __restrict__ Ko, u16* __restrict__ Vo) {
  const u16* A; const u16* W; u16* C;
  if (blockIdx.z == 0)      { A = qb; W = wq; C = Qo; }
  else if (blockIdx.z == 1) { A = kb; W = wk; C = Ko; }
  else                      { A = vb; W = wv; C = Vo; }
  gemm_core<0>(A, W, nullptr, C, 1024, 1024, 1024, blockIdx.x, blockIdx.y, threadIdx.x);
}

// ---------------- V transpose: [32][2048][64] -> [32][64][2048] ----------------
__global__ __launch_bounds__(256) void transpose64(const u16* __restrict__ in, u16* __restrict__ out) {
  int bh = blockIdx.y, tb = blockIdx.x;
  __shared__ u16 tile[64 * 72];
  int tid = threadIdx.x;
#pragma unroll
  for (int it = 0; it < 2; it++) {
    int idx = it * 256 + tid;
    int r = idx >> 3, c8 = (idx & 7) * 8;
    u16x8 v = *(const u16x8*)(in + ((size_t)bh * 2048 + tb * 64 + r) * 64 + c8);
    int byte = ((r * 72 + c8) * 2) ^ (((r >> 3) & 7) << 4);
    *(u16x8*)((char*)tile + byte) = v;
  }
  __syncthreads();
#pragma unroll
  for (int it = 0; it < 2; it++) {
    int idx = it * 256 + tid;
    int d = idx >> 3, t8 = (idx & 7) * 8;
    u16x8 o;
#pragma unroll
    for (int e = 0; e < 8; e++) {
      int t = t8 + e;
      int byte = ((t * 72 + d) * 2) ^ (((t >> 3) & 7) << 4);
      o[e] = *(const u16*)((const char*)tile + byte);
    }
    *(u16x8*)(out + ((size_t)bh * 64 + d) * 2048 + tb * 64 + t8) = o;
  }
}

// ---------------- flash attention v4: LDS-staged K/V, swapped-QK, split-KV x2 ----------------
__global__ __launch_bounds__(256, 4) void attn4(const u16* __restrict__ Q, const u16* __restrict__ Kg,
                                                const u16* __restrict__ VT,
                                                const float* __restrict__ maskbias,
                                                u16* __restrict__ O0, u16* __restrict__ O1,
                                                float* __restrict__ Ms, float* __restrict__ Ss) {
  const int T = 2048;
  int bh = blockIdx.x;
  int qt = blockIdx.y;
  int sp = blockIdx.z;
  int b = bh >> 4;
  const u16* Qh = Q  + (size_t)bh * T * 64;
  const u16* Kh = Kg + (size_t)bh * T * 64;
  const u16* Vh = VT + (size_t)bh * T * 64;   // [64][2048]
  u16* Oh = (sp ? O1 : O0) + (size_t)bh * T * 64;
  const float* mb = maskbias + b * T + sp * 1024;
  int tid = threadIdx.x, w = tid >> 6, l = tid & 63;
  int q32 = l & 31, h = l >> 5;
  int qbase = qt * 128 + w * 32;
  const float C = 0.125f * LOG2E;

  __shared__ u16 Ks[2][4096];
  __shared__ u16 Vs[2][4096];

  bf16x8 qf[4];
#pragma unroll
  for (int dc = 0; dc < 4; dc++)
    qf[dc] = *(const bf16x8*)(Qh + (size_t)(qbase + q32) * 64 + dc * 16 + h * 8);

  int rl = l >> 3, ob = (l & 7) * 16;
  int osw = ob ^ (rl << 4);
  int r0 = w * 16 + rl, r1 = w * 16 + 8 + rl;
  const u16* pK0 = Kh + (size_t)(sp * 1024 + r0) * 64 + (osw >> 1);
  const u16* pK1 = Kh + (size_t)(sp * 1024 + r1) * 64 + (osw >> 1);
  const u16* pV0 = Vh + (size_t)r0 * 2048 + sp * 1024 + (osw >> 1);
  const u16* pV1 = Vh + (size_t)r1 * 2048 + sp * 1024 + (osw >> 1);
  u16* dK0 = &Ks[0][0] + (w * 16) * 64;
  u16* dK1 = &Ks[0][0] + (w * 16 + 8) * 64;
  u16* dV0 = &Vs[0][0] + (w * 16) * 64;
  u16* dV1 = &Vs[0][0] + (w * 16 + 8) * 64;

  auto stage = [&](int buf) {
    gload_lds16(pK0, dK0 + buf * 4096);
    gload_lds16(pK1, dK1 + buf * 4096);
    gload_lds16(pV0, dV0 + buf * 4096);
    gload_lds16(pV1, dV1 + buf * 4096);
    pK0 += 4096; pK1 += 4096; pV0 += 64; pV1 += 64;
  };

  f32x16 acc[2];
  acc[0] = (f32x16)0.0f; acc[1] = (f32x16)0.0f;
  float m_ = -3e30f, s_ = 0.0f;

  int swz = (q32 & 7) << 4;

  stage(0);
  for (int t = 0; t < 16; t++) {
    int cur = t & 1;
    __syncthreads();
    if (t < 15) stage(cur ^ 1);
    const char* ksb = (const char*)(&Ks[0][0] + cur * 4096);
    const char* vsb = (const char*)(&Vs[0][0] + cur * 4096);

    bf16x8 kf[2][4];
#pragma unroll
    for (int kvc = 0; kvc < 2; kvc++)
#pragma unroll
      for (int dc = 0; dc < 4; dc++)
        kf[kvc][dc] = *(const bf16x8*)(ksb + (kvc * 32 + q32) * 128 + ((dc * 32 + h * 16) ^ swz));

    f32x16 st[2];
    st[0] = (f32x16)0.0f; st[1] = (f32x16)0.0f;
#pragma unroll
    for (int kvc = 0; kvc < 2; kvc++)
#pragma unroll
      for (int dc = 0; dc < 4; dc++)
        st[kvc] = __builtin_amdgcn_mfma_f32_32x32x16_bf16(kf[kvc][dc], qf[dc], st[kvc], 0, 0, 0);

    float p[32];
    float pmax = -3e30f;
#pragma unroll
    for (int kvc = 0; kvc < 2; kvc++) {
#pragma unroll
      for (int g = 0; g < 4; g++) {
        f32x4 mv = *(const f32x4*)(mb + t * 64 + kvc * 32 + g * 8 + h * 4);
#pragma unroll
        for (int r = 0; r < 4; r++) {
          float val = st[kvc][g * 4 + r] * C + mv[r];
          p[kvc * 16 + g * 4 + r] = val;
          pmax = fmaxf(pmax, val);
        }
      }
    }
    pmax = fmaxf(pmax, __shfl_xor(pmax, 32));

    if (__any(pmax - m_ > 8.0f)) {
      float mnew = fmaxf(m_, pmax);
      float fsc = __builtin_amdgcn_exp2f(m_ - mnew);
      s_ *= fsc;
      m_ = mnew;
#pragma unroll
      for (int g = 0; g < 4; g++)
#pragma unroll
        for (int r = 0; r < 4; r++) {
          float f = __shfl(fsc, g * 8 + h * 4 + r);
          acc[0][g * 4 + r] *= f;
          acc[1][g * 4 + r] *= f;
        }
    }

    float rsum = 0.0f;
    u32 wds[16];
#pragma unroll
    for (int i = 0; i < 16; i++) {
      float a = __builtin_amdgcn_exp2f(p[2 * i] - m_);
      float bq = __builtin_amdgcn_exp2f(p[2 * i + 1] - m_);
      rsum += a + bq;
      union { __bf16 h2[2]; u32 u; } cv;
      cv.h2[0] = (__bf16)a; cv.h2[1] = (__bf16)bq;
      wds[i] = cv.u;
    }
    rsum += __shfl_xor(rsum, 32);
    s_ += rsum;

#pragma unroll
    for (int kvc = 0; kvc < 2; kvc++) {
      int bse = kvc * 8;
      u32 sw0 = __shfl_xor(wds[bse + 0], 32), sw1 = __shfl_xor(wds[bse + 1], 32);
      u32 sw2 = __shfl_xor(wds[bse + 2], 32), sw3 = __shfl_xor(wds[bse + 3], 32);
      u32 sw4 = __shfl_xor(wds[bse + 4], 32), sw5 = __shfl_xor(wds[bse + 5], 32);
      u32 sw6 = __shfl_xor(wds[bse + 6], 32), sw7 = __shfl_xor(wds[bse + 7], 32);
      union { u32 u[4]; bf16x8 v; } pa0, pa1;
      pa0.u[0] = h ? sw2 : wds[bse + 0];
      pa0.u[1] = h ? sw3 : wds[bse + 1];
      pa0.u[2] = h ? wds[bse + 2] : sw0;
      pa0.u[3] = h ? wds[bse + 3] : sw1;
      pa1.u[0] = h ? sw6 : wds[bse + 4];
      pa1.u[1] = h ? sw7 : wds[bse + 5];
      pa1.u[2] = h ? wds[bse + 6] : sw4;
      pa1.u[3] = h ? wds[bse + 7] : sw5;
#pragma unroll
      for (int cl = 0; cl < 2; cl++) {
        bf16x8 pa = cl ? pa1.v : pa0.v;
        int cg = kvc * 2 + cl;
#pragma unroll
        for (int dblk = 0; dblk < 2; dblk++) {
          bf16x8 vf = *(const bf16x8*)(vsb + (dblk * 32 + q32) * 128 + ((cg * 32 + h * 16) ^ swz));
          acc[dblk] = __builtin_amdgcn_mfma_f32_32x32x16_bf16(pa, vf, acc[dblk], 0, 0, 0);
        }
      }
    }
  }

#pragma unroll
  for (int g = 0; g < 4; g++) {
#pragma unroll
    for (int r = 0; r < 4; r++) {
      int row = g * 8 + h * 4 + r;
#pragma unroll
      for (int dblk = 0; dblk < 2; dblk++)
        Oh[(size_t)(qbase + row) * 64 + dblk * 32 + q32] = f2bf(acc[dblk][g * 4 + r]);
    }
  }
  if (h == 0) {
    int ro = sp * 65536 + bh * 2048 + qbase + q32;
    Ms[ro] = m_;
    Ss[ro] = s_;
  }
}

// ---------------- split-KV combine (2 splits) ----------------
__global__ __launch_bounds__(256) void attn_combine(const u16* __restrict__ O0, const u16* __restrict__ O1,
                                                    const float* __restrict__ Ms, const float* __restrict__ Ss,
                                                    const float* __restrict__ qmaskf, u16* __restrict__ out) {
  int idx = blockIdx.x * 256 + threadIdx.x;
  int row = idx >> 3;
  int d8 = (idx & 7) * 8;
  int bh = row >> 11, r = row & 2047, b = bh >> 4;
  float m0 = Ms[row], m1 = Ms[65536 + row];
  float mstar = fmaxf(m0, m1);
  float w0 = __builtin_amdgcn_exp2f(m0 - mstar);
  float w1 = __builtin_amdgcn_exp2f(m1 - mstar);
  float den = w0 * Ss[row] + w1 * Ss[65536 + row];
  float scale = qmaskf[b * 2048 + r] / den;
  size_t base = (size_t)row * 64 + d8;
  u16x8 a0 = *(const u16x8*)(O0 + base);
  u16x8 a1 = *(const u16x8*)(O1 + base);
  u16x8 o;
#pragma unroll
  for (int e = 0; e < 8; e++)
    o[e] = f2bf((w0 * bf2f(a0[e]) + w1 * bf2f(a1[e])) * scale);
  *(u16x8*)(out + base) = o;
}

// ---------------- residual + split-K partial sum + (bias) + layernorm ----------------
template<int NP, int A_F32, int ADD_BIAS, int OUT_F32>
__global__ __launch_bounds__(256) void add_ln_multi(const void* __restrict__ Ap,
                                                    const u16* __restrict__ P0, const u16* __restrict__ P1,
                                                    const u16* __restrict__ P2, const u16* __restrict__ P3,
                                                    const float* __restrict__ bias,
                                                    const float* __restrict__ g, const float* __restrict__ be,
                                                    void* __restrict__ outp) {
  int row = blockIdx.x, tid = threadIdx.x;
  int lane = tid & 63, wave = tid >> 6;
  size_t rb = (size_t)row * 1024;
  float x[4];
  if (A_F32) {
    f32x4 a = ((const f32x4*)((const float*)Ap + rb))[tid];
#pragma unroll
    for (int j = 0; j < 4; j++) x[j] = a[j];
  } else {
    u16x4 au = ((const u16x4*)((const u16*)Ap + rb))[tid];
#pragma unroll
    for (int j = 0; j < 4; j++) x[j] = bf2f(au[j]);
  }
  {
    u16x4 p = ((const u16x4*)(P0 + rb))[tid];
#pragma unroll
    for (int j = 0; j < 4; j++) x[j] += bf2f(p[j]);
  }
  if (NP > 1) {
    u16x4 p = ((const u16x4*)(P1 + rb))[tid];
#pragma unroll
    for (int j = 0; j < 4; j++) x[j] += bf2f(p[j]);
  }
  if (NP > 2) {
    u16x4 p = ((const u16x4*)(P2 + rb))[tid];
#pragma unroll
    for (int j = 0; j < 4; j++) x[j] += bf2f(p[j]);
  }
  if (NP > 3) {
    u16x4 p = ((const u16x4*)(P3 + rb))[tid];
#pragma unroll
    for (int j = 0; j < 4; j++) x[j] += bf2f(p[j]);
  }
  if (ADD_BIAS) {
    f32x4 bv = ((const f32x4*)bias)[tid];
#pragma unroll
    for (int j = 0; j < 4; j++) x[j] += bv[j];
  }
  float s = x[0] + x[1] + x[2] + x[3];
  float q = x[0] * x[0] + x[1] * x[1] + x[2] * x[2] + x[3] * x[3];
#pragma unroll
  for (int m = 1; m < 64; m <<= 1) { s += __shfl_xor(s, m); q += __shfl_xor(q, m); }
  __shared__ float rs[4], rq[4];
  if (lane == 0) { rs[wave] = s; rq[wave] = q; }
  __syncthreads();
  float S = rs[0] + rs[1] + rs[2] + rs[3];
  float Qq = rq[0] + rq[1] + rq[2] + rq[3];
  float mean = S * (1.0f / 1024.0f);
  float var = Qq * (1.0f / 1024.0f) - mean * mean;
  float rstd = rsqrtf(var + 1e-5f);
  if (OUT_F32) {
    f32x4 y;
#pragma unroll
    for (int j = 0; j < 4; j++) { int col = tid * 4 + j; y[j] = (x[j] - mean) * rstd * g[col] + be[col]; }
    ((f32x4*)((float*)outp + rb))[tid] = y;
  } else {
    u16x4 y;
#pragma unroll
    for (int j = 0; j < 4; j++) { int col = tid * 4 + j; y[j] = f2bf((x[j] - mean) * rstd * g[col] + be[col]); }
    ((u16x4*)((u16*)outp + rb))[tid] = y;
  }
}

// ---------------- launch ----------------
extern "C" void kernel_launch(void* const* d_in, const int* in_sizes, int n_in,
                              void* d_out, int out_size, void* d_ws, size_t ws_size,
                              hipStream_t stream) {
  const float* q   = (const float*)d_in[0];
  const float* k   = (const float*)d_in[1];
  const float* v   = (const float*)d_in[2];
  const void*  pad = d_in[3];
  const float* Wq  = (const float*)d_in[4];
  const float* Wk  = (const float*)d_in[5];
  const float* Wv  = (const float*)d_in[6];
  const float* Wo  = (const float*)d_in[7];
  const float* W1  = (const float*)d_in[8];
  const float* b1  = (const float*)d_in[9];
  const float* W2  = (const float*)d_in[10];
  const float* b2  = (const float*)d_in[11];
  const float* g1  = (const float*)d_in[12];
  const float* be1 = (const float*)d_in[13];
  const float* g2  = (const float*)d_in[14];
  const float* be2 = (const float*)d_in[15];
  float* out = (float*)d_out;
  char* ws = (char*)d_ws;
  const size_t MB = 1u << 20;

  u16* wq_b = (u16*)(ws + 0 * MB);
  u16* wk_b = (u16*)(ws + 2 * MB);
  u16* wv_b = (u16*)(ws + 4 * MB);
  u16* wo_b = (u16*)(ws + 6 * MB);
  u16* w1_b = (u16*)(ws + 8 * MB);
  u16* w2_b = (u16*)(ws + 16 * MB);
  u16* qb   = (u16*)(ws + 24 * MB);
  u16* kb   = (u16*)(ws + 32 * MB);
  u16* vb   = (u16*)(ws + 40 * MB);
  u16* Qb   = (u16*)(ws + 48 * MB);
  u16* Kb   = (u16*)(ws + 56 * MB);
  u16* Vb   = (u16*)(ws + 64 * MB);
  u16* VTb  = (u16*)(ws + 72 * MB);
  u16* hatt = (u16*)(ws + 80 * MB);
  // liveness overlays
  u16* Op0  = (u16*)(ws + 24 * MB);   // qb dead after QKV
  u16* Op1  = (u16*)(ws + 32 * MB);   // kb dead
  float* Ms = (float*)(ws + 88 * MB);
  float* Ss = (float*)(ws + 89 * MB);
  u16* WP   = (u16*)(ws + 40 * MB);   // Wo split-K partials x2 (vb,Qb dead): 40-56
  u16* h1b  = (u16*)(ws + 24 * MB);   // Op0 dead after combine
  u16* ff1  = (u16*)(ws + 32 * MB);   // Op1/WP/Kb dead after LN1: 32-64 (32 MB)
  u16* Fp   = (u16*)(ws + 64 * MB);   // FFN2 split-K partials x4: 64-96
  float* maskbias = (float*)(ws + 96 * MB);
  float* qmaskf   = (float*)(ws + 96 * MB + 16384);

  build_masks<<<1, 256, 0, stream>>>(pad, maskbias, qmaskf, in_sizes[3]);

  cvt_all<<<24576, 256, 0, stream>>>(q, k, v, Wq, Wk, Wv, Wo, W1, W2,
                                     qb, kb, vb, wq_b, wk_b, wv_b, wo_b, w1_b, w2_b);

  gemm_qkv<<<dim3(8, 32, 3), 512, 0, stream>>>(qb, kb, vb, wq_b, wk_b, wv_b, Qb, Kb, Vb);

  transpose64<<<dim3(32, 32), 256, 0, stream>>>(Vb, VTb);

  attn4<<<dim3(32, 16, 2), 256, 0, stream>>>(Qb, Kb, VTb, maskbias, Op0, Op1, Ms, Ss);

  attn_combine<<<2048, 256, 0, stream>>>(Op0, Op1, Ms, Ss, qmaskf, hatt);

  // Wo: split-K x2 (Kc=512), partials -> WP[2][4096][1024]
  gemm_splitk<<<dim3(8, 32, 2), 512, 0, stream>>>(hatt, wo_b, WP, 1024, 1024, 512);

  // LN1: q + WP0 + WP1 -> h1b (bf16)
  add_ln_multi<2, 1, 0, 0><<<4096, 256, 0, stream>>>(q, WP, WP + 4194304, nullptr, nullptr,
                                                     nullptr, g1, be1, h1b);

  // FFN1: h1 @ W1^T + b1, GELU -> ff1
  gemm_bt<2><<<dim3(32, 32), 512, 0, stream>>>(h1b, w1_b, b1, ff1, 4096, 1024);

  // FFN2: split-K x4 (Kc=1024), partials -> Fp[4][4096][1024]
  gemm_splitk<<<dim3(8, 32, 4), 512, 0, stream>>>(ff1, w2_b, Fp, 1024, 4096, 1024);

  // LN2: h1 + sum(Fp) + b2 -> out (f32)
  add_ln_multi<4, 0, 1, 1><<<4096, 256, 0, stream>>>(h1b, Fp, Fp + 4194304, Fp + 2 * 4194304,
                                                     Fp + 3 * 4194304, b2, g2, be2, out);
}

// Round 9
// 270.621 us; speedup vs baseline: 1.8074x; 1.0312x over previous
//
#include <hip/hip_runtime.h>

typedef unsigned short u16;
typedef unsigned int u32;
typedef __attribute__((ext_vector_type(8))) __bf16 bf16x8;
typedef __attribute__((ext_vector_type(4))) float f32x4;
typedef __attribute__((ext_vector_type(16))) float f32x16;
typedef __attribute__((ext_vector_type(4))) unsigned short u16x4;
typedef __attribute__((ext_vector_type(8))) unsigned short u16x8;
typedef __attribute__((ext_vector_type(2))) int i32x2;

#define LOG2E 1.44269504088896340736f

__device__ __forceinline__ u16 f2bf(float f) {
  union { float f; unsigned u; } c; c.f = f;
  unsigned r = c.u + 0x7FFFu + ((c.u >> 16) & 1u);
  return (u16)(r >> 16);
}
__device__ __forceinline__ float bf2f(u16 h) {
  union { unsigned u; float f; } c; c.u = ((unsigned)h) << 16;
  return c.f;
}
__device__ __forceinline__ float max3f(float a, float b, float c) {
  return fmaxf(fmaxf(a, b), c);
}

__device__ __forceinline__ void gload_lds16(const u16* g, u16* l) {
  __builtin_amdgcn_global_load_lds((const __attribute__((address_space(1))) unsigned int*)g,
                                   (__attribute__((address_space(3))) unsigned int*)l, 16, 0, 0);
}

// fast exact GELU: erf via Abramowitz-Stegun 7.1.26 (|eps| <= 1.5e-7)
__device__ __forceinline__ float gelu_fast(float x) {
  float z = fabsf(x) * 0.70710678118654752f;
  float t = 1.0f / (1.0f + 0.3275911f * z);
  float poly = t * (0.254829592f + t * (-0.284496736f + t * (1.421413741f +
               t * (-1.453152027f + t * 1.061405429f))));
  float e = __builtin_amdgcn_exp2f(-z * z * LOG2E);
  float erfz = 1.0f - poly * e;
  float s = (x >= 0.0f) ? erfz : -erfz;
  return 0.5f * x * (1.0f + s);
}

// ---------------- fused f32 -> bf16 conversion (all 9 tensors, one launch) ----------------
__global__ __launch_bounds__(256) void cvt_all(
    const float* __restrict__ s0, const float* __restrict__ s1, const float* __restrict__ s2,
    const float* __restrict__ s3, const float* __restrict__ s4, const float* __restrict__ s5,
    const float* __restrict__ s6, const float* __restrict__ s7, const float* __restrict__ s8,
    u16* __restrict__ d0, u16* __restrict__ d1, u16* __restrict__ d2,
    u16* __restrict__ d3, u16* __restrict__ d4, u16* __restrict__ d5,
    u16* __restrict__ d6, u16* __restrict__ d7, u16* __restrict__ d8) {
  int i = blockIdx.x * 256 + threadIdx.x;
  if (i >= 6291456) return;
  const float* src; u16* dst; int off;
  if (i < 3145728) {
    if (i < 1048576)      { src = s0; dst = d0; off = 0; }
    else if (i < 2097152) { src = s1; dst = d1; off = 1048576; }
    else                  { src = s2; dst = d2; off = 2097152; }
  } else if (i < 4194304) {
    if (i < 3407872)      { src = s3; dst = d3; off = 3145728; }
    else if (i < 3670016) { src = s4; dst = d4; off = 3407872; }
    else if (i < 3932160) { src = s5; dst = d5; off = 3670016; }
    else                  { src = s6; dst = d6; off = 3932160; }
  } else {
    if (i < 5242880)      { src = s7; dst = d7; off = 4194304; }
    else                  { src = s8; dst = d8; off = 5242880; }
  }
  int j = i - off;
  f32x4 v = ((const f32x4*)src)[j];
  u16x4 o;
  o[0] = f2bf(v[0]); o[1] = f2bf(v[1]); o[2] = f2bf(v[2]); o[3] = f2bf(v[3]);
  ((u16x4*)dst)[j] = o;
}

// ---------------- mask expansion (bool/int32 autodetect) ----------------
__global__ void build_masks(const void* __restrict__ pm, float* __restrict__ maskbias,
                            float* __restrict__ qmask, int n) {
  __shared__ int sflag;
  if (threadIdx.x == 0) sflag = 0;
  __syncthreads();
  const unsigned* pw = (const unsigned*)pm;
  int nwords = n / 4;
  int local = 0;
  for (int i = threadIdx.x; i < nwords; i += blockDim.x)
    if (pw[i] > 1u) local = 1;
  if (local) atomicOr(&sflag, 1);
  __syncthreads();
  bool isbool = (sflag != 0);
  for (int i = threadIdx.x; i < n; i += blockDim.x) {
    int m = isbool ? (int)((const unsigned char*)pm)[i] : ((const int*)pm)[i];
    maskbias[i] = m ? 0.0f : -2e30f;
    qmask[i]    = m ? 1.0f : 0.0f;
  }
}

// ---------------- GEMM core v5: BK=64, swizzled LDS (2-way-free), 1 barrier/phase ----------
// C[M,N] = act(A[M,Klen] @ W[N,Klen]^T + bias) -> bf16.  512 threads/block, 64KB LDS.
template<int EPI>
__device__ __forceinline__ void gemm_core(const u16* __restrict__ A, const u16* __restrict__ Bw,
                                          const float* __restrict__ bias, u16* __restrict__ C,
                                          int N, int Kstride, int Klen, int bn, int bm, int tid) {
  __shared__ u16 smem[2][16384];   // [buf][ A 0..8191 | B 8192..16383 ]  64 KB
  int wave = tid >> 6, lane = tid & 63;
  int l15 = lane & 15, l4 = lane >> 4;
  int wr = (wave >> 1) * 32;       // 4 wave-rows over 128
  int wc = (wave & 1) * 64;        // 2 wave-cols over 128
  int mrow0 = bm * 128, ncol0 = bn * 128;
  int rl = lane >> 3;                         // sub-row 0..7
  int osw = ((lane & 7) * 16) ^ (rl << 4);    // swizzled byte offset in 128B row
  int oswe = osw >> 1;                        // elements

  const u16* asrc0 = A  + (size_t)(mrow0 + wave * 16 + rl) * Kstride + oswe;
  const u16* asrc1 = A  + (size_t)(mrow0 + wave * 16 + 8 + rl) * Kstride + oswe;
  const u16* bsrc0 = Bw + (size_t)(ncol0 + wave * 16 + rl) * Kstride + oswe;
  const u16* bsrc1 = Bw + (size_t)(ncol0 + wave * 16 + 8 + rl) * Kstride + oswe;
  u16* adst0 = &smem[0][wave * 1024];
  u16* adst1 = &smem[0][wave * 1024 + 512];
  u16* bdst0 = &smem[0][8192 + wave * 1024];
  u16* bdst1 = &smem[0][8192 + wave * 1024 + 512];

  auto stage = [&](int buf, int k0) {
    gload_lds16(asrc0 + k0, adst0 + buf * 16384);
    gload_lds16(asrc1 + k0, adst1 + buf * 16384);
    gload_lds16(bsrc0 + k0, bdst0 + buf * 16384);
    gload_lds16(bsrc1 + k0, bdst1 + buf * 16384);
  };

  f32x4 acc[2][4];
#pragma unroll
  for (int i = 0; i < 2; i++)
#pragma unroll
    for (int j = 0; j < 4; j++) acc[i][j] = (f32x4)0.0f;

  int nsteps = Klen >> 6;
  stage(0, 0);
  int swzr = (l15 & 7) << 4;
  for (int s = 0; s < nsteps; s++) {
    asm volatile("s_waitcnt vmcnt(0)" ::: "memory");  // tile s landed (flew during phase s-1)
    __builtin_amdgcn_s_barrier();
    if (s + 1 < nsteps) stage((s + 1) & 1, (s + 1) << 6);  // issue-early, lands during this phase
    const char* as = (const char*)&smem[s & 1][0];
    const char* bs = (const char*)&smem[s & 1][8192];
#pragma unroll
    for (int kk = 0; kk < 2; kk++) {
      bf16x8 af[2], bfr[4];
#pragma unroll
      for (int mi = 0; mi < 2; mi++)
        af[mi]  = *(const bf16x8*)(as + (wr + mi * 16 + l15) * 128 + ((kk * 64 + l4 * 16) ^ swzr));
#pragma unroll
      for (int ni = 0; ni < 4; ni++)
        bfr[ni] = *(const bf16x8*)(bs + (wc + ni * 16 + l15) * 128 + ((kk * 64 + l4 * 16) ^ swzr));
#pragma unroll
      for (int mi = 0; mi < 2; mi++)
#pragma unroll
        for (int ni = 0; ni < 4; ni++)
          acc[mi][ni] = __builtin_amdgcn_mfma_f32_16x16x32_bf16(af[mi], bfr[ni], acc[mi][ni], 0, 0, 0);
    }
  }

  // epilogue: single-pass LDS bounce ([128][136] u16 = 34 KB) -> coalesced u16x8 stores
  __syncthreads();
  u16* ct = &smem[0][0];
#pragma unroll
  for (int ni = 0; ni < 4; ni++) {
    int gcol = ncol0 + wc + ni * 16 + l15;
    float bv = (EPI > 0) ? bias[gcol] : 0.0f;
#pragma unroll
    for (int mi = 0; mi < 2; mi++) {
#pragma unroll
      for (int r = 0; r < 4; r++) {
        float v = acc[mi][ni][r] + bv;
        if (EPI == 2) v = gelu_fast(v);
        ct[(wr + mi * 16 + l4 * 4 + r) * 136 + wc + ni * 16 + l15] = f2bf(v);
      }
    }
  }
  __syncthreads();
  int lrow = tid >> 2, cq = tid & 3;
#pragma unroll
  for (int j = 0; j < 4; j++) {
    int col = cq * 8 + j * 32;
    u16x8 vv = *(const u16x8*)(ct + lrow * 136 + col);
    *(u16x8*)(C + (size_t)(mrow0 + lrow) * N + ncol0 + col) = vv;
  }
}

template<int EPI>
__global__ __launch_bounds__(512, 4) void gemm_bt(const u16* __restrict__ A, const u16* __restrict__ Bw,
                                                  const float* __restrict__ bias, u16* __restrict__ C,
                                                  int N, int K) {
  gemm_core<EPI>(A, Bw, bias, C, N, K, K, blockIdx.x, blockIdx.y, threadIdx.x);
}

// split-K GEMM: blockIdx.z selects K-chunk of length Kc; writes bf16 partial at P + z*M*N
__global__ __launch_bounds__(512, 4) void gemm_splitk(const u16* __restrict__ A, const u16* __restrict__ Bw,
                                                      u16* __restrict__ P, int N, int Kstride, int Kc) {
  int z = blockIdx.z;
  size_t M = (size_t)gridDim.y * 128;
  gemm_core<0>(A + (size_t)z * Kc, Bw + (size_t)z * Kc, nullptr,
               P + (size_t)z * M * N, N, Kstride, Kc, blockIdx.x, blockIdx.y, threadIdx.x);
}

__global__ __launch_bounds__(512, 4) void gemm_qkv(const u16* __restrict__ qb, const u16* __restrict__ kb,
                                                   const u16* __restrict__ vb,
                                                   const u16* __restrict__ wq, const u16* __restrict__ wk,
                                                   const u16* __restrict__ wv,
                                                   u16* __restrict__ Qo, u16* __restrict__ Ko, u16* __restrict__ Vo) {
  const u16* A; const u16* W; u16* C;
  if (blockIdx.z == 0)      { A = qb; W = wq; C = Qo; }
  else if (blockIdx.z == 1) { A = kb; W = wk; C = Ko; }
  else                      { A = vb; W = wv; C = Vo; }
  gemm_core<0>(A, W, nullptr, C, 1024, 1024, 1024, blockIdx.x, blockIdx.y, threadIdx.x);
}

// ---------------- V transpose: [32][2048][64] -> [32][64][2048] ----------------
__global__ __launch_bounds__(256) void transpose64(const u16* __restrict__ in, u16* __restrict__ out) {
  int bh = blockIdx.y, tb = blockIdx.x;
  __shared__ u16 tile[64 * 72];
  int tid = threadIdx.x;
#pragma unroll
  for (int it = 0; it < 2; it++) {
    int idx = it * 256 + tid;
    int r = idx >> 3, c8 = (idx & 7) * 8;
    u16x8 v = *(const u16x8*)(in + ((size_t)bh * 2048 + tb * 64 + r) * 64 + c8);
    int byte = ((r * 72 + c8) * 2) ^ (((r >> 3) & 7) << 4);
    *(u16x8*)((char*)tile + byte) = v;
  }
  __syncthreads();
#pragma unroll
  for (int it = 0; it < 2; it++) {
    int idx = it * 256 + tid;
    int d = idx >> 3, t8 = (idx & 7) * 8;
    u16x8 o;
#pragma unroll
    for (int e = 0; e < 8; e++) {
      int t = t8 + e;
      int byte = ((t * 72 + d) * 2) ^ (((t >> 3) & 7) << 4);
      o[e] = *(const u16*)((const char*)tile + byte);
    }
    *(u16x8*)(out + ((size_t)bh * 64 + d) * 2048 + tb * 64 + t8) = o;
  }
}

// ---------------- flash attention v5: LDS K/V, swapped-QK, permlane softmax ----------------
__global__ __launch_bounds__(256, 4) void attn4(const u16* __restrict__ Q, const u16* __restrict__ Kg,
                                                const u16* __restrict__ VT,
                                                const float* __restrict__ maskbias,
                                                u16* __restrict__ O0, u16* __restrict__ O1,
                                                float* __restrict__ Ms, float* __restrict__ Ss) {
  const int T = 2048;
  int bh = blockIdx.x;
  int qt = blockIdx.y;
  int sp = blockIdx.z;
  int b = bh >> 4;
  const u16* Qh = Q  + (size_t)bh * T * 64;
  const u16* Kh = Kg + (size_t)bh * T * 64;
  const u16* Vh = VT + (size_t)bh * T * 64;   // [64][2048]
  u16* Oh = (sp ? O1 : O0) + (size_t)bh * T * 64;
  const float* mb = maskbias + b * T + sp * 1024;
  int tid = threadIdx.x, w = tid >> 6, l = tid & 63;
  int q32 = l & 31, h = l >> 5;
  int qbase = qt * 128 + w * 32;
  const float C = 0.125f * LOG2E;

  __shared__ u16 Ks[2][4096];
  __shared__ u16 Vs[2][4096];

  bf16x8 qf[4];
#pragma unroll
  for (int dc = 0; dc < 4; dc++)
    qf[dc] = *(const bf16x8*)(Qh + (size_t)(qbase + q32) * 64 + dc * 16 + h * 8);

  int rl = l >> 3, ob = (l & 7) * 16;
  int osw = ob ^ (rl << 4);
  int r0 = w * 16 + rl, r1 = w * 16 + 8 + rl;
  const u16* pK0 = Kh + (size_t)(sp * 1024 + r0) * 64 + (osw >> 1);
  const u16* pK1 = Kh + (size_t)(sp * 1024 + r1) * 64 + (osw >> 1);
  const u16* pV0 = Vh + (size_t)r0 * 2048 + sp * 1024 + (osw >> 1);
  const u16* pV1 = Vh + (size_t)r1 * 2048 + sp * 1024 + (osw >> 1);
  u16* dK0 = &Ks[0][0] + (w * 16) * 64;
  u16* dK1 = &Ks[0][0] + (w * 16 + 8) * 64;
  u16* dV0 = &Vs[0][0] + (w * 16) * 64;
  u16* dV1 = &Vs[0][0] + (w * 16 + 8) * 64;

  auto stage = [&](int buf) {
    gload_lds16(pK0, dK0 + buf * 4096);
    gload_lds16(pK1, dK1 + buf * 4096);
    gload_lds16(pV0, dV0 + buf * 4096);
    gload_lds16(pV1, dV1 + buf * 4096);
    pK0 += 4096; pK1 += 4096; pV0 += 64; pV1 += 64;
  };

  f32x16 acc[2];
  acc[0] = (f32x16)0.0f; acc[1] = (f32x16)0.0f;
  float m_ = -3e30f, s_ = 0.0f;

  int swz = (q32 & 7) << 4;

  stage(0);
  for (int t = 0; t < 16; t++) {
    int cur = t & 1;
    __syncthreads();
    if (t < 15) stage(cur ^ 1);
    const char* ksb = (const char*)(&Ks[0][0] + cur * 4096);
    const char* vsb = (const char*)(&Vs[0][0] + cur * 4096);

    bf16x8 kf[2][4];
#pragma unroll
    for (int kvc = 0; kvc < 2; kvc++)
#pragma unroll
      for (int dc = 0; dc < 4; dc++)
        kf[kvc][dc] = *(const bf16x8*)(ksb + (kvc * 32 + q32) * 128 + ((dc * 32 + h * 16) ^ swz));

    f32x16 st[2];
    st[0] = (f32x16)0.0f; st[1] = (f32x16)0.0f;
#pragma unroll
    for (int kvc = 0; kvc < 2; kvc++)
#pragma unroll
      for (int dc = 0; dc < 4; dc++)
        st[kvc] = __builtin_amdgcn_mfma_f32_32x32x16_bf16(kf[kvc][dc], qf[dc], st[kvc], 0, 0, 0);

    float p[32];
#pragma unroll
    for (int kvc = 0; kvc < 2; kvc++) {
#pragma unroll
      for (int g = 0; g < 4; g++) {
        f32x4 mv = *(const f32x4*)(mb + t * 64 + kvc * 32 + g * 8 + h * 4);
#pragma unroll
        for (int r = 0; r < 4; r++)
          p[kvc * 16 + g * 4 + r] = st[kvc][g * 4 + r] * C + mv[r];
      }
    }
    // lane-local max via two max3 chains, then permlane cross-half
    float ma = p[0], mb2 = p[16];
#pragma unroll
    for (int i = 0; i < 7; i++) {
      ma  = max3f(ma,  p[1 + 2 * i],  p[2 + 2 * i]);
      mb2 = max3f(mb2, p[17 + 2 * i], p[18 + 2 * i]);
    }
    ma = fmaxf(ma, p[15]); mb2 = fmaxf(mb2, p[31]);
    float pmax = fmaxf(ma, mb2);
    i32x2 pr = __builtin_amdgcn_permlane32_swap(__float_as_int(pmax), __float_as_int(pmax), false, false);
    pmax = fmaxf(__int_as_float(pr[0]), __int_as_float(pr[1]));

    if (__any(pmax - m_ > 8.0f)) {
      float mnew = fmaxf(m_, pmax);
      float fsc = __builtin_amdgcn_exp2f(m_ - mnew);
      s_ *= fsc;
      m_ = mnew;
#pragma unroll
      for (int g = 0; g < 4; g++)
#pragma unroll
        for (int r = 0; r < 4; r++) {
          float f = __shfl(fsc, g * 8 + h * 4 + r);
          acc[0][g * 4 + r] *= f;
          acc[1][g * 4 + r] *= f;
        }
    }

    float rsum = 0.0f;
    u32 wds[16];
#pragma unroll
    for (int i = 0; i < 16; i++) {
      float a = __builtin_amdgcn_exp2f(p[2 * i] - m_);
      float bq = __builtin_amdgcn_exp2f(p[2 * i + 1] - m_);
      rsum += a + bq;
      union { __bf16 h2[2]; u32 u; } cv;
      cv.h2[0] = (__bf16)a; cv.h2[1] = (__bf16)bq;
      wds[i] = cv.u;
    }
    i32x2 sr = __builtin_amdgcn_permlane32_swap(__float_as_int(rsum), __float_as_int(rsum), false, false);
    rsum = __int_as_float(sr[0]) + __int_as_float(sr[1]);
    s_ += rsum;

#pragma unroll
    for (int kvc = 0; kvc < 2; kvc++) {
      int bse = kvc * 8;
      i32x2 r02 = __builtin_amdgcn_permlane32_swap((int)wds[bse + 0], (int)wds[bse + 2], false, false);
      i32x2 r13 = __builtin_amdgcn_permlane32_swap((int)wds[bse + 1], (int)wds[bse + 3], false, false);
      i32x2 r46 = __builtin_amdgcn_permlane32_swap((int)wds[bse + 4], (int)wds[bse + 6], false, false);
      i32x2 r57 = __builtin_amdgcn_permlane32_swap((int)wds[bse + 5], (int)wds[bse + 7], false, false);
      union { u32 u[4]; bf16x8 v; } pa0, pa1;
      pa0.u[0] = (u32)r02[0]; pa0.u[1] = (u32)r13[0]; pa0.u[2] = (u32)r02[1]; pa0.u[3] = (u32)r13[1];
      pa1.u[0] = (u32)r46[0]; pa1.u[1] = (u32)r57[0]; pa1.u[2] = (u32)r46[1]; pa1.u[3] = (u32)r57[1];
#pragma unroll
      for (int cl = 0; cl < 2; cl++) {
        bf16x8 pa = cl ? pa1.v : pa0.v;
        int cg = kvc * 2 + cl;
#pragma unroll
        for (int dblk = 0; dblk < 2; dblk++) {
          bf16x8 vf = *(const bf16x8*)(vsb + (dblk * 32 + q32) * 128 + ((cg * 32 + h * 16) ^ swz));
          acc[dblk] = __builtin_amdgcn_mfma_f32_32x32x16_bf16(pa, vf, acc[dblk], 0, 0, 0);
        }
      }
    }
  }

#pragma unroll
  for (int g = 0; g < 4; g++) {
#pragma unroll
    for (int r = 0; r < 4; r++) {
      int row = g * 8 + h * 4 + r;
#pragma unroll
      for (int dblk = 0; dblk < 2; dblk++)
        Oh[(size_t)(qbase + row) * 64 + dblk * 32 + q32] = f2bf(acc[dblk][g * 4 + r]);
    }
  }
  if (h == 0) {
    int ro = sp * 65536 + bh * 2048 + qbase + q32;
    Ms[ro] = m_;
    Ss[ro] = s_;
  }
}

// ---------------- split-KV combine (2 splits) ----------------
__global__ __launch_bounds__(256) void attn_combine(const u16* __restrict__ O0, const u16* __restrict__ O1,
                                                    const float* __restrict__ Ms, const float* __restrict__ Ss,
                                                    const float* __restrict__ qmaskf, u16* __restrict__ out) {
  int idx = blockIdx.x * 256 + threadIdx.x;
  int row = idx >> 3;
  int d8 = (idx & 7) * 8;
  int bh = row >> 11, r = row & 2047, b = bh >> 4;
  float m0 = Ms[row], m1 = Ms[65536 + row];
  float mstar = fmaxf(m0, m1);
  float w0 = __builtin_amdgcn_exp2f(m0 - mstar);
  float w1 = __builtin_amdgcn_exp2f(m1 - mstar);
  float den = w0 * Ss[row] + w1 * Ss[65536 + row];
  float scale = qmaskf[b * 2048 + r] / den;
  size_t base = (size_t)row * 64 + d8;
  u16x8 a0 = *(const u16x8*)(O0 + base);
  u16x8 a1 = *(const u16x8*)(O1 + base);
  u16x8 o;
#pragma unroll
  for (int e = 0; e < 8; e++)
    o[e] = f2bf((w0 * bf2f(a0[e]) + w1 * bf2f(a1[e])) * scale);
  *(u16x8*)(out + base) = o;
}

// ---------------- residual + split-K partial sum + (bias) + layernorm ----------------
template<int NP, int A_F32, int ADD_BIAS, int OUT_F32>
__global__ __launch_bounds__(256) void add_ln_multi(const void* __restrict__ Ap,
                                                    const u16* __restrict__ P0, const u16* __restrict__ P1,
                                                    const u16* __restrict__ P2, const u16* __restrict__ P3,
                                                    const float* __restrict__ bias,
                                                    const float* __restrict__ g, const float* __restrict__ be,
                                                    void* __restrict__ outp) {
  int row = blockIdx.x, tid = threadIdx.x;
  int lane = tid & 63, wave = tid >> 6;
  size_t rb = (size_t)row * 1024;
  float x[4];
  if (A_F32) {
    f32x4 a = ((const f32x4*)((const float*)Ap + rb))[tid];
#pragma unroll
    for (int j = 0; j < 4; j++) x[j] = a[j];
  } else {
    u16x4 au = ((const u16x4*)((const u16*)Ap + rb))[tid];
#pragma unroll
    for (int j = 0; j < 4; j++) x[j] = bf2f(au[j]);
  }
  {
    u16x4 p = ((const u16x4*)(P0 + rb))[tid];
#pragma unroll
    for (int j = 0; j < 4; j++) x[j] += bf2f(p[j]);
  }
  if (NP > 1) {
    u16x4 p = ((const u16x4*)(P1 + rb))[tid];
#pragma unroll
    for (int j = 0; j < 4; j++) x[j] += bf2f(p[j]);
  }
  if (NP > 2) {
    u16x4 p = ((const u16x4*)(P2 + rb))[tid];
#pragma unroll
    for (int j = 0; j < 4; j++) x[j] += bf2f(p[j]);
  }
  if (NP > 3) {
    u16x4 p = ((const u16x4*)(P3 + rb))[tid];
#pragma unroll
    for (int j = 0; j < 4; j++) x[j] += bf2f(p[j]);
  }
  if (ADD_BIAS) {
    f32x4 bv = ((const f32x4*)bias)[tid];
#pragma unroll
    for (int j = 0; j < 4; j++) x[j] += bv[j];
  }
  float s = x[0] + x[1] + x[2] + x[3];
  float q = x[0] * x[0] + x[1] * x[1] + x[2] * x[2] + x[3] * x[3];
#pragma unroll
  for (int m = 1; m < 64; m <<= 1) { s += __shfl_xor(s, m); q += __shfl_xor(q, m); }
  __shared__ float rs[4], rq[4];
  if (lane == 0) { rs[wave] = s; rq[wave] = q; }
  __syncthreads();
  float S = rs[0] + rs[1] + rs[2] + rs[3];
  float Qq = rq[0] + rq[1] + rq[2] + rq[3];
  float mean = S * (1.0f / 1024.0f);
  float var = Qq * (1.0f / 1024.0f) - mean * mean;
  float rstd = rsqrtf(var + 1e-5f);
  if (OUT_F32) {
    f32x4 y;
#pragma unroll
    for (int j = 0; j < 4; j++) { int col = tid * 4 + j; y[j] = (x[j] - mean) * rstd * g[col] + be[col]; }
    ((f32x4*)((float*)outp + rb))[tid] = y;
  } else {
    u16x4 y;
#pragma unroll
    for (int j = 0; j < 4; j++) { int col = tid * 4 + j; y[j] = f2bf((x[j] - mean) * rstd * g[col] + be[col]); }
    ((u16x4*)((u16*)outp + rb))[tid] = y;
  }
}

// ---------------- launch ----------------
extern "C" void kernel_launch(void* const* d_in, const int* in_sizes, int n_in,
                              void* d_out, int out_size, void* d_ws, size_t ws_size,
                              hipStream_t stream) {
  const float* q   = (const float*)d_in[0];
  const float* k   = (const float*)d_in[1];
  const float* v   = (const float*)d_in[2];
  const void*  pad = d_in[3];
  const float* Wq  = (const float*)d_in[4];
  const float* Wk  = (const float*)d_in[5];
  const float* Wv  = (const float*)d_in[6];
  const float* Wo  = (const float*)d_in[7];
  const float* W1  = (const float*)d_in[8];
  const float* b1  = (const float*)d_in[9];
  const float* W2  = (const float*)d_in[10];
  const float* b2  = (const float*)d_in[11];
  const float* g1  = (const float*)d_in[12];
  const float* be1 = (const float*)d_in[13];
  const float* g2  = (const float*)d_in[14];
  const float* be2 = (const float*)d_in[15];
  float* out = (float*)d_out;
  char* ws = (char*)d_ws;
  const size_t MB = 1u << 20;

  u16* wq_b = (u16*)(ws + 0 * MB);
  u16* wk_b = (u16*)(ws + 2 * MB);
  u16* wv_b = (u16*)(ws + 4 * MB);
  u16* wo_b = (u16*)(ws + 6 * MB);
  u16* w1_b = (u16*)(ws + 8 * MB);
  u16* w2_b = (u16*)(ws + 16 * MB);
  u16* qb   = (u16*)(ws + 24 * MB);
  u16* kb   = (u16*)(ws + 32 * MB);
  u16* vb   = (u16*)(ws + 40 * MB);
  u16* Qb   = (u16*)(ws + 48 * MB);
  u16* Kb   = (u16*)(ws + 56 * MB);
  u16* Vb   = (u16*)(ws + 64 * MB);
  u16* VTb  = (u16*)(ws + 72 * MB);
  u16* hatt = (u16*)(ws + 80 * MB);
  // liveness overlays
  u16* Op0  = (u16*)(ws + 24 * MB);   // qb dead after QKV
  u16* Op1  = (u16*)(ws + 32 * MB);   // kb dead
  float* Ms = (float*)(ws + 88 * MB);
  float* Ss = (float*)(ws + 89 * MB);
  u16* WP   = (u16*)(ws + 40 * MB);   // Wo split-K partials x2 (vb,Qb dead): 40-56
  u16* h1b  = (u16*)(ws + 24 * MB);   // Op0 dead after combine
  u16* ff1  = (u16*)(ws + 32 * MB);   // Op1/WP/Kb dead after LN1: 32-64 (32 MB)
  u16* Fp   = (u16*)(ws + 64 * MB);   // FFN2 split-K partials x4: 64-96
  float* maskbias = (float*)(ws + 96 * MB);
  float* qmaskf   = (float*)(ws + 96 * MB + 16384);

  build_masks<<<1, 256, 0, stream>>>(pad, maskbias, qmaskf, in_sizes[3]);

  cvt_all<<<24576, 256, 0, stream>>>(q, k, v, Wq, Wk, Wv, Wo, W1, W2,
                                     qb, kb, vb, wq_b, wk_b, wv_b, wo_b, w1_b, w2_b);

  gemm_qkv<<<dim3(8, 32, 3), 512, 0, stream>>>(qb, kb, vb, wq_b, wk_b, wv_b, Qb, Kb, Vb);

  transpose64<<<dim3(32, 32), 256, 0, stream>>>(Vb, VTb);

  attn4<<<dim3(32, 16, 2), 256, 0, stream>>>(Qb, Kb, VTb, maskbias, Op0, Op1, Ms, Ss);

  attn_combine<<<2048, 256, 0, stream>>>(Op0, Op1, Ms, Ss, qmaskf, hatt);

  // Wo: split-K x2 (Kc=512), partials -> WP[2][4096][1024]
  gemm_splitk<<<dim3(8, 32, 2), 512, 0, stream>>>(hatt, wo_b, WP, 1024, 1024, 512);

  // LN1: q + WP0 + WP1 -> h1b (bf16)
  add_ln_multi<2, 1, 0, 0><<<4096, 256, 0, stream>>>(q, WP, WP + 4194304, nullptr, nullptr,
                                                     nullptr, g1, be1, h1b);

  // FFN1: h1 @ W1^T + b1, GELU -> ff1
  gemm_bt<2><<<dim3(32, 32), 512, 0, stream>>>(h1b, w1_b, b1, ff1, 4096, 1024);

  // FFN2: split-K x4 (Kc=1024), partials -> Fp[4][4096][1024]
  gemm_splitk<<<dim3(8, 32, 4), 512, 0, stream>>>(ff1, w2_b, Fp, 1024, 4096, 1024);

  // LN2: h1 + sum(Fp) + b2 -> out (f32)
  add_ln_multi<4, 0, 1, 1><<<4096, 256, 0, stream>>>(h1b, Fp, Fp + 4194304, Fp + 2 * 4194304,
                                                     Fp + 3 * 4194304, b2, g2, be2, out);
}